// Round 1
// baseline (6227.570 us; speedup 1.0000x reference)
//
#include <hip/hip_runtime.h>
#include <math.h>

#define B_ 8
#define D_ 1024
#define N_ 4096
#define K_ 64
#define H_ 512

// ---------------- helpers ----------------
__device__ __forceinline__ float block_reduce_sum256(float v, float* sm) {
  int tid = threadIdx.x;
  sm[tid] = v;
  __syncthreads();
  for (int s = 128; s > 0; s >>= 1) {
    if (tid < s) sm[tid] += sm[tid + s];
    __syncthreads();
  }
  float r = sm[0];
  __syncthreads();
  return r;
}

// ---------------- 128x128x8 NN SGEMM (C[b] = A @ B[b] + bias) ----------------
// A: [M,Kd] row-major (shared across batch), B: [Kd,N] row-major, C: [M,N]
__global__ __launch_bounds__(256)
void sgemm128_nn(const float* __restrict__ A, const float* __restrict__ Bm,
                 float* __restrict__ C, const float* __restrict__ bias,
                 int M, int N, int Kd, long sB, long sC) {
  __shared__ float As[8][128];
  __shared__ float Bs[8][128];
  const float* Bp = Bm + (long)blockIdx.z * sB;
  float* Cp = C + (long)blockIdx.z * sC;
  int m0 = blockIdx.y * 128, n0 = blockIdx.x * 128;
  int tid = threadIdx.x;
  int tx = tid & 15, ty = tid >> 4;
  int arow = tid >> 1, acol = (tid & 1) * 4;
  int brow = tid >> 5, bcol = (tid & 31) * 4;
  float acc[8][8];
#pragma unroll
  for (int i = 0; i < 8; ++i)
#pragma unroll
    for (int j = 0; j < 8; ++j) acc[i][j] = 0.f;

  for (int k0 = 0; k0 < Kd; k0 += 8) {
    float4 av = *(const float4*)(A + (long)(m0 + arow) * Kd + k0 + acol);
    float4 bv = *(const float4*)(Bp + (long)(k0 + brow) * N + n0 + bcol);
    __syncthreads();
    As[acol + 0][arow] = av.x;
    As[acol + 1][arow] = av.y;
    As[acol + 2][arow] = av.z;
    As[acol + 3][arow] = av.w;
    *(float4*)&Bs[brow][bcol] = bv;
    __syncthreads();
#pragma unroll
    for (int kk = 0; kk < 8; ++kk) {
      float4 a0 = *(const float4*)&As[kk][ty * 8];
      float4 a1 = *(const float4*)&As[kk][ty * 8 + 4];
      float4 b0 = *(const float4*)&Bs[kk][tx * 8];
      float4 b1 = *(const float4*)&Bs[kk][tx * 8 + 4];
      float am[8] = {a0.x, a0.y, a0.z, a0.w, a1.x, a1.y, a1.z, a1.w};
      float bn[8] = {b0.x, b0.y, b0.z, b0.w, b1.x, b1.y, b1.z, b1.w};
#pragma unroll
      for (int i = 0; i < 8; ++i)
#pragma unroll
        for (int j = 0; j < 8; ++j) acc[i][j] += am[i] * bn[j];
    }
  }
#pragma unroll
  for (int i = 0; i < 8; ++i) {
    int m = m0 + ty * 8 + i;
    float bb = bias ? bias[m] : 0.f;
    float4 o0, o1;
    o0.x = acc[i][0] + bb; o0.y = acc[i][1] + bb; o0.z = acc[i][2] + bb; o0.w = acc[i][3] + bb;
    o1.x = acc[i][4] + bb; o1.y = acc[i][5] + bb; o1.z = acc[i][6] + bb; o1.w = acc[i][7] + bb;
    *(float4*)(Cp + (long)m * N + n0 + tx * 8) = o0;
    *(float4*)(Cp + (long)m * N + n0 + tx * 8 + 4) = o1;
  }
}

// ---------------- 64x64x16 NN SGEMM (batched A option) ----------------
__global__ __launch_bounds__(256)
void sgemm64_nn(const float* __restrict__ A, const float* __restrict__ Bm,
                float* __restrict__ C, const float* __restrict__ bias,
                int M, int N, int Kd, long sA, long sB, long sC) {
  __shared__ float As[16][64];
  __shared__ float Bs[16][64];
  const float* Ap = A + (long)blockIdx.z * sA;
  const float* Bp = Bm + (long)blockIdx.z * sB;
  float* Cp = C + (long)blockIdx.z * sC;
  int m0 = blockIdx.y * 64, n0 = blockIdx.x * 64;
  int tid = threadIdx.x;
  int tx = tid & 15, ty = tid >> 4;
  int arow = tid >> 2, acol = (tid & 3) * 4;
  int brow = tid >> 4, bcol = (tid & 15) * 4;
  float acc[4][4];
#pragma unroll
  for (int i = 0; i < 4; ++i)
#pragma unroll
    for (int j = 0; j < 4; ++j) acc[i][j] = 0.f;

  for (int k0 = 0; k0 < Kd; k0 += 16) {
    float4 av = *(const float4*)(Ap + (long)(m0 + arow) * Kd + k0 + acol);
    float4 bv = *(const float4*)(Bp + (long)(k0 + brow) * N + n0 + bcol);
    __syncthreads();
    As[acol + 0][arow] = av.x;
    As[acol + 1][arow] = av.y;
    As[acol + 2][arow] = av.z;
    As[acol + 3][arow] = av.w;
    *(float4*)&Bs[brow][bcol] = bv;
    __syncthreads();
#pragma unroll
    for (int kk = 0; kk < 16; ++kk) {
      float4 a = *(const float4*)&As[kk][ty * 4];
      float4 bq = *(const float4*)&Bs[kk][tx * 4];
      float am[4] = {a.x, a.y, a.z, a.w};
      float bn[4] = {bq.x, bq.y, bq.z, bq.w};
#pragma unroll
      for (int i = 0; i < 4; ++i)
#pragma unroll
        for (int j = 0; j < 4; ++j) acc[i][j] += am[i] * bn[j];
    }
  }
#pragma unroll
  for (int i = 0; i < 4; ++i) {
    int m = m0 + ty * 4 + i;
    float bb = bias ? bias[m] : 0.f;
    float4 o;
    o.x = acc[i][0] + bb; o.y = acc[i][1] + bb; o.z = acc[i][2] + bb; o.w = acc[i][3] + bb;
    *(float4*)(Cp + (long)m * N + n0 + tx * 4) = o;
  }
}

// ---------------- BN stats (training-mode batch stats, folded scale/shift) ----------------
__global__ __launch_bounds__(256)
void bn_stats(const float* __restrict__ Y, const float* __restrict__ g,
              const float* __restrict__ be, float* __restrict__ scale,
              float* __restrict__ shift, int C) {
  int c = blockIdx.x;
  double s1 = 0.0, s2 = 0.0;
  for (int idx = threadIdx.x; idx < B_ * N_; idx += 256) {
    int b = idx >> 12, n = idx & (N_ - 1);
    float v = Y[((long)b * C + c) * N_ + n];
    s1 += v;
    s2 += (double)v * (double)v;
  }
  __shared__ double r1[256], r2[256];
  int tid = threadIdx.x;
  r1[tid] = s1; r2[tid] = s2;
  __syncthreads();
  for (int s = 128; s > 0; s >>= 1) {
    if (tid < s) { r1[tid] += r1[tid + s]; r2[tid] += r2[tid + s]; }
    __syncthreads();
  }
  if (tid == 0) {
    double m = r1[0] / (double)(B_ * N_);
    double var = r2[0] / (double)(B_ * N_) - m * m;
    float sc = (float)((double)g[c] / sqrt(var + 1e-5));
    scale[c] = sc;
    shift[c] = (float)((double)be[c] - m * (double)sc);
  }
}

__global__ __launch_bounds__(256)
void bn_relu(float* __restrict__ Y, const float* __restrict__ scale,
             const float* __restrict__ shift, int C) {
  long i4 = (long)blockIdx.x * 256 + threadIdx.x;
  long i = i4 * 4;
  int c = (int)((i >> 12) % C);
  float sc = scale[c], sh = shift[c];
  float4 v = *(float4*)(Y + i);
  v.x = fmaxf(v.x * sc + sh, 0.f);
  v.y = fmaxf(v.y * sc + sh, 0.f);
  v.z = fmaxf(v.z * sc + sh, 0.f);
  v.w = fmaxf(v.w * sc + sh, 0.f);
  *(float4*)(Y + i) = v;
}

// ---------------- softmax over K (axis=1), writes transposed score/logp + pi accumulation ----
__global__ __launch_bounds__(256)
void softmax_k(const float* __restrict__ ls, float* __restrict__ scoreT,
               float* __restrict__ logpT, float* __restrict__ pi_raw) {
  __shared__ float ploc[64];
  int tid = threadIdx.x;
  if (tid < 64) ploc[tid] = 0.f;
  __syncthreads();
  long gid = (long)blockIdx.x * 256 + tid;
  int b = (int)(gid >> 12);
  int n = (int)(gid & (N_ - 1));
  const float* x = ls + ((long)b * K_) * N_ + n;
  float mx = -1e30f;
  for (int k = 0; k < 64; ++k) mx = fmaxf(mx, x[(long)k * N_]);
  float s = 0.f;
  for (int k = 0; k < 64; ++k) s += expf(x[(long)k * N_] - mx);
  float lg = logf(s);
  float inv = 1.f / s;
  float* st = scoreT + gid * 64;
  float* lp = logpT + gid * 64;
  for (int k = 0; k < 64; ++k) {
    float xv = x[(long)k * N_] - mx;
    float e = expf(xv);
    float sc = e * inv;
    st[k] = sc;
    lp[k] = xv - lg;
    atomicAdd(&ploc[k], sc);
  }
  __syncthreads();
  if (tid < 64) atomicAdd(&pi_raw[b * 64 + tid], ploc[tid]);
}

__global__ void pi_fin(const float* __restrict__ pr, float* __restrict__ pi) {
  int i = blockIdx.x * 256 + threadIdx.x;
  if (i < B_ * K_) pi[i] = fmaxf(pr[i], 1e-4f);
}

// ---------------- mu_xyz (one wave per (k,b)) ----------------
__global__ __launch_bounds__(64)
void mu_xyz_k(const float* __restrict__ scoreT, const float* __restrict__ xyz,
              const float* __restrict__ pi, float* __restrict__ mu, float* __restrict__ yn) {
  int k = blockIdx.x, b = blockIdx.y, t = threadIdx.x;
  const float* st = scoreT + ((long)b * N_) * K_ + k;
  const float* xp = xyz + (long)b * 3 * N_;
  float a0 = 0, a1 = 0, a2 = 0;
  for (int n = t; n < N_; n += 64) {
    float s = st[(long)n * K_];
    a0 += s * xp[n];
    a1 += s * xp[N_ + n];
    a2 += s * xp[2 * N_ + n];
  }
  for (int off = 32; off > 0; off >>= 1) {
    a0 += __shfl_down(a0, off);
    a1 += __shfl_down(a1, off);
    a2 += __shfl_down(a2, off);
  }
  if (t == 0) {
    float p = pi[b * K_ + k];
    float m0 = a0 / p, m1 = a1 / p, m2 = a2 / p;
    mu[((long)b * 3 + 0) * K_ + k] = m0;
    mu[((long)b * 3 + 1) * K_ + k] = m1;
    mu[((long)b * 3 + 2) * K_ + k] = m2;
    yn[b * K_ + k] = m0 * m0 + m1 * m1 + m2 * m2;
  }
}

// ---------------- regularizers ----------------
__global__ __launch_bounds__(256)
void reg_xyz_k(const float* __restrict__ mu, float* __restrict__ out) {
  __shared__ float red[256];
  int b = blockIdx.x, tid = threadIdx.x;
  float acc = 0.f;
  for (int e = tid; e < 4096; e += 256) {
    int m = e >> 6, n2 = e & 63;
    float g = 0.f;
    for (int d = 0; d < 3; ++d)
      g += mu[((long)b * 3 + d) * K_ + m] * mu[((long)b * 3 + d) * K_ + n2];
    acc += fabsf(g - (m == n2 ? 1.f : 0.f));
  }
  float tot = block_reduce_sum256(acc, red);
  if (tid == 0) atomicAdd(out, tot * (1e-7f / 32768.f));
}

__global__ __launch_bounds__(256)
void reg_fea_k(const float* __restrict__ nT, float* __restrict__ out) {
  __shared__ float red[256];
  int b = blockIdx.x, tid = threadIdx.x;
  float acc = 0.f;
  for (int e = tid; e < 4096; e += 256) {
    int m = e >> 6, n2 = e & 63;
    const float* pm_ = nT + ((long)b * K_ + m) * D_;
    const float* pn_ = nT + ((long)b * K_ + n2) * D_;
    float g0 = 0, g1 = 0, g2 = 0, g3 = 0;
    for (int d = 0; d < D_; d += 4) {
      g0 += pm_[d] * pn_[d];
      g1 += pm_[d + 1] * pn_[d + 1];
      g2 += pm_[d + 2] * pn_[d + 2];
      g3 += pm_[d + 3] * pn_[d + 3];
    }
    float g = (g0 + g1) + (g2 + g3);
    acc += fabsf(g - (m == n2 ? 1.f : 0.f));
  }
  float tot = block_reduce_sum256(acc, red);
  if (tid == 0) atomicAdd(out, tot * (1e-4f / 32768.f));
}

// ---------------- cost_xyz ----------------
__global__ __launch_bounds__(256)
void cost_xyz_k(const float* __restrict__ xyz, const float* __restrict__ mu,
                const float* __restrict__ yn, float* __restrict__ cost) {
  __shared__ float m0s[64], m1s[64], m2s[64], yl[64];
  int b = blockIdx.y;
  int tid = threadIdx.x;
  if (tid < 64) {
    m0s[tid] = mu[((long)b * 3 + 0) * K_ + tid];
    m1s[tid] = mu[((long)b * 3 + 1) * K_ + tid];
    m2s[tid] = mu[((long)b * 3 + 2) * K_ + tid];
    yl[tid] = yn[b * K_ + tid];
  }
  __syncthreads();
  int n = blockIdx.x * 256 + tid;
  const float* xp = xyz + (long)b * 3 * N_;
  float x0 = xp[n], x1 = xp[N_ + n], x2 = xp[2 * N_ + n];
  float xn = x0 * x0 + x1 * x1 + x2 * x2;
  float* cr = cost + ((long)b * N_ + n) * K_;
  for (int m = 0; m < 64; ++m)
    cr[m] = xn + yl[m] - 2.f * (x0 * m0s[m] + x1 * m1s[m] + x2 * m2s[m]);
}

// ---------------- mu_fea finalize: /pi then normalize; writes [D,K] and [K,D] ----------------
__global__ __launch_bounds__(256)
void mu_finalize(const float* __restrict__ mu_raw, const float* __restrict__ pi,
                 float* __restrict__ n_mu, float* __restrict__ n_muT) {
  __shared__ float red[256];
  int k = blockIdx.x, b = blockIdx.y, tid = threadIdx.x;
  float p = pi[b * K_ + k];
  float ss = 0.f;
  for (int d = tid; d < D_; d += 256) {
    float v = mu_raw[((long)b * D_ + d) * K_ + k] / p;
    ss += v * v;
  }
  float tot = block_reduce_sum256(ss, red);
  float inv = 1.f / fmaxf(sqrtf(tot), 1e-12f);
  for (int d = tid; d < D_; d += 256) {
    float v = mu_raw[((long)b * D_ + d) * K_ + k] / p * inv;
    n_mu[((long)b * D_ + d) * K_ + k] = v;
    n_muT[((long)b * K_ + k) * D_ + d] = v;
  }
}

// ---------------- feature inverse norms ----------------
__global__ __launch_bounds__(256)
void inv_nrm_k(const float* __restrict__ F, float* __restrict__ invn) {
  int b = blockIdx.y;
  int n = blockIdx.x * 256 + threadIdx.x;
  const float* f = F + (long)b * D_ * N_ + n;
  float s0 = 0, s1 = 0, s2 = 0, s3 = 0;
  for (int d = 0; d < D_; d += 4) {
    float v0 = f[(long)d * N_], v1 = f[(long)(d + 1) * N_];
    float v2 = f[(long)(d + 2) * N_], v3 = f[(long)(d + 3) * N_];
    s0 += v0 * v0; s1 += v1 * v1; s2 += v2 * v2; s3 += v3 * v3;
  }
  float ss = (s0 + s1) + (s2 + s3);
  invn[b * N_ + n] = 1.f / fmaxf(sqrtf(ss), 1e-12f);
}

// ---------------- cost_fea: TN GEMM, epilogue 2 - 2*dot*invn[n] ----------------
__global__ __launch_bounds__(256)
void cost_fea_gemm(const float* __restrict__ F, const float* __restrict__ nmu,
                   const float* __restrict__ invn, float* __restrict__ cost) {
  __shared__ float As[16][64];
  __shared__ float Bs[16][64];
  int b = blockIdx.y, n0 = blockIdx.x * 64;
  int tid = threadIdx.x;
  int tx = tid & 15, ty = tid >> 4;
  int lr = tid >> 4, lc = (tid & 15) * 4;
  const float* Fp = F + (long)b * D_ * N_;
  const float* Mp = nmu + (long)b * D_ * K_;
  float acc[4][4];
#pragma unroll
  for (int i = 0; i < 4; ++i)
#pragma unroll
    for (int j = 0; j < 4; ++j) acc[i][j] = 0.f;

  for (int d0 = 0; d0 < D_; d0 += 16) {
    float4 av = *(const float4*)(Fp + (long)(d0 + lr) * N_ + n0 + lc);
    float4 bv = *(const float4*)(Mp + (long)(d0 + lr) * K_ + lc);
    __syncthreads();
    *(float4*)&As[lr][lc] = av;
    *(float4*)&Bs[lr][lc] = bv;
    __syncthreads();
#pragma unroll
    for (int kk = 0; kk < 16; ++kk) {
      float4 a = *(const float4*)&As[kk][ty * 4];
      float4 bq = *(const float4*)&Bs[kk][tx * 4];
      float am[4] = {a.x, a.y, a.z, a.w};
      float bn[4] = {bq.x, bq.y, bq.z, bq.w};
#pragma unroll
      for (int i = 0; i < 4; ++i)
#pragma unroll
        for (int j = 0; j < 4; ++j) acc[i][j] += am[i] * bn[j];
    }
  }
#pragma unroll
  for (int i = 0; i < 4; ++i) {
    int n = n0 + ty * 4 + i;
    float w = -2.f * invn[b * N_ + n];
    float4 o;
    o.x = 2.f + w * acc[i][0];
    o.y = 2.f + w * acc[i][1];
    o.z = 2.f + w * acc[i][2];
    o.w = 2.f + w * acc[i][3];
    *(float4*)(cost + ((long)b * N_ + n) * K_ + tx * 4) = o;
  }
}

// ---------------- Sinkhorn (25 iters) + fused loss ----------------
__global__ __launch_bounds__(1024)
void sinkhorn_loss(const float* __restrict__ cost_x, const float* __restrict__ cost_f,
                   const float* __restrict__ logpT, float* __restrict__ out) {
  __shared__ float u[N_];
  __shared__ float v[64];
  __shared__ float pm[1024];
  __shared__ float ps[1024];
  int b = blockIdx.x;
  const float* C = (blockIdx.y == 0 ? cost_x : cost_f) + (long)b * N_ * K_;
  const float eps = 1e-3f, ti = 1000.0f;
  const float lgp = -8.317766166719343f;   // -log(4096)
  const float lgq = -4.1588830833596715f;  // -log(64)
  int tid = threadIdx.x;
  for (int i = tid; i < N_; i += 1024) u[i] = 0.f;
  if (tid < 64) v[tid] = 0.f;
  __syncthreads();
  for (int it = 0; it < 25; ++it) {
    // u update (rows, lse over j)
#pragma unroll
    for (int r = 0; r < 4; ++r) {
      int i = tid + r * 1024;
      const float* cr = C + (long)i * 64;
      float ui = u[i];
      float mx = -1e30f;
      for (int j = 0; j < 64; ++j) mx = fmaxf(mx, (ui + v[j] - cr[j]) * ti);
      float s = 0.f;
      for (int j = 0; j < 64; ++j) s += expf((ui + v[j] - cr[j]) * ti - mx);
      u[i] = eps * (lgp - (mx + logf(s))) + ui;
    }
    __syncthreads();
    // v update (cols, lse over i) — 16 partial threads per column
    int j = tid & 63, sub = tid >> 6;
    float vj = v[j];
    float m = -1e30f, s = 0.f;
    for (int r = 0; r < 256; ++r) {
      int i = sub + r * 16;
      float a = (u[i] + vj - C[(long)i * 64 + j]) * ti;
      if (a > m) { s = s * expf(m - a) + 1.f; m = a; }
      else s += expf(a - m);
    }
    pm[tid] = m; ps[tid] = s;
    __syncthreads();
    if (tid < 64) {
      float M = -1e30f;
      for (int sb = 0; sb < 16; ++sb) M = fmaxf(M, pm[sb * 64 + tid]);
      float S = 0.f;
      for (int sb = 0; sb < 16; ++sb) S += ps[sb * 64 + tid] * expf(pm[sb * 64 + tid] - M);
      v[tid] = eps * (lgq - (M + logf(S))) + v[tid];
    }
    __syncthreads();
  }
  // fused loss: -(1/B) * sum_{i,j} gamma_ij * logpT[b,i,j]
  float part = 0.f;
  for (int r = 0; r < 4; ++r) {
    int i = tid + r * 1024;
    const float* cr = C + (long)i * 64;
    const float* lp = logpT + ((long)b * N_ + i) * 64;
    float ui = u[i];
    for (int j = 0; j < 64; ++j)
      part += expf((ui + v[j] - cr[j]) * ti) * lp[j];
  }
  pm[tid] = part;
  __syncthreads();
  for (int s2 = 512; s2 > 0; s2 >>= 1) {
    if (tid < s2) pm[tid] += pm[tid + s2];
    __syncthreads();
  }
  if (tid == 0) atomicAdd(out, -pm[0] / (float)B_);
}

// ---------------- launch ----------------
extern "C" void kernel_launch(void* const* d_in, const int* in_sizes, int n_in,
                              void* d_out, int out_size, void* d_ws, size_t ws_size,
                              hipStream_t stream) {
  const float* feature = (const float*)d_in[0];
  const float* xyz = (const float*)d_in[1];
  const float* w1 = (const float*)d_in[2];
  const float* b1 = (const float*)d_in[3];
  const float* g1 = (const float*)d_in[4];
  const float* be1 = (const float*)d_in[5];
  const float* w2 = (const float*)d_in[6];
  const float* b2 = (const float*)d_in[7];
  const float* g2 = (const float*)d_in[8];
  const float* be2 = (const float*)d_in[9];
  const float* w3 = (const float*)d_in[10];
  const float* b3 = (const float*)d_in[11];
  float* out = (float*)d_out;
  float* ws = (float*)d_ws;

  const long sz_h = (long)B_ * H_ * N_;   // 16,777,216
  const long sz_sc = (long)B_ * N_ * K_;  // 2,097,152
  float* h1 = ws;
  float* h2 = h1 + sz_h;
  // h1 region reused after conv2:
  float* log_score = h1;
  float* scoreT = h1 + sz_sc;
  float* logpT = h1 + 2 * sz_sc;
  float* cost_x = h1 + 3 * sz_sc;
  float* cost_f = h1 + 4 * sz_sc;
  float* sm = h2 + sz_h;
  float* mu_raw = sm; sm += (long)B_ * D_ * K_;
  float* n_mu = sm;   sm += (long)B_ * D_ * K_;
  float* n_muT = sm;  sm += (long)B_ * D_ * K_;
  float* inv_nrm = sm; sm += (long)B_ * N_;
  float* mu_x = sm;   sm += 2048;
  float* yn = sm;     sm += 512;
  float* pi_raw = sm; sm += 512;
  float* pi = sm;     sm += 512;
  float* sc1 = sm; sm += 512;
  float* sh1 = sm; sm += 512;
  float* sc2 = sm; sm += 512;
  float* sh2 = sm; sm += 512;

  hipMemsetAsync(d_out, 0, sizeof(float) * out_size, stream);
  hipMemsetAsync(pi_raw, 0, 512 * sizeof(float), stream);

  // conv1: [512,1024] @ [1024,4096] per batch
  {
    dim3 g(N_ / 128, H_ / 128, B_);
    sgemm128_nn<<<g, 256, 0, stream>>>(w1, feature, h1, b1, H_, N_, D_,
                                       (long)D_ * N_, (long)H_ * N_);
  }
  bn_stats<<<H_, 256, 0, stream>>>(h1, g1, be1, sc1, sh1, H_);
  bn_relu<<<(int)(sz_h / 4 / 256), 256, 0, stream>>>(h1, sc1, sh1, H_);
  // conv2
  {
    dim3 g(N_ / 128, H_ / 128, B_);
    sgemm128_nn<<<g, 256, 0, stream>>>(w2, h1, h2, b2, H_, N_, H_,
                                       (long)H_ * N_, (long)H_ * N_);
  }
  bn_stats<<<H_, 256, 0, stream>>>(h2, g2, be2, sc2, sh2, H_);
  bn_relu<<<(int)(sz_h / 4 / 256), 256, 0, stream>>>(h2, sc2, sh2, H_);
  // conv3: [64,512] @ [512,4096]
  {
    dim3 g(N_ / 64, K_ / 64, B_);
    sgemm64_nn<<<g, 256, 0, stream>>>(w3, h2, log_score, b3, K_, N_, H_, 0L,
                                      (long)H_ * N_, (long)K_ * N_);
  }
  softmax_k<<<B_ * N_ / 256, 256, 0, stream>>>(log_score, scoreT, logpT, pi_raw);
  pi_fin<<<2, 256, 0, stream>>>(pi_raw, pi);
  {
    dim3 g(K_, B_);
    mu_xyz_k<<<g, 64, 0, stream>>>(scoreT, xyz, pi, mu_x, yn);
  }
  reg_xyz_k<<<B_, 256, 0, stream>>>(mu_x, out);
  {
    dim3 g(N_ / 256, B_);
    cost_xyz_k<<<g, 256, 0, stream>>>(xyz, mu_x, yn, cost_x);
  }
  // mu_fea: F[b] [1024,4096] @ scoreT[b] [4096,64]
  {
    dim3 g(K_ / 64, D_ / 64, B_);
    sgemm64_nn<<<g, 256, 0, stream>>>(feature, scoreT, mu_raw, nullptr, D_, K_, N_,
                                      (long)D_ * N_, (long)N_ * K_, (long)D_ * K_);
  }
  {
    dim3 g(K_, B_);
    mu_finalize<<<g, 256, 0, stream>>>(mu_raw, pi, n_mu, n_muT);
  }
  reg_fea_k<<<B_, 256, 0, stream>>>(n_muT, out);
  {
    dim3 g(N_ / 256, B_);
    inv_nrm_k<<<g, 256, 0, stream>>>(feature, inv_nrm);
  }
  {
    dim3 g(N_ / 64, B_);
    cost_fea_gemm<<<g, 256, 0, stream>>>(feature, n_mu, inv_nrm, cost_f);
  }
  {
    dim3 g(B_, 2);
    sinkhorn_loss<<<g, 1024, 0, stream>>>(cost_x, cost_f, logpT, out);
  }
}

// Round 2
// 2770.235 us; speedup vs baseline: 2.2480x; 2.2480x over previous
//
#include <hip/hip_runtime.h>
#include <math.h>

#define B_ 8
#define D_ 1024
#define N_ 4096
#define K_ 64
#define H_ 512

// ---------------- helpers ----------------
__device__ __forceinline__ float block_reduce_sum256(float v, float* sm) {
  int tid = threadIdx.x;
  sm[tid] = v;
  __syncthreads();
  for (int s = 128; s > 0; s >>= 1) {
    if (tid < s) sm[tid] += sm[tid + s];
    __syncthreads();
  }
  float r = sm[0];
  __syncthreads();
  return r;
}

// ---------------- 128x128x8 NN SGEMM (C[b] = A @ B[b] + bias) ----------------
__global__ __launch_bounds__(256)
void sgemm128_nn(const float* __restrict__ A, const float* __restrict__ Bm,
                 float* __restrict__ C, const float* __restrict__ bias,
                 int M, int N, int Kd, long sB, long sC) {
  __shared__ float As[8][128];
  __shared__ float Bs[8][128];
  const float* Bp = Bm + (long)blockIdx.z * sB;
  float* Cp = C + (long)blockIdx.z * sC;
  int m0 = blockIdx.y * 128, n0 = blockIdx.x * 128;
  int tid = threadIdx.x;
  int tx = tid & 15, ty = tid >> 4;
  int arow = tid >> 1, acol = (tid & 1) * 4;
  int brow = tid >> 5, bcol = (tid & 31) * 4;
  float acc[8][8];
#pragma unroll
  for (int i = 0; i < 8; ++i)
#pragma unroll
    for (int j = 0; j < 8; ++j) acc[i][j] = 0.f;

  for (int k0 = 0; k0 < Kd; k0 += 8) {
    float4 av = *(const float4*)(A + (long)(m0 + arow) * Kd + k0 + acol);
    float4 bv = *(const float4*)(Bp + (long)(k0 + brow) * N + n0 + bcol);
    __syncthreads();
    As[acol + 0][arow] = av.x;
    As[acol + 1][arow] = av.y;
    As[acol + 2][arow] = av.z;
    As[acol + 3][arow] = av.w;
    *(float4*)&Bs[brow][bcol] = bv;
    __syncthreads();
#pragma unroll
    for (int kk = 0; kk < 8; ++kk) {
      float4 a0 = *(const float4*)&As[kk][ty * 8];
      float4 a1 = *(const float4*)&As[kk][ty * 8 + 4];
      float4 b0 = *(const float4*)&Bs[kk][tx * 8];
      float4 b1 = *(const float4*)&Bs[kk][tx * 8 + 4];
      float am[8] = {a0.x, a0.y, a0.z, a0.w, a1.x, a1.y, a1.z, a1.w};
      float bn[8] = {b0.x, b0.y, b0.z, b0.w, b1.x, b1.y, b1.z, b1.w};
#pragma unroll
      for (int i = 0; i < 8; ++i)
#pragma unroll
        for (int j = 0; j < 8; ++j) acc[i][j] += am[i] * bn[j];
    }
  }
#pragma unroll
  for (int i = 0; i < 8; ++i) {
    int m = m0 + ty * 8 + i;
    float bb = bias ? bias[m] : 0.f;
    float4 o0, o1;
    o0.x = acc[i][0] + bb; o0.y = acc[i][1] + bb; o0.z = acc[i][2] + bb; o0.w = acc[i][3] + bb;
    o1.x = acc[i][4] + bb; o1.y = acc[i][5] + bb; o1.z = acc[i][6] + bb; o1.w = acc[i][7] + bb;
    *(float4*)(Cp + (long)m * N + n0 + tx * 8) = o0;
    *(float4*)(Cp + (long)m * N + n0 + tx * 8 + 4) = o1;
  }
}

// ---------------- 64x64x16 NN SGEMM ----------------
__global__ __launch_bounds__(256)
void sgemm64_nn(const float* __restrict__ A, const float* __restrict__ Bm,
                float* __restrict__ C, const float* __restrict__ bias,
                int M, int N, int Kd, long sA, long sB, long sC) {
  __shared__ float As[16][64];
  __shared__ float Bs[16][64];
  const float* Ap = A + (long)blockIdx.z * sA;
  const float* Bp = Bm + (long)blockIdx.z * sB;
  float* Cp = C + (long)blockIdx.z * sC;
  int m0 = blockIdx.y * 64, n0 = blockIdx.x * 64;
  int tid = threadIdx.x;
  int tx = tid & 15, ty = tid >> 4;
  int arow = tid >> 2, acol = (tid & 3) * 4;
  int brow = tid >> 4, bcol = (tid & 15) * 4;
  float acc[4][4];
#pragma unroll
  for (int i = 0; i < 4; ++i)
#pragma unroll
    for (int j = 0; j < 4; ++j) acc[i][j] = 0.f;

  for (int k0 = 0; k0 < Kd; k0 += 16) {
    float4 av = *(const float4*)(Ap + (long)(m0 + arow) * Kd + k0 + acol);
    float4 bv = *(const float4*)(Bp + (long)(k0 + brow) * N + n0 + bcol);
    __syncthreads();
    As[acol + 0][arow] = av.x;
    As[acol + 1][arow] = av.y;
    As[acol + 2][arow] = av.z;
    As[acol + 3][arow] = av.w;
    *(float4*)&Bs[brow][bcol] = bv;
    __syncthreads();
#pragma unroll
    for (int kk = 0; kk < 16; ++kk) {
      float4 a = *(const float4*)&As[kk][ty * 4];
      float4 bq = *(const float4*)&Bs[kk][tx * 4];
      float am[4] = {a.x, a.y, a.z, a.w};
      float bn[4] = {bq.x, bq.y, bq.z, bq.w};
#pragma unroll
      for (int i = 0; i < 4; ++i)
#pragma unroll
        for (int j = 0; j < 4; ++j) acc[i][j] += am[i] * bn[j];
    }
  }
#pragma unroll
  for (int i = 0; i < 4; ++i) {
    int m = m0 + ty * 4 + i;
    float bb = bias ? bias[m] : 0.f;
    float4 o;
    o.x = acc[i][0] + bb; o.y = acc[i][1] + bb; o.z = acc[i][2] + bb; o.w = acc[i][3] + bb;
    *(float4*)(Cp + (long)m * N + n0 + tx * 4) = o;
  }
}

// ---------------- BN stats ----------------
__global__ __launch_bounds__(256)
void bn_stats(const float* __restrict__ Y, const float* __restrict__ g,
              const float* __restrict__ be, float* __restrict__ scale,
              float* __restrict__ shift, int C) {
  int c = blockIdx.x;
  double s1 = 0.0, s2 = 0.0;
  for (int idx = threadIdx.x; idx < B_ * N_; idx += 256) {
    int b = idx >> 12, n = idx & (N_ - 1);
    float v = Y[((long)b * C + c) * N_ + n];
    s1 += v;
    s2 += (double)v * (double)v;
  }
  __shared__ double r1[256], r2[256];
  int tid = threadIdx.x;
  r1[tid] = s1; r2[tid] = s2;
  __syncthreads();
  for (int s = 128; s > 0; s >>= 1) {
    if (tid < s) { r1[tid] += r1[tid + s]; r2[tid] += r2[tid + s]; }
    __syncthreads();
  }
  if (tid == 0) {
    double m = r1[0] / (double)(B_ * N_);
    double var = r2[0] / (double)(B_ * N_) - m * m;
    float sc = (float)((double)g[c] / sqrt(var + 1e-5));
    scale[c] = sc;
    shift[c] = (float)((double)be[c] - m * (double)sc);
  }
}

__global__ __launch_bounds__(256)
void bn_relu(float* __restrict__ Y, const float* __restrict__ scale,
             const float* __restrict__ shift, int C) {
  long i4 = (long)blockIdx.x * 256 + threadIdx.x;
  long i = i4 * 4;
  int c = (int)((i >> 12) % C);
  float sc = scale[c], sh = shift[c];
  float4 v = *(float4*)(Y + i);
  v.x = fmaxf(v.x * sc + sh, 0.f);
  v.y = fmaxf(v.y * sc + sh, 0.f);
  v.z = fmaxf(v.z * sc + sh, 0.f);
  v.w = fmaxf(v.w * sc + sh, 0.f);
  *(float4*)(Y + i) = v;
}

// ---------------- softmax over K; scoreT [b][n][K], logp [b][K][N] ----------------
__global__ __launch_bounds__(256)
void softmax_k(const float* __restrict__ ls, float* __restrict__ scoreT,
               float* __restrict__ logpKN, float* __restrict__ pi_raw) {
  __shared__ float ploc[64];
  int tid = threadIdx.x;
  if (tid < 64) ploc[tid] = 0.f;
  __syncthreads();
  long gid = (long)blockIdx.x * 256 + tid;
  int b = (int)(gid >> 12);
  int n = (int)(gid & (N_ - 1));
  const float* x = ls + ((long)b * K_) * N_ + n;
  float mx = -1e30f;
  for (int k = 0; k < 64; ++k) mx = fmaxf(mx, x[(long)k * N_]);
  float s = 0.f;
  for (int k = 0; k < 64; ++k) s += expf(x[(long)k * N_] - mx);
  float lg = logf(s);
  float inv = 1.f / s;
  float* st = scoreT + gid * 64;
  float* lp = logpKN + ((long)b * K_) * N_ + n;
  for (int k = 0; k < 64; ++k) {
    float xv = x[(long)k * N_] - mx;
    float e = expf(xv);
    float sc = e * inv;
    st[k] = sc;
    lp[(long)k * N_] = xv - lg;
    atomicAdd(&ploc[k], sc);
  }
  __syncthreads();
  if (tid < 64) atomicAdd(&pi_raw[b * 64 + tid], ploc[tid]);
}

__global__ void pi_fin(const float* __restrict__ pr, float* __restrict__ pi) {
  int i = blockIdx.x * 256 + threadIdx.x;
  if (i < B_ * K_) pi[i] = fmaxf(pr[i], 1e-4f);
}

// ---------------- mu_xyz ----------------
__global__ __launch_bounds__(64)
void mu_xyz_k(const float* __restrict__ scoreT, const float* __restrict__ xyz,
              const float* __restrict__ pi, float* __restrict__ mu, float* __restrict__ yn) {
  int k = blockIdx.x, b = blockIdx.y, t = threadIdx.x;
  const float* st = scoreT + ((long)b * N_) * K_ + k;
  const float* xp = xyz + (long)b * 3 * N_;
  float a0 = 0, a1 = 0, a2 = 0;
  for (int n = t; n < N_; n += 64) {
    float s = st[(long)n * K_];
    a0 += s * xp[n];
    a1 += s * xp[N_ + n];
    a2 += s * xp[2 * N_ + n];
  }
  for (int off = 32; off > 0; off >>= 1) {
    a0 += __shfl_down(a0, off);
    a1 += __shfl_down(a1, off);
    a2 += __shfl_down(a2, off);
  }
  if (t == 0) {
    float p = pi[b * K_ + k];
    float m0 = a0 / p, m1 = a1 / p, m2 = a2 / p;
    mu[((long)b * 3 + 0) * K_ + k] = m0;
    mu[((long)b * 3 + 1) * K_ + k] = m1;
    mu[((long)b * 3 + 2) * K_ + k] = m2;
    yn[b * K_ + k] = m0 * m0 + m1 * m1 + m2 * m2;
  }
}

// ---------------- regularizers ----------------
__global__ __launch_bounds__(256)
void reg_xyz_k(const float* __restrict__ mu, float* __restrict__ out) {
  __shared__ float red[256];
  int b = blockIdx.x, tid = threadIdx.x;
  float acc = 0.f;
  for (int e = tid; e < 4096; e += 256) {
    int m = e >> 6, n2 = e & 63;
    float g = 0.f;
    for (int d = 0; d < 3; ++d)
      g += mu[((long)b * 3 + d) * K_ + m] * mu[((long)b * 3 + d) * K_ + n2];
    acc += fabsf(g - (m == n2 ? 1.f : 0.f));
  }
  float tot = block_reduce_sum256(acc, red);
  if (tid == 0) atomicAdd(out, tot * (1e-7f / 32768.f));
}

__global__ __launch_bounds__(256)
void reg_fea_k(const float* __restrict__ nT, float* __restrict__ out) {
  __shared__ float red[256];
  int b = blockIdx.x, tid = threadIdx.x;
  float acc = 0.f;
  for (int e = tid; e < 4096; e += 256) {
    int m = e >> 6, n2 = e & 63;
    const float* pm_ = nT + ((long)b * K_ + m) * D_;
    const float* pn_ = nT + ((long)b * K_ + n2) * D_;
    float g0 = 0, g1 = 0, g2 = 0, g3 = 0;
    for (int d = 0; d < D_; d += 4) {
      g0 += pm_[d] * pn_[d];
      g1 += pm_[d + 1] * pn_[d + 1];
      g2 += pm_[d + 2] * pn_[d + 2];
      g3 += pm_[d + 3] * pn_[d + 3];
    }
    float g = (g0 + g1) + (g2 + g3);
    acc += fabsf(g - (m == n2 ? 1.f : 0.f));
  }
  float tot = block_reduce_sum256(acc, red);
  if (tid == 0) atomicAdd(out, tot * (1e-4f / 32768.f));
}

// ---------------- cost_xyz -> [b][K][N] ----------------
__global__ __launch_bounds__(256)
void cost_xyz_k(const float* __restrict__ xyz, const float* __restrict__ mu,
                const float* __restrict__ yn, float* __restrict__ cost) {
  __shared__ float m0s[64], m1s[64], m2s[64], yl[64];
  int b = blockIdx.y;
  int tid = threadIdx.x;
  if (tid < 64) {
    m0s[tid] = mu[((long)b * 3 + 0) * K_ + tid];
    m1s[tid] = mu[((long)b * 3 + 1) * K_ + tid];
    m2s[tid] = mu[((long)b * 3 + 2) * K_ + tid];
    yl[tid] = yn[b * K_ + tid];
  }
  __syncthreads();
  int n = blockIdx.x * 256 + tid;
  const float* xp = xyz + (long)b * 3 * N_;
  float x0 = xp[n], x1 = xp[N_ + n], x2 = xp[2 * N_ + n];
  float xn = x0 * x0 + x1 * x1 + x2 * x2;
  float* cb = cost + ((long)b * K_) * N_ + n;
  for (int m = 0; m < 64; ++m)
    cb[(long)m * N_] = xn + yl[m] - 2.f * (x0 * m0s[m] + x1 * m1s[m] + x2 * m2s[m]);
}

// ---------------- mu_fea finalize: /pi then normalize -> n_muT [b][K][D] ----------------
__global__ __launch_bounds__(256)
void mu_finalize(const float* __restrict__ mu_raw, const float* __restrict__ pi,
                 float* __restrict__ n_muT) {
  __shared__ float red[256];
  int k = blockIdx.x, b = blockIdx.y, tid = threadIdx.x;
  float p = pi[b * K_ + k];
  float ss = 0.f;
  for (int d = tid; d < D_; d += 256) {
    float v = mu_raw[((long)b * D_ + d) * K_ + k] / p;
    ss += v * v;
  }
  float tot = block_reduce_sum256(ss, red);
  float inv = 1.f / fmaxf(sqrtf(tot), 1e-12f);
  for (int d = tid; d < D_; d += 256) {
    float v = mu_raw[((long)b * D_ + d) * K_ + k] / p * inv;
    n_muT[((long)b * K_ + k) * D_ + d] = v;
  }
}

// ---------------- feature inverse norms ----------------
__global__ __launch_bounds__(256)
void inv_nrm_k(const float* __restrict__ F, float* __restrict__ invn) {
  int b = blockIdx.y;
  int n = blockIdx.x * 256 + threadIdx.x;
  const float* f = F + (long)b * D_ * N_ + n;
  float s0 = 0, s1 = 0, s2 = 0, s3 = 0;
  for (int d = 0; d < D_; d += 4) {
    float v0 = f[(long)d * N_], v1 = f[(long)(d + 1) * N_];
    float v2 = f[(long)(d + 2) * N_], v3 = f[(long)(d + 3) * N_];
    s0 += v0 * v0; s1 += v1 * v1; s2 += v2 * v2; s3 += v3 * v3;
  }
  float ss = (s0 + s1) + (s2 + s3);
  invn[b * N_ + n] = 1.f / fmaxf(sqrtf(ss), 1e-12f);
}

// ---------------- cost_fea: [K][N] = 2 - 2 * (n_muT @ F) * invn[n] ----------------
__global__ __launch_bounds__(256)
void cost_fea_kn(const float* __restrict__ nmuT, const float* __restrict__ F,
                 const float* __restrict__ invn, float* __restrict__ cost) {
  __shared__ float As[16][64];
  __shared__ float Bs[16][64];
  int b = blockIdx.z;
  int n0 = blockIdx.x * 64;
  const float* Ap = nmuT + (long)b * K_ * D_;
  const float* Bp = F + (long)b * D_ * N_;
  float* Cp = cost + (long)b * K_ * N_;
  int tid = threadIdx.x;
  int tx = tid & 15, ty = tid >> 4;
  int arow = tid >> 2, acol = (tid & 3) * 4;
  int brow = tid >> 4, bcol = (tid & 15) * 4;
  float acc[4][4];
#pragma unroll
  for (int i = 0; i < 4; ++i)
#pragma unroll
    for (int j = 0; j < 4; ++j) acc[i][j] = 0.f;

  for (int k0 = 0; k0 < D_; k0 += 16) {
    float4 av = *(const float4*)(Ap + (long)arow * D_ + k0 + acol);
    float4 bv = *(const float4*)(Bp + (long)(k0 + brow) * N_ + n0 + bcol);
    __syncthreads();
    As[acol + 0][arow] = av.x;
    As[acol + 1][arow] = av.y;
    As[acol + 2][arow] = av.z;
    As[acol + 3][arow] = av.w;
    *(float4*)&Bs[brow][bcol] = bv;
    __syncthreads();
#pragma unroll
    for (int kk = 0; kk < 16; ++kk) {
      float4 a = *(const float4*)&As[kk][ty * 4];
      float4 bq = *(const float4*)&Bs[kk][tx * 4];
      float am[4] = {a.x, a.y, a.z, a.w};
      float bn[4] = {bq.x, bq.y, bq.z, bq.w};
#pragma unroll
      for (int i = 0; i < 4; ++i)
#pragma unroll
        for (int j = 0; j < 4; ++j) acc[i][j] += am[i] * bn[j];
    }
  }
  float4 ivn = *(const float4*)(invn + (long)b * N_ + n0 + tx * 4);
#pragma unroll
  for (int i = 0; i < 4; ++i) {
    int m = ty * 4 + i;  // cluster row
    float4 o;
    o.x = 2.f - 2.f * acc[i][0] * ivn.x;
    o.y = 2.f - 2.f * acc[i][1] * ivn.y;
    o.z = 2.f - 2.f * acc[i][2] * ivn.z;
    o.w = 2.f - 2.f * acc[i][3] * ivn.w;
    *(float4*)(Cp + (long)m * N_ + n0 + tx * 4) = o;
  }
}

// ---------------- cooperative Sinkhorn: 16 groups x 16 slices x 256 rows ----------------
// costAll: [16][K][N] (cost_x batches 0..7, then cost_f batches 0..7)
__global__ __launch_bounds__(256, 1)
void sinkhorn_coop(const float* __restrict__ costAll, const float* __restrict__ logpKN,
                   float* __restrict__ out, float* __restrict__ partM,
                   float* __restrict__ partS, unsigned int* __restrict__ cnt) {
  __shared__ float tile[4][64][33];
  __shared__ float vsh[64];
  __shared__ float wm[4][64];
  __shared__ float wsum[4][64];
  __shared__ float red[256];
  const int tid = threadIdx.x;
  const int g = blockIdx.x & 15;   // group: branch*8 + batch
  const int s = blockIdx.x >> 4;   // slice within group
  const int w = tid >> 6, lane = tid & 63;
  const int i = s * 256 + tid;     // my row (point index)
  const float* C = costAll + (long)g * K_ * N_;
  const float eps = 1e-3f, ti = 1000.0f;
  const float lgp = -8.317766166719343f;   // -log(4096)
  const float lgq = -4.1588830833596715f;  // -log(64)

  // cache my cost row in registers (read from HBM exactly once)
  float c[64];
#pragma unroll
  for (int j = 0; j < 64; ++j) c[j] = C[(long)j * N_ + i];

  float u = 0.f;
  if (tid < 64) vsh[tid] = 0.f;
  __syncthreads();

  for (int it = 0; it < 25; ++it) {
    // ---- u-update: max-shifted LSE over 64 clusters, all in regs/LDS-broadcast
    float dm = -1e30f;
#pragma unroll
    for (int j = 0; j < 64; ++j) dm = fmaxf(dm, vsh[j] - c[j]);
    float ssum = 0.f;
#pragma unroll
    for (int j = 0; j < 64; ++j) ssum += __expf((vsh[j] - c[j] - dm) * ti);
    float lse = (u + dm) * ti + __logf(ssum);
    u = eps * (lgp - lse) + u;

    // ---- column partials via per-wave LDS transpose (two 32-col halves)
    // after u-update each exp((u+v-c)/eps) <= exp(lgp): plain-sum scaled by e^{-lgp} is safe
    float Mcol = -1e30f, Scol = 0.f;  // valid in lanes where rh==0 at the end
#pragma unroll
    for (int h = 0; h < 2; ++h) {
#pragma unroll
      for (int j2 = 0; j2 < 32; ++j2) {
        int j = h * 32 + j2;
        tile[w][lane][j2] = (u + vsh[j] - c[j]) * ti;
      }
      __syncthreads();
      int col = lane & 31, rh = lane >> 5;
      float Mh = -1e30f, Sh = 0.f;
#pragma unroll
      for (int r = 0; r < 32; ++r) {
        float a = tile[w][rh * 32 + r][col];
        Mh = fmaxf(Mh, a);
        Sh += __expf(a - lgp);
      }
      float Mo = __shfl_xor(Mh, 32);
      float So = __shfl_xor(Sh, 32);
      Mh = fmaxf(Mh, Mo);
      Sh += So;
      if (rh == 0) { wm[w][h * 32 + col] = Mh; wsum[w][h * 32 + col] = Sh; }
      __syncthreads();
    }
    (void)Mcol; (void)Scol;
    // ---- block merge + write global partials (double-buffered)
    int buf = it & 1;
    if (tid < 64) {
      float Mb = fmaxf(fmaxf(wm[0][tid], wm[1][tid]), fmaxf(wm[2][tid], wm[3][tid]));
      float Sb = wsum[0][tid] + wsum[1][tid] + wsum[2][tid] + wsum[3][tid];
      long idx = (((long)buf * 16 + g) * 64 + tid) * 16 + s;
      partM[idx] = Mb;
      partS[idx] = Sb;
    }
    __syncthreads();
    // ---- group barrier (device-scope, monotonic counter)
    if (tid == 0) {
      __threadfence();
      __hip_atomic_fetch_add(&cnt[g], 1u, __ATOMIC_ACQ_REL, __HIP_MEMORY_SCOPE_AGENT);
      unsigned target = 16u * (unsigned)(it + 1);
      while (__hip_atomic_load(&cnt[g], __ATOMIC_ACQUIRE, __HIP_MEMORY_SCOPE_AGENT) < target)
        __builtin_amdgcn_s_sleep(1);
      __threadfence();
    }
    __syncthreads();
    // ---- v-update (redundant per block; deterministic, identical across blocks)
    if (tid < 64) {
      long base = (((long)buf * 16 + g) * 64 + tid) * 16;
      float M = -1e30f, S = 0.f;
#pragma unroll
      for (int p = 0; p < 16; ++p) {
        M = fmaxf(M, partM[base + p]);
        S += partS[base + p];
      }
      float lsec = fmaxf(M, lgp + __logf(S));
      vsh[tid] = eps * (lgq - lsec) + vsh[tid];
    }
    __syncthreads();
  }

  // ---- fused loss: -(1/B) * sum_j gamma_ij * logp[j][i]
  const float* lp = logpKN + ((long)(g & 7) * K_) * N_ + i;
  float part = 0.f;
#pragma unroll
  for (int j = 0; j < 64; ++j) {
    float gma = __expf((u + vsh[j] - c[j]) * ti);
    part += gma * lp[(long)j * N_];
  }
  red[tid] = part;
  __syncthreads();
  for (int st2 = 128; st2 > 0; st2 >>= 1) {
    if (tid < st2) red[tid] += red[tid + st2];
    __syncthreads();
  }
  if (tid == 0) atomicAdd(out, -red[0] / (float)B_);
}

// ---------------- launch ----------------
extern "C" void kernel_launch(void* const* d_in, const int* in_sizes, int n_in,
                              void* d_out, int out_size, void* d_ws, size_t ws_size,
                              hipStream_t stream) {
  const float* feature = (const float*)d_in[0];
  const float* xyz = (const float*)d_in[1];
  const float* w1 = (const float*)d_in[2];
  const float* b1 = (const float*)d_in[3];
  const float* g1 = (const float*)d_in[4];
  const float* be1 = (const float*)d_in[5];
  const float* w2 = (const float*)d_in[6];
  const float* b2 = (const float*)d_in[7];
  const float* g2 = (const float*)d_in[8];
  const float* be2 = (const float*)d_in[9];
  const float* w3 = (const float*)d_in[10];
  const float* b3 = (const float*)d_in[11];
  float* out = (float*)d_out;
  float* ws = (float*)d_ws;

  const long sz_h = (long)B_ * H_ * N_;   // 16,777,216
  const long sz_sc = (long)B_ * N_ * K_;  // 2,097,152
  float* h1 = ws;
  float* h2 = h1 + sz_h;
  // h1 region reused after conv2:
  float* log_score = h1;
  float* scoreT = h1 + sz_sc;
  float* logpKN = h1 + 2 * sz_sc;
  float* cost_x = h1 + 3 * sz_sc;  // [8][K][N]
  float* cost_f = h1 + 4 * sz_sc;  // [8][K][N], contiguous after cost_x
  float* sm = h2 + sz_h;
  float* mu_raw = sm; sm += (long)B_ * D_ * K_;
  float* n_muT = sm;  sm += (long)B_ * D_ * K_;
  float* partM = sm;  sm += 2 * 16 * 64 * 16;
  float* partS = sm;  sm += 2 * 16 * 64 * 16;
  unsigned int* cnt = (unsigned int*)sm; sm += 16;
  float* inv_nrm = sm; sm += (long)B_ * N_;
  float* mu_x = sm;   sm += 2048;
  float* yn = sm;     sm += 512;
  float* pi_raw = sm; sm += 512;
  float* pi = sm;     sm += 512;
  float* sc1 = sm; sm += 512;
  float* sh1 = sm; sm += 512;
  float* sc2 = sm; sm += 512;
  float* sh2 = sm; sm += 512;

  hipMemsetAsync(d_out, 0, sizeof(float) * out_size, stream);
  hipMemsetAsync(pi_raw, 0, 512 * sizeof(float), stream);
  hipMemsetAsync(cnt, 0, 16 * sizeof(unsigned int), stream);

  // conv1
  {
    dim3 g(N_ / 128, H_ / 128, B_);
    sgemm128_nn<<<g, 256, 0, stream>>>(w1, feature, h1, b1, H_, N_, D_,
                                       (long)D_ * N_, (long)H_ * N_);
  }
  bn_stats<<<H_, 256, 0, stream>>>(h1, g1, be1, sc1, sh1, H_);
  bn_relu<<<(int)(sz_h / 4 / 256), 256, 0, stream>>>(h1, sc1, sh1, H_);
  // conv2
  {
    dim3 g(N_ / 128, H_ / 128, B_);
    sgemm128_nn<<<g, 256, 0, stream>>>(w2, h1, h2, b2, H_, N_, H_,
                                       (long)H_ * N_, (long)H_ * N_);
  }
  bn_stats<<<H_, 256, 0, stream>>>(h2, g2, be2, sc2, sh2, H_);
  bn_relu<<<(int)(sz_h / 4 / 256), 256, 0, stream>>>(h2, sc2, sh2, H_);
  // conv3
  {
    dim3 g(N_ / 64, K_ / 64, B_);
    sgemm64_nn<<<g, 256, 0, stream>>>(w3, h2, log_score, b3, K_, N_, H_, 0L,
                                      (long)H_ * N_, (long)K_ * N_);
  }
  softmax_k<<<B_ * N_ / 256, 256, 0, stream>>>(log_score, scoreT, logpKN, pi_raw);
  pi_fin<<<2, 256, 0, stream>>>(pi_raw, pi);
  {
    dim3 g(K_, B_);
    mu_xyz_k<<<g, 64, 0, stream>>>(scoreT, xyz, pi, mu_x, yn);
  }
  reg_xyz_k<<<B_, 256, 0, stream>>>(mu_x, out);
  {
    dim3 g(N_ / 256, B_);
    cost_xyz_k<<<g, 256, 0, stream>>>(xyz, mu_x, yn, cost_x);
  }
  // mu_fea
  {
    dim3 g(K_ / 64, D_ / 64, B_);
    sgemm64_nn<<<g, 256, 0, stream>>>(feature, scoreT, mu_raw, nullptr, D_, K_, N_,
                                      (long)D_ * N_, (long)N_ * K_, (long)D_ * K_);
  }
  {
    dim3 g(K_, B_);
    mu_finalize<<<g, 256, 0, stream>>>(mu_raw, pi, n_muT);
  }
  reg_fea_k<<<B_, 256, 0, stream>>>(n_muT, out);
  {
    dim3 g(N_ / 256, B_);
    inv_nrm_k<<<g, 256, 0, stream>>>(feature, inv_nrm);
  }
  {
    dim3 g(N_ / 64, 1, B_);
    cost_fea_kn<<<g, 256, 0, stream>>>(n_muT, feature, inv_nrm, cost_f);
  }
  // cooperative Sinkhorn + fused loss (both branches, all batches, one launch)
  {
    void* kargs[] = {(void*)&cost_x, (void*)&logpKN, (void*)&out,
                     (void*)&partM, (void*)&partS, (void*)&cnt};
    hipLaunchCooperativeKernel((const void*)sinkhorn_coop, dim3(256), dim3(256),
                               kargs, 0, stream);
  }
}

// Round 3
// 2076.618 us; speedup vs baseline: 2.9989x; 1.3340x over previous
//
#include <hip/hip_runtime.h>
#include <math.h>

#define B_ 8
#define D_ 1024
#define N_ 4096
#define K_ 64
#define H_ 512

typedef short sx8 __attribute__((ext_vector_type(8)));
typedef float fx4 __attribute__((ext_vector_type(4)));

// ---------------- helpers ----------------
__device__ __forceinline__ float block_reduce_sum256(float v, float* sm) {
  int tid = threadIdx.x;
  sm[tid] = v;
  __syncthreads();
  for (int s = 128; s > 0; s >>= 1) {
    if (tid < s) sm[tid] += sm[tid + s];
    __syncthreads();
  }
  float r = sm[0];
  __syncthreads();
  return r;
}

__device__ __forceinline__ ushort f2bf(float f) {
  unsigned u = __float_as_uint(f);
  unsigned r = (u + 0x7fffu + ((u >> 16) & 1u)) >> 16;
  return (ushort)r;
}
__device__ __forceinline__ float bf2f(ushort h) {
  return __uint_as_float(((unsigned)h) << 16);
}

// ---------------- weight split: f32 -> bf16 hi/lo ----------------
__global__ __launch_bounds__(256)
void split_w(const float* __restrict__ W, ushort* __restrict__ Wh,
             ushort* __restrict__ Wl, int n) {
  int i = blockIdx.x * 256 + threadIdx.x;
  if (i < n) {
    float f = W[i];
    ushort h = f2bf(f);
    Wh[i] = h;
    Wl[i] = f2bf(f - bf2f(h));
  }
}

// ---------------- feature transpose+split: [B][D][N] f32 -> [B][N][D] bf16 hi/lo ----
__global__ __launch_bounds__(256)
void transpose_split(const float* __restrict__ F, ushort* __restrict__ FhT,
                     ushort* __restrict__ FlT) {
  __shared__ float tile[64][65];
  int b = blockIdx.z, d0 = blockIdx.y * 64, n0 = blockIdx.x * 64;
  const float* src = F + ((long)b * D_ + d0) * N_ + n0;
  int t = threadIdx.x;
  int rr4 = t >> 4, c4 = (t & 15) * 4;
#pragma unroll
  for (int p = 0; p < 4; ++p) {
    int dr = p * 16 + rr4;
    float4 v = *(const float4*)(src + (long)dr * N_ + c4);
    tile[dr][c4 + 0] = v.x;
    tile[dr][c4 + 1] = v.y;
    tile[dr][c4 + 2] = v.z;
    tile[dr][c4 + 3] = v.w;
  }
  __syncthreads();
  int nlb = t >> 3, ds = (t & 7) * 8;
#pragma unroll
  for (int p = 0; p < 2; ++p) {
    int nl = p * 32 + nlb;
    sx8 hv, lv;
#pragma unroll
    for (int j = 0; j < 8; ++j) {
      float f = tile[ds + j][nl];
      ushort h = f2bf(f);
      hv[j] = (short)h;
      lv[j] = (short)f2bf(f - bf2f(h));
    }
    long o = ((long)b * N_ + n0 + nl) * D_ + d0 + ds;
    *(sx8*)(FhT + o) = hv;
    *(sx8*)(FlT + o) = lv;
  }
}

// ---------------- split-bf16 MFMA GEMM: C[b][M][N] = A[M][Kd] * B[b][Kd][N] + bias ----
// A given as bf16 hi/lo [M][Kd]; B given TRANSPOSED bf16 hi/lo [b][N][Kd].
__global__ __launch_bounds__(256)
void gemm_split_bf16(const ushort* __restrict__ Ah, const ushort* __restrict__ Al,
                     const ushort* __restrict__ BhT, const ushort* __restrict__ BlT,
                     float* __restrict__ C, const float* __restrict__ bias,
                     int N, int Kd, long sBT, long sC) {
  __shared__ ushort As[2][128][40];
  __shared__ ushort Bs[2][128][40];
  const int t = threadIdx.x;
  const int m0 = blockIdx.y * 128, n0 = blockIdx.x * 128;
  const long bo = (long)blockIdx.z * sBT;
  float* Cp = C + (long)blockIdx.z * sC;
  const int half = t >> 7, r = t & 127;
  const ushort* Asrc = (half ? Al : Ah) + (long)(m0 + r) * Kd;
  const ushort* Bsrc = (half ? BlT : BhT) + bo + (long)(n0 + r) * Kd;
  ushort* AsD = &As[half][r][0];
  ushort* BsD = &Bs[half][r][0];
  const int w = t >> 6, ln = t & 15, qd = (t & 63) >> 4;
  const int wm = w >> 1, wn = w & 1;

  fx4 acc[4][4];
#pragma unroll
  for (int i = 0; i < 4; ++i)
#pragma unroll
    for (int j = 0; j < 4; ++j) acc[i][j] = (fx4)0.f;

  for (int k0 = 0; k0 < Kd; k0 += 32) {
    uint4 a0 = *(const uint4*)(Asrc + k0);
    uint4 a1 = *(const uint4*)(Asrc + k0 + 8);
    uint4 a2 = *(const uint4*)(Asrc + k0 + 16);
    uint4 a3 = *(const uint4*)(Asrc + k0 + 24);
    uint4 b0 = *(const uint4*)(Bsrc + k0);
    uint4 b1 = *(const uint4*)(Bsrc + k0 + 8);
    uint4 b2 = *(const uint4*)(Bsrc + k0 + 16);
    uint4 b3 = *(const uint4*)(Bsrc + k0 + 24);
    __syncthreads();
    *(uint4*)(AsD + 0) = a0;
    *(uint4*)(AsD + 8) = a1;
    *(uint4*)(AsD + 16) = a2;
    *(uint4*)(AsD + 24) = a3;
    *(uint4*)(BsD + 0) = b0;
    *(uint4*)(BsD + 8) = b1;
    *(uint4*)(BsD + 16) = b2;
    *(uint4*)(BsD + 24) = b3;
    __syncthreads();
    sx8 ahf[4], alf[4], bhf[4], blf[4];
#pragma unroll
    for (int mt = 0; mt < 4; ++mt) {
      ahf[mt] = *(const sx8*)&As[0][wm * 64 + mt * 16 + ln][qd * 8];
      alf[mt] = *(const sx8*)&As[1][wm * 64 + mt * 16 + ln][qd * 8];
    }
#pragma unroll
    for (int nt = 0; nt < 4; ++nt) {
      bhf[nt] = *(const sx8*)&Bs[0][wn * 64 + nt * 16 + ln][qd * 8];
      blf[nt] = *(const sx8*)&Bs[1][wn * 64 + nt * 16 + ln][qd * 8];
    }
#pragma unroll
    for (int mt = 0; mt < 4; ++mt)
#pragma unroll
      for (int nt = 0; nt < 4; ++nt) {
        acc[mt][nt] = __builtin_amdgcn_mfma_f32_16x16x32_bf16(ahf[mt], bhf[nt], acc[mt][nt], 0, 0, 0);
        acc[mt][nt] = __builtin_amdgcn_mfma_f32_16x16x32_bf16(alf[mt], bhf[nt], acc[mt][nt], 0, 0, 0);
        acc[mt][nt] = __builtin_amdgcn_mfma_f32_16x16x32_bf16(ahf[mt], blf[nt], acc[mt][nt], 0, 0, 0);
      }
  }
#pragma unroll
  for (int mt = 0; mt < 4; ++mt) {
#pragma unroll
    for (int rr = 0; rr < 4; ++rr) {
      int row = m0 + wm * 64 + mt * 16 + qd * 4 + rr;
      float bb = bias[row];
#pragma unroll
      for (int nt = 0; nt < 4; ++nt) {
        int col = n0 + wn * 64 + nt * 16 + ln;
        Cp[(long)row * N + col] = acc[mt][nt][rr] + bb;
      }
    }
  }
}

// ---------------- 64x64x16 NN SGEMM (f32; conv3 + mu_fea) ----------------
__global__ __launch_bounds__(256)
void sgemm64_nn(const float* __restrict__ A, const float* __restrict__ Bm,
                float* __restrict__ C, const float* __restrict__ bias,
                int M, int N, int Kd, long sA, long sB, long sC) {
  __shared__ float As[16][64];
  __shared__ float Bs[16][64];
  const float* Ap = A + (long)blockIdx.z * sA;
  const float* Bp = Bm + (long)blockIdx.z * sB;
  float* Cp = C + (long)blockIdx.z * sC;
  int m0 = blockIdx.y * 64, n0 = blockIdx.x * 64;
  int tid = threadIdx.x;
  int tx = tid & 15, ty = tid >> 4;
  int arow = tid >> 2, acol = (tid & 3) * 4;
  int brow = tid >> 4, bcol = (tid & 15) * 4;
  float acc[4][4];
#pragma unroll
  for (int i = 0; i < 4; ++i)
#pragma unroll
    for (int j = 0; j < 4; ++j) acc[i][j] = 0.f;

  for (int k0 = 0; k0 < Kd; k0 += 16) {
    float4 av = *(const float4*)(Ap + (long)(m0 + arow) * Kd + k0 + acol);
    float4 bv = *(const float4*)(Bp + (long)(k0 + brow) * N + n0 + bcol);
    __syncthreads();
    As[acol + 0][arow] = av.x;
    As[acol + 1][arow] = av.y;
    As[acol + 2][arow] = av.z;
    As[acol + 3][arow] = av.w;
    *(float4*)&Bs[brow][bcol] = bv;
    __syncthreads();
#pragma unroll
    for (int kk = 0; kk < 16; ++kk) {
      float4 a = *(const float4*)&As[kk][ty * 4];
      float4 bq = *(const float4*)&Bs[kk][tx * 4];
      float am[4] = {a.x, a.y, a.z, a.w};
      float bn[4] = {bq.x, bq.y, bq.z, bq.w};
#pragma unroll
      for (int i = 0; i < 4; ++i)
#pragma unroll
        for (int j = 0; j < 4; ++j) acc[i][j] += am[i] * bn[j];
    }
  }
#pragma unroll
  for (int i = 0; i < 4; ++i) {
    int m = m0 + ty * 4 + i;
    float bb = bias ? bias[m] : 0.f;
    float4 o;
    o.x = acc[i][0] + bb; o.y = acc[i][1] + bb; o.z = acc[i][2] + bb; o.w = acc[i][3] + bb;
    *(float4*)(Cp + (long)m * N + n0 + tx * 4) = o;
  }
}

// ---------------- BN stats ----------------
__global__ __launch_bounds__(256)
void bn_stats(const float* __restrict__ Y, const float* __restrict__ g,
              const float* __restrict__ be, float* __restrict__ scale,
              float* __restrict__ shift, int C) {
  int c = blockIdx.x;
  double s1 = 0.0, s2 = 0.0;
  for (int idx = threadIdx.x; idx < B_ * N_; idx += 256) {
    int b = idx >> 12, n = idx & (N_ - 1);
    float v = Y[((long)b * C + c) * N_ + n];
    s1 += v;
    s2 += (double)v * (double)v;
  }
  __shared__ double r1[256], r2[256];
  int tid = threadIdx.x;
  r1[tid] = s1; r2[tid] = s2;
  __syncthreads();
  for (int s = 128; s > 0; s >>= 1) {
    if (tid < s) { r1[tid] += r1[tid + s]; r2[tid] += r2[tid + s]; }
    __syncthreads();
  }
  if (tid == 0) {
    double m = r1[0] / (double)(B_ * N_);
    double var = r2[0] / (double)(B_ * N_) - m * m;
    float sc = (float)((double)g[c] / sqrt(var + 1e-5));
    scale[c] = sc;
    shift[c] = (float)((double)be[c] - m * (double)sc);
  }
}

// ---------------- BN+ReLU in place (layer 2) ----------------
__global__ __launch_bounds__(256)
void bn_relu(float* __restrict__ Y, const float* __restrict__ scale,
             const float* __restrict__ shift, int C) {
  long i4 = (long)blockIdx.x * 256 + threadIdx.x;
  long i = i4 * 4;
  int c = (int)((i >> 12) % C);
  float sc = scale[c], sh = shift[c];
  float4 v = *(float4*)(Y + i);
  v.x = fmaxf(v.x * sc + sh, 0.f);
  v.y = fmaxf(v.y * sc + sh, 0.f);
  v.z = fmaxf(v.z * sc + sh, 0.f);
  v.w = fmaxf(v.w * sc + sh, 0.f);
  *(float4*)(Y + i) = v;
}

// ---------------- BN+ReLU + transpose+split (layer 1): [B][H][N] f32 -> [B][N][H] bf16 hi/lo
__global__ __launch_bounds__(256)
void bn_relu_t(const float* __restrict__ Y, const float* __restrict__ scale,
               const float* __restrict__ shift, ushort* __restrict__ OhT,
               ushort* __restrict__ OlT) {
  __shared__ float tile[64][65];
  int b = blockIdx.z, h0 = blockIdx.y * 64, n0 = blockIdx.x * 64;
  const float* src = Y + ((long)b * H_ + h0) * N_ + n0;
  int t = threadIdx.x;
  int rr4 = t >> 4, c4 = (t & 15) * 4;
#pragma unroll
  for (int p = 0; p < 4; ++p) {
    int hl = p * 16 + rr4;
    float sc = scale[h0 + hl], sh = shift[h0 + hl];
    float4 v = *(const float4*)(src + (long)hl * N_ + c4);
    tile[hl][c4 + 0] = fmaxf(v.x * sc + sh, 0.f);
    tile[hl][c4 + 1] = fmaxf(v.y * sc + sh, 0.f);
    tile[hl][c4 + 2] = fmaxf(v.z * sc + sh, 0.f);
    tile[hl][c4 + 3] = fmaxf(v.w * sc + sh, 0.f);
  }
  __syncthreads();
  int nlb = t >> 3, hs = (t & 7) * 8;
#pragma unroll
  for (int p = 0; p < 2; ++p) {
    int nl = p * 32 + nlb;
    sx8 hv, lv;
#pragma unroll
    for (int j = 0; j < 8; ++j) {
      float f = tile[hs + j][nl];
      ushort h = f2bf(f);
      hv[j] = (short)h;
      lv[j] = (short)f2bf(f - bf2f(h));
    }
    long o = ((long)b * N_ + n0 + nl) * H_ + h0 + hs;
    *(sx8*)(OhT + o) = hv;
    *(sx8*)(OlT + o) = lv;
  }
}

// ---------------- softmax over K; scoreT [b][n][K], logp [b][K][N] ----------------
__global__ __launch_bounds__(256)
void softmax_k(const float* __restrict__ ls, float* __restrict__ scoreT,
               float* __restrict__ logpKN, float* __restrict__ pi_raw) {
  __shared__ float ploc[64];
  int tid = threadIdx.x;
  if (tid < 64) ploc[tid] = 0.f;
  __syncthreads();
  long gid = (long)blockIdx.x * 256 + tid;
  int b = (int)(gid >> 12);
  int n = (int)(gid & (N_ - 1));
  const float* x = ls + ((long)b * K_) * N_ + n;
  float mx = -1e30f;
  for (int k = 0; k < 64; ++k) mx = fmaxf(mx, x[(long)k * N_]);
  float s = 0.f;
  for (int k = 0; k < 64; ++k) s += expf(x[(long)k * N_] - mx);
  float lg = logf(s);
  float inv = 1.f / s;
  float* st = scoreT + gid * 64;
  float* lp = logpKN + ((long)b * K_) * N_ + n;
  for (int k = 0; k < 64; ++k) {
    float xv = x[(long)k * N_] - mx;
    float e = expf(xv);
    float sc = e * inv;
    st[k] = sc;
    lp[(long)k * N_] = xv - lg;
    atomicAdd(&ploc[k], sc);
  }
  __syncthreads();
  if (tid < 64) atomicAdd(&pi_raw[b * 64 + tid], ploc[tid]);
}

__global__ void pi_fin(const float* __restrict__ pr, float* __restrict__ pi) {
  int i = blockIdx.x * 256 + threadIdx.x;
  if (i < B_ * K_) pi[i] = fmaxf(pr[i], 1e-4f);
}

// ---------------- mu_xyz ----------------
__global__ __launch_bounds__(64)
void mu_xyz_k(const float* __restrict__ scoreT, const float* __restrict__ xyz,
              const float* __restrict__ pi, float* __restrict__ mu, float* __restrict__ yn) {
  int k = blockIdx.x, b = blockIdx.y, t = threadIdx.x;
  const float* st = scoreT + ((long)b * N_) * K_ + k;
  const float* xp = xyz + (long)b * 3 * N_;
  float a0 = 0, a1 = 0, a2 = 0;
  for (int n = t; n < N_; n += 64) {
    float s = st[(long)n * K_];
    a0 += s * xp[n];
    a1 += s * xp[N_ + n];
    a2 += s * xp[2 * N_ + n];
  }
  for (int off = 32; off > 0; off >>= 1) {
    a0 += __shfl_down(a0, off);
    a1 += __shfl_down(a1, off);
    a2 += __shfl_down(a2, off);
  }
  if (t == 0) {
    float p = pi[b * K_ + k];
    float m0 = a0 / p, m1 = a1 / p, m2 = a2 / p;
    mu[((long)b * 3 + 0) * K_ + k] = m0;
    mu[((long)b * 3 + 1) * K_ + k] = m1;
    mu[((long)b * 3 + 2) * K_ + k] = m2;
    yn[b * K_ + k] = m0 * m0 + m1 * m1 + m2 * m2;
  }
}

// ---------------- regularizers ----------------
__global__ __launch_bounds__(256)
void reg_xyz_k(const float* __restrict__ mu, float* __restrict__ out) {
  __shared__ float red[256];
  int b = blockIdx.x, tid = threadIdx.x;
  float acc = 0.f;
  for (int e = tid; e < 4096; e += 256) {
    int m = e >> 6, n2 = e & 63;
    float g = 0.f;
    for (int d = 0; d < 3; ++d)
      g += mu[((long)b * 3 + d) * K_ + m] * mu[((long)b * 3 + d) * K_ + n2];
    acc += fabsf(g - (m == n2 ? 1.f : 0.f));
  }
  float tot = block_reduce_sum256(acc, red);
  if (tid == 0) atomicAdd(out, tot * (1e-7f / 32768.f));
}

__global__ __launch_bounds__(256)
void reg_fea_k(const float* __restrict__ nT, float* __restrict__ out) {
  __shared__ float red[256];
  int b = blockIdx.x, tid = threadIdx.x;
  float acc = 0.f;
  for (int e = tid; e < 4096; e += 256) {
    int m = e >> 6, n2 = e & 63;
    const float* pm_ = nT + ((long)b * K_ + m) * D_;
    const float* pn_ = nT + ((long)b * K_ + n2) * D_;
    float g0 = 0, g1 = 0, g2 = 0, g3 = 0;
    for (int d = 0; d < D_; d += 4) {
      g0 += pm_[d] * pn_[d];
      g1 += pm_[d + 1] * pn_[d + 1];
      g2 += pm_[d + 2] * pn_[d + 2];
      g3 += pm_[d + 3] * pn_[d + 3];
    }
    float g = (g0 + g1) + (g2 + g3);
    acc += fabsf(g - (m == n2 ? 1.f : 0.f));
  }
  float tot = block_reduce_sum256(acc, red);
  if (tid == 0) atomicAdd(out, tot * (1e-4f / 32768.f));
}

// ---------------- cost_xyz -> [b][K][N] ----------------
__global__ __launch_bounds__(256)
void cost_xyz_k(const float* __restrict__ xyz, const float* __restrict__ mu,
                const float* __restrict__ yn, float* __restrict__ cost) {
  __shared__ float m0s[64], m1s[64], m2s[64], yl[64];
  int b = blockIdx.y;
  int tid = threadIdx.x;
  if (tid < 64) {
    m0s[tid] = mu[((long)b * 3 + 0) * K_ + tid];
    m1s[tid] = mu[((long)b * 3 + 1) * K_ + tid];
    m2s[tid] = mu[((long)b * 3 + 2) * K_ + tid];
    yl[tid] = yn[b * K_ + tid];
  }
  __syncthreads();
  int n = blockIdx.x * 256 + tid;
  const float* xp = xyz + (long)b * 3 * N_;
  float x0 = xp[n], x1 = xp[N_ + n], x2 = xp[2 * N_ + n];
  float xn = x0 * x0 + x1 * x1 + x2 * x2;
  float* cb = cost + ((long)b * K_) * N_ + n;
  for (int m = 0; m < 64; ++m)
    cb[(long)m * N_] = xn + yl[m] - 2.f * (x0 * m0s[m] + x1 * m1s[m] + x2 * m2s[m]);
}

// ---------------- mu_fea finalize -> n_muT [b][K][D] ----------------
__global__ __launch_bounds__(256)
void mu_finalize(const float* __restrict__ mu_raw, const float* __restrict__ pi,
                 float* __restrict__ n_muT) {
  __shared__ float red[256];
  int k = blockIdx.x, b = blockIdx.y, tid = threadIdx.x;
  float p = pi[b * K_ + k];
  float ss = 0.f;
  for (int d = tid; d < D_; d += 256) {
    float v = mu_raw[((long)b * D_ + d) * K_ + k] / p;
    ss += v * v;
  }
  float tot = block_reduce_sum256(ss, red);
  float inv = 1.f / fmaxf(sqrtf(tot), 1e-12f);
  for (int d = tid; d < D_; d += 256) {
    float v = mu_raw[((long)b * D_ + d) * K_ + k] / p * inv;
    n_muT[((long)b * K_ + k) * D_ + d] = v;
  }
}

// ---------------- feature inverse norms ----------------
__global__ __launch_bounds__(256)
void inv_nrm_k(const float* __restrict__ F, float* __restrict__ invn) {
  int b = blockIdx.y;
  int n = blockIdx.x * 256 + threadIdx.x;
  const float* f = F + (long)b * D_ * N_ + n;
  float s0 = 0, s1 = 0, s2 = 0, s3 = 0;
  for (int d = 0; d < D_; d += 4) {
    float v0 = f[(long)d * N_], v1 = f[(long)(d + 1) * N_];
    float v2 = f[(long)(d + 2) * N_], v3 = f[(long)(d + 3) * N_];
    s0 += v0 * v0; s1 += v1 * v1; s2 += v2 * v2; s3 += v3 * v3;
  }
  float ss = (s0 + s1) + (s2 + s3);
  invn[b * N_ + n] = 1.f / fmaxf(sqrtf(ss), 1e-12f);
}

// ---------------- cost_fea: [K][N] = 2 - 2 * (n_muT @ F) * invn[n] ----------------
__global__ __launch_bounds__(256)
void cost_fea_kn(const float* __restrict__ nmuT, const float* __restrict__ F,
                 const float* __restrict__ invn, float* __restrict__ cost) {
  __shared__ float As[16][64];
  __shared__ float Bs[16][64];
  int b = blockIdx.z;
  int n0 = blockIdx.x * 64;
  const float* Ap = nmuT + (long)b * K_ * D_;
  const float* Bp = F + (long)b * D_ * N_;
  float* Cp = cost + (long)b * K_ * N_;
  int tid = threadIdx.x;
  int tx = tid & 15, ty = tid >> 4;
  int arow = tid >> 2, acol = (tid & 3) * 4;
  int brow = tid >> 4, bcol = (tid & 15) * 4;
  float acc[4][4];
#pragma unroll
  for (int i = 0; i < 4; ++i)
#pragma unroll
    for (int j = 0; j < 4; ++j) acc[i][j] = 0.f;

  for (int k0 = 0; k0 < D_; k0 += 16) {
    float4 av = *(const float4*)(Ap + (long)arow * D_ + k0 + acol);
    float4 bv = *(const float4*)(Bp + (long)(k0 + brow) * N_ + n0 + bcol);
    __syncthreads();
    As[acol + 0][arow] = av.x;
    As[acol + 1][arow] = av.y;
    As[acol + 2][arow] = av.z;
    As[acol + 3][arow] = av.w;
    *(float4*)&Bs[brow][bcol] = bv;
    __syncthreads();
#pragma unroll
    for (int kk = 0; kk < 16; ++kk) {
      float4 a = *(const float4*)&As[kk][ty * 4];
      float4 bq = *(const float4*)&Bs[kk][tx * 4];
      float am[4] = {a.x, a.y, a.z, a.w};
      float bn[4] = {bq.x, bq.y, bq.z, bq.w};
#pragma unroll
      for (int i = 0; i < 4; ++i)
#pragma unroll
        for (int j = 0; j < 4; ++j) acc[i][j] += am[i] * bn[j];
    }
  }
  float4 ivn = *(const float4*)(invn + (long)b * N_ + n0 + tx * 4);
#pragma unroll
  for (int i = 0; i < 4; ++i) {
    int m = ty * 4 + i;
    float4 o;
    o.x = 2.f - 2.f * acc[i][0] * ivn.x;
    o.y = 2.f - 2.f * acc[i][1] * ivn.y;
    o.z = 2.f - 2.f * acc[i][2] * ivn.z;
    o.w = 2.f - 2.f * acc[i][3] * ivn.w;
    *(float4*)(Cp + (long)m * N_ + n0 + tx * 4) = o;
  }
}

// ---------------- cooperative Sinkhorn: 16 groups x 16 slices x 256 rows ----------------
__global__ __launch_bounds__(256, 1)
void sinkhorn_coop(const float* __restrict__ costAll, const float* __restrict__ logpKN,
                   float* __restrict__ out, float* __restrict__ partM,
                   float* __restrict__ partS, unsigned int* __restrict__ cnt) {
  __shared__ float tile[4][64][33];
  __shared__ float vsh[64];
  __shared__ float wm[4][64];
  __shared__ float wsum[4][64];
  __shared__ float red[256];
  const int tid = threadIdx.x;
  const int g = blockIdx.x & 15;   // group: branch*8 + batch
  const int s = blockIdx.x >> 4;   // slice within group
  const int w = tid >> 6, lane = tid & 63;
  const int i = s * 256 + tid;     // my row (point index)
  const float* C = costAll + (long)g * K_ * N_;
  const float eps = 1e-3f, ti = 1000.0f;
  const float lgp = -8.317766166719343f;   // -log(4096)
  const float lgq = -4.1588830833596715f;  // -log(64)

  float c[64];
#pragma unroll
  for (int j = 0; j < 64; ++j) c[j] = C[(long)j * N_ + i];

  float u = 0.f;
  if (tid < 64) vsh[tid] = 0.f;
  __syncthreads();

  for (int it = 0; it < 25; ++it) {
    // ---- u-update
    float dm = -1e30f;
#pragma unroll
    for (int j = 0; j < 64; ++j) dm = fmaxf(dm, vsh[j] - c[j]);
    float ssum = 0.f;
#pragma unroll
    for (int j = 0; j < 64; ++j) ssum += __expf((vsh[j] - c[j] - dm) * ti);
    float lse = (u + dm) * ti + __logf(ssum);
    u = eps * (lgp - lse) + u;

    // ---- column partials via per-wave LDS transpose
#pragma unroll
    for (int h = 0; h < 2; ++h) {
#pragma unroll
      for (int j2 = 0; j2 < 32; ++j2) {
        int j = h * 32 + j2;
        tile[w][lane][j2] = (u + vsh[j] - c[j]) * ti;
      }
      __syncthreads();
      int col = lane & 31, rh = lane >> 5;
      float Mh = -1e30f, Sh = 0.f;
#pragma unroll
      for (int r = 0; r < 32; ++r) {
        float a = tile[w][rh * 32 + r][col];
        Mh = fmaxf(Mh, a);
        Sh += __expf(a - lgp);
      }
      float Mo = __shfl_xor(Mh, 32);
      float So = __shfl_xor(Sh, 32);
      Mh = fmaxf(Mh, Mo);
      Sh += So;
      if (rh == 0) { wm[w][h * 32 + col] = Mh; wsum[w][h * 32 + col] = Sh; }
      __syncthreads();
    }
    int buf = it & 1;
    if (tid < 64) {
      float Mb = fmaxf(fmaxf(wm[0][tid], wm[1][tid]), fmaxf(wm[2][tid], wm[3][tid]));
      float Sb = wsum[0][tid] + wsum[1][tid] + wsum[2][tid] + wsum[3][tid];
      long idx = (((long)buf * 16 + g) * 64 + tid) * 16 + s;
      __hip_atomic_store(&partM[idx], Mb, __ATOMIC_RELAXED, __HIP_MEMORY_SCOPE_AGENT);
      __hip_atomic_store(&partS[idx], Sb, __ATOMIC_RELAXED, __HIP_MEMORY_SCOPE_AGENT);
    }
    __syncthreads();  // drains vmcnt for wave 0's stores before tid0's RMW
    // ---- group barrier: padded per-group counter (own 128B line), no L2 writeback
    if (tid == 0) {
      __hip_atomic_fetch_add(&cnt[g * 32], 1u, __ATOMIC_RELEASE, __HIP_MEMORY_SCOPE_AGENT);
      unsigned target = 16u * (unsigned)(it + 1);
      while (__hip_atomic_load(&cnt[g * 32], __ATOMIC_ACQUIRE, __HIP_MEMORY_SCOPE_AGENT) < target)
        __builtin_amdgcn_s_sleep(2);
    }
    __syncthreads();
    // ---- v-update (redundant per block; reads bypass caches via agent scope)
    if (tid < 64) {
      long base = (((long)buf * 16 + g) * 64 + tid) * 16;
      float M = -1e30f, S = 0.f;
#pragma unroll
      for (int p = 0; p < 16; ++p) {
        M = fmaxf(M, __hip_atomic_load(&partM[base + p], __ATOMIC_RELAXED, __HIP_MEMORY_SCOPE_AGENT));
        S += __hip_atomic_load(&partS[base + p], __ATOMIC_RELAXED, __HIP_MEMORY_SCOPE_AGENT);
      }
      float lsec = fmaxf(M, lgp + __logf(S));
      vsh[tid] = eps * (lgq - lsec) + vsh[tid];
    }
    __syncthreads();
  }

  // ---- fused loss
  const float* lp = logpKN + ((long)(g & 7) * K_) * N_ + i;
  float part = 0.f;
#pragma unroll
  for (int j = 0; j < 64; ++j) {
    float gma = __expf((u + vsh[j] - c[j]) * ti);
    part += gma * lp[(long)j * N_];
  }
  red[tid] = part;
  __syncthreads();
  for (int st2 = 128; st2 > 0; st2 >>= 1) {
    if (tid < st2) red[tid] += red[tid + st2];
    __syncthreads();
  }
  if (tid == 0) atomicAdd(out, -red[0] / (float)B_);
}

// ---------------- launch ----------------
extern "C" void kernel_launch(void* const* d_in, const int* in_sizes, int n_in,
                              void* d_out, int out_size, void* d_ws, size_t ws_size,
                              hipStream_t stream) {
  const float* feature = (const float*)d_in[0];
  const float* xyz = (const float*)d_in[1];
  const float* w1 = (const float*)d_in[2];
  const float* b1 = (const float*)d_in[3];
  const float* g1 = (const float*)d_in[4];
  const float* be1 = (const float*)d_in[5];
  const float* w2 = (const float*)d_in[6];
  const float* b2 = (const float*)d_in[7];
  const float* g2 = (const float*)d_in[8];
  const float* be2 = (const float*)d_in[9];
  const float* w3 = (const float*)d_in[10];
  const float* b3 = (const float*)d_in[11];
  float* out = (float*)d_out;
  float* ws = (float*)d_ws;

  const long RSZ = 16777216L;  // floats per region (67 MB)
  float* regA = ws;
  float* regB1 = ws + RSZ;
  float* regB2 = ws + 2 * RSZ;
  float* sm = ws + 3 * RSZ;

  // phase-1 aliases
  ushort* FhT = (ushort*)regB1;   // [B][N][D] bf16
  ushort* FlT = (ushort*)regB2;
  float* h1raw = regA;            // [B][H][N] f32
  // phase-2 aliases (after conv1 consumed FhT/FlT)
  ushort* h1hT = (ushort*)regB1;            // [B][N][H] bf16 (33.5 MB)
  ushort* h1lT = (ushort*)regB1 + RSZ;      // second half of regB1
  float* h2 = regB2;              // [B][H][N] f32
  // phase-3 aliases (after h1raw consumed)
  const long sz_sc = (long)B_ * N_ * K_;  // 2,097,152
  float* log_score = regA;
  float* scoreT = regA + sz_sc;
  float* logpKN = regA + 2 * sz_sc;
  float* cost_x = regA + 3 * sz_sc;
  float* cost_f = regA + 4 * sz_sc;

  // smalls
  ushort* Wh1 = (ushort*)sm; sm += 262144;  // 524288 ushorts
  ushort* Wl1 = (ushort*)sm; sm += 262144;
  ushort* Wh2 = (ushort*)sm; sm += 131072;  // 262144 ushorts
  ushort* Wl2 = (ushort*)sm; sm += 131072;
  float* mu_raw = sm; sm += (long)B_ * D_ * K_;
  float* n_muT = sm;  sm += (long)B_ * D_ * K_;
  float* partM = sm;  sm += 2 * 16 * 64 * 16;
  float* partS = sm;  sm += 2 * 16 * 64 * 16;
  unsigned int* cnt = (unsigned int*)sm; sm += 512;  // 16 groups x 32-uint pad
  float* inv_nrm = sm; sm += (long)B_ * N_;
  float* mu_x = sm;   sm += 2048;
  float* yn = sm;     sm += 512;
  float* pi_raw = sm; sm += 512;
  float* pi = sm;     sm += 512;
  float* sc1 = sm; sm += 512;
  float* sh1 = sm; sm += 512;
  float* sc2 = sm; sm += 512;
  float* sh2 = sm; sm += 512;

  hipMemsetAsync(d_out, 0, sizeof(float) * out_size, stream);
  hipMemsetAsync(pi_raw, 0, 512 * sizeof(float), stream);
  hipMemsetAsync(cnt, 0, 512 * sizeof(unsigned int), stream);

  // weight splits
  split_w<<<(H_ * D_) / 256, 256, 0, stream>>>(w1, Wh1, Wl1, H_ * D_);
  split_w<<<(H_ * H_) / 256, 256, 0, stream>>>(w2, Wh2, Wl2, H_ * H_);
  // feature transpose+split
  {
    dim3 g(N_ / 64, D_ / 64, B_);
    transpose_split<<<g, 256, 0, stream>>>(feature, FhT, FlT);
  }
  // conv1 (MFMA split-bf16): [512,1024] @ [1024,4096]
  {
    dim3 g(N_ / 128, H_ / 128, B_);
    gemm_split_bf16<<<g, 256, 0, stream>>>(Wh1, Wl1, FhT, FlT, h1raw, b1,
                                           N_, D_, (long)N_ * D_, (long)H_ * N_);
  }
  bn_stats<<<H_, 256, 0, stream>>>(h1raw, g1, be1, sc1, sh1, H_);
  // BN+ReLU fused with transpose+split -> h1hT/h1lT [B][N][H]
  {
    dim3 g(N_ / 64, H_ / 64, B_);
    bn_relu_t<<<g, 256, 0, stream>>>(h1raw, sc1, sh1, h1hT, h1lT);
  }
  // conv2 (MFMA split-bf16): [512,512] @ [512,4096]
  {
    dim3 g(N_ / 128, H_ / 128, B_);
    gemm_split_bf16<<<g, 256, 0, stream>>>(Wh2, Wl2, h1hT, h1lT, h2, b2,
                                           N_, H_, (long)N_ * H_, (long)H_ * N_);
  }
  bn_stats<<<H_, 256, 0, stream>>>(h2, g2, be2, sc2, sh2, H_);
  bn_relu<<<(int)((long)B_ * H_ * N_ / 4 / 256), 256, 0, stream>>>(h2, sc2, sh2, H_);
  // conv3 (f32): [64,512] @ [512,4096]
  {
    dim3 g(N_ / 64, K_ / 64, B_);
    sgemm64_nn<<<g, 256, 0, stream>>>(w3, h2, log_score, b3, K_, N_, H_, 0L,
                                      (long)H_ * N_, (long)K_ * N_);
  }
  softmax_k<<<B_ * N_ / 256, 256, 0, stream>>>(log_score, scoreT, logpKN, pi_raw);
  pi_fin<<<2, 256, 0, stream>>>(pi_raw, pi);
  {
    dim3 g(K_, B_);
    mu_xyz_k<<<g, 64, 0, stream>>>(scoreT, xyz, pi, mu_x, yn);
  }
  reg_xyz_k<<<B_, 256, 0, stream>>>(mu_x, out);
  {
    dim3 g(N_ / 256, B_);
    cost_xyz_k<<<g, 256, 0, stream>>>(xyz, mu_x, yn, cost_x);
  }
  {
    dim3 g(K_ / 64, D_ / 64, B_);
    sgemm64_nn<<<g, 256, 0, stream>>>(feature, scoreT, mu_raw, nullptr, D_, K_, N_,
                                      (long)D_ * N_, (long)N_ * K_, (long)D_ * K_);
  }
  {
    dim3 g(K_, B_);
    mu_finalize<<<g, 256, 0, stream>>>(mu_raw, pi, n_muT);
  }
  reg_fea_k<<<B_, 256, 0, stream>>>(n_muT, out);
  {
    dim3 g(N_ / 256, B_);
    inv_nrm_k<<<g, 256, 0, stream>>>(feature, inv_nrm);
  }
  {
    dim3 g(N_ / 64, 1, B_);
    cost_fea_kn<<<g, 256, 0, stream>>>(n_muT, feature, inv_nrm, cost_f);
  }
  {
    void* kargs[] = {(void*)&cost_x, (void*)&logpKN, (void*)&out,
                     (void*)&partM, (void*)&partS, (void*)&cnt};
    hipLaunchCooperativeKernel((const void*)sinkhorn_coop, dim3(256), dim3(256),
                               kargs, 0, stream);
  }
}

// Round 4
// 1415.224 us; speedup vs baseline: 4.4004x; 1.4673x over previous
//
#include <hip/hip_runtime.h>
#include <math.h>

#define B_ 8
#define D_ 1024
#define N_ 4096
#define K_ 64
#define H_ 512

typedef short sx8 __attribute__((ext_vector_type(8)));
typedef float fx4 __attribute__((ext_vector_type(4)));

// ---------------- helpers ----------------
__device__ __forceinline__ float block_reduce_sum256(float v, float* sm) {
  int tid = threadIdx.x;
  sm[tid] = v;
  __syncthreads();
  for (int s = 128; s > 0; s >>= 1) {
    if (tid < s) sm[tid] += sm[tid + s];
    __syncthreads();
  }
  float r = sm[0];
  __syncthreads();
  return r;
}

__device__ __forceinline__ ushort f2bf(float f) {
  unsigned u = __float_as_uint(f);
  unsigned r = (u + 0x7fffu + ((u >> 16) & 1u)) >> 16;
  return (ushort)r;
}
__device__ __forceinline__ float bf2f(ushort h) {
  return __uint_as_float(((unsigned)h) << 16);
}

// ---------------- weight split: f32 -> bf16 hi/lo ----------------
__global__ __launch_bounds__(256)
void split_w(const float* __restrict__ W, ushort* __restrict__ Wh,
             ushort* __restrict__ Wl, int n) {
  int i = blockIdx.x * 256 + threadIdx.x;
  if (i < n) {
    float f = W[i];
    ushort h = f2bf(f);
    Wh[i] = h;
    Wl[i] = f2bf(f - bf2f(h));
  }
}

// ---------------- feature transpose+split: [B][D][N] f32 -> [B][N][D] bf16 hi/lo ----
__global__ __launch_bounds__(256)
void transpose_split(const float* __restrict__ F, ushort* __restrict__ FhT,
                     ushort* __restrict__ FlT) {
  __shared__ float tile[64][65];
  int b = blockIdx.z, d0 = blockIdx.y * 64, n0 = blockIdx.x * 64;
  const float* src = F + ((long)b * D_ + d0) * N_ + n0;
  int t = threadIdx.x;
  int rr4 = t >> 4, c4 = (t & 15) * 4;
#pragma unroll
  for (int p = 0; p < 4; ++p) {
    int dr = p * 16 + rr4;
    float4 v = *(const float4*)(src + (long)dr * N_ + c4);
    tile[dr][c4 + 0] = v.x;
    tile[dr][c4 + 1] = v.y;
    tile[dr][c4 + 2] = v.z;
    tile[dr][c4 + 3] = v.w;
  }
  __syncthreads();
  int nlb = t >> 3, ds = (t & 7) * 8;
#pragma unroll
  for (int p = 0; p < 2; ++p) {
    int nl = p * 32 + nlb;
    sx8 hv, lv;
#pragma unroll
    for (int j = 0; j < 8; ++j) {
      float f = tile[ds + j][nl];
      ushort h = f2bf(f);
      hv[j] = (short)h;
      lv[j] = (short)f2bf(f - bf2f(h));
    }
    long o = ((long)b * N_ + n0 + nl) * D_ + d0 + ds;
    *(sx8*)(FhT + o) = hv;
    *(sx8*)(FlT + o) = lv;
  }
}

// ---------------- split-bf16 MFMA GEMM ----------------
__global__ __launch_bounds__(256)
void gemm_split_bf16(const ushort* __restrict__ Ah, const ushort* __restrict__ Al,
                     const ushort* __restrict__ BhT, const ushort* __restrict__ BlT,
                     float* __restrict__ C, const float* __restrict__ bias,
                     int N, int Kd, long sBT, long sC) {
  __shared__ ushort As[2][128][40];
  __shared__ ushort Bs[2][128][40];
  const int t = threadIdx.x;
  const int m0 = blockIdx.y * 128, n0 = blockIdx.x * 128;
  const long bo = (long)blockIdx.z * sBT;
  float* Cp = C + (long)blockIdx.z * sC;
  const int half = t >> 7, r = t & 127;
  const ushort* Asrc = (half ? Al : Ah) + (long)(m0 + r) * Kd;
  const ushort* Bsrc = (half ? BlT : BhT) + bo + (long)(n0 + r) * Kd;
  ushort* AsD = &As[half][r][0];
  ushort* BsD = &Bs[half][r][0];
  const int w = t >> 6, ln = t & 15, qd = (t & 63) >> 4;
  const int wm = w >> 1, wn = w & 1;

  fx4 acc[4][4];
#pragma unroll
  for (int i = 0; i < 4; ++i)
#pragma unroll
    for (int j = 0; j < 4; ++j) acc[i][j] = (fx4)0.f;

  for (int k0 = 0; k0 < Kd; k0 += 32) {
    uint4 a0 = *(const uint4*)(Asrc + k0);
    uint4 a1 = *(const uint4*)(Asrc + k0 + 8);
    uint4 a2 = *(const uint4*)(Asrc + k0 + 16);
    uint4 a3 = *(const uint4*)(Asrc + k0 + 24);
    uint4 b0 = *(const uint4*)(Bsrc + k0);
    uint4 b1 = *(const uint4*)(Bsrc + k0 + 8);
    uint4 b2 = *(const uint4*)(Bsrc + k0 + 16);
    uint4 b3 = *(const uint4*)(Bsrc + k0 + 24);
    __syncthreads();
    *(uint4*)(AsD + 0) = a0;
    *(uint4*)(AsD + 8) = a1;
    *(uint4*)(AsD + 16) = a2;
    *(uint4*)(AsD + 24) = a3;
    *(uint4*)(BsD + 0) = b0;
    *(uint4*)(BsD + 8) = b1;
    *(uint4*)(BsD + 16) = b2;
    *(uint4*)(BsD + 24) = b3;
    __syncthreads();
    sx8 ahf[4], alf[4], bhf[4], blf[4];
#pragma unroll
    for (int mt = 0; mt < 4; ++mt) {
      ahf[mt] = *(const sx8*)&As[0][wm * 64 + mt * 16 + ln][qd * 8];
      alf[mt] = *(const sx8*)&As[1][wm * 64 + mt * 16 + ln][qd * 8];
    }
#pragma unroll
    for (int nt = 0; nt < 4; ++nt) {
      bhf[nt] = *(const sx8*)&Bs[0][wn * 64 + nt * 16 + ln][qd * 8];
      blf[nt] = *(const sx8*)&Bs[1][wn * 64 + nt * 16 + ln][qd * 8];
    }
#pragma unroll
    for (int mt = 0; mt < 4; ++mt)
#pragma unroll
      for (int nt = 0; nt < 4; ++nt) {
        acc[mt][nt] = __builtin_amdgcn_mfma_f32_16x16x32_bf16(ahf[mt], bhf[nt], acc[mt][nt], 0, 0, 0);
        acc[mt][nt] = __builtin_amdgcn_mfma_f32_16x16x32_bf16(alf[mt], bhf[nt], acc[mt][nt], 0, 0, 0);
        acc[mt][nt] = __builtin_amdgcn_mfma_f32_16x16x32_bf16(ahf[mt], blf[nt], acc[mt][nt], 0, 0, 0);
      }
  }
#pragma unroll
  for (int mt = 0; mt < 4; ++mt) {
#pragma unroll
    for (int rr = 0; rr < 4; ++rr) {
      int row = m0 + wm * 64 + mt * 16 + qd * 4 + rr;
      float bb = bias[row];
#pragma unroll
      for (int nt = 0; nt < 4; ++nt) {
        int col = n0 + wn * 64 + nt * 16 + ln;
        Cp[(long)row * N + col] = acc[mt][nt][rr] + bb;
      }
    }
  }
}

// ---------------- 64x64x16 NN SGEMM (f32; conv3) ----------------
__global__ __launch_bounds__(256)
void sgemm64_nn(const float* __restrict__ A, const float* __restrict__ Bm,
                float* __restrict__ C, const float* __restrict__ bias,
                int M, int N, int Kd, long sA, long sB, long sC) {
  __shared__ float As[16][64];
  __shared__ float Bs[16][64];
  const float* Ap = A + (long)blockIdx.z * sA;
  const float* Bp = Bm + (long)blockIdx.z * sB;
  float* Cp = C + (long)blockIdx.z * sC;
  int m0 = blockIdx.y * 64, n0 = blockIdx.x * 64;
  int tid = threadIdx.x;
  int tx = tid & 15, ty = tid >> 4;
  int arow = tid >> 2, acol = (tid & 3) * 4;
  int brow = tid >> 4, bcol = (tid & 15) * 4;
  float acc[4][4];
#pragma unroll
  for (int i = 0; i < 4; ++i)
#pragma unroll
    for (int j = 0; j < 4; ++j) acc[i][j] = 0.f;

  for (int k0 = 0; k0 < Kd; k0 += 16) {
    float4 av = *(const float4*)(Ap + (long)(m0 + arow) * Kd + k0 + acol);
    float4 bv = *(const float4*)(Bp + (long)(k0 + brow) * N + n0 + bcol);
    __syncthreads();
    As[acol + 0][arow] = av.x;
    As[acol + 1][arow] = av.y;
    As[acol + 2][arow] = av.z;
    As[acol + 3][arow] = av.w;
    *(float4*)&Bs[brow][bcol] = bv;
    __syncthreads();
#pragma unroll
    for (int kk = 0; kk < 16; ++kk) {
      float4 a = *(const float4*)&As[kk][ty * 4];
      float4 bq = *(const float4*)&Bs[kk][tx * 4];
      float am[4] = {a.x, a.y, a.z, a.w};
      float bn[4] = {bq.x, bq.y, bq.z, bq.w};
#pragma unroll
      for (int i = 0; i < 4; ++i)
#pragma unroll
        for (int j = 0; j < 4; ++j) acc[i][j] += am[i] * bn[j];
    }
  }
#pragma unroll
  for (int i = 0; i < 4; ++i) {
    int m = m0 + ty * 4 + i;
    float bb = bias ? bias[m] : 0.f;
    float4 o;
    o.x = acc[i][0] + bb; o.y = acc[i][1] + bb; o.z = acc[i][2] + bb; o.w = acc[i][3] + bb;
    *(float4*)(Cp + (long)m * N + n0 + tx * 4) = o;
  }
}

// ---------------- mu_fea with N-split: mu_raw[b][D][K] += F-chunk @ scoreT-chunk ----
__global__ __launch_bounds__(256)
void mu_fea_split(const float* __restrict__ F, const float* __restrict__ scoreT,
                  float* __restrict__ mu_raw) {
  __shared__ float As[16][64];
  __shared__ float Bs[16][64];
  int b = blockIdx.z;
  int d0 = blockIdx.y * 64;
  int nbase = blockIdx.x * 512;  // 8 chunks of 512
  const float* Ap = F + (long)b * D_ * N_;
  const float* Bp = scoreT + (long)b * N_ * K_;
  int tid = threadIdx.x;
  int tx = tid & 15, ty = tid >> 4;
  int arow = tid >> 2, acol = (tid & 3) * 4;
  int brow = tid >> 4, bcol = (tid & 15) * 4;
  float acc[4][4];
#pragma unroll
  for (int i = 0; i < 4; ++i)
#pragma unroll
    for (int j = 0; j < 4; ++j) acc[i][j] = 0.f;

  for (int k0 = 0; k0 < 512; k0 += 16) {
    float4 av = *(const float4*)(Ap + (long)(d0 + arow) * N_ + nbase + k0 + acol);
    float4 bv = *(const float4*)(Bp + (long)(nbase + k0 + brow) * K_ + bcol);
    __syncthreads();
    As[acol + 0][arow] = av.x;
    As[acol + 1][arow] = av.y;
    As[acol + 2][arow] = av.z;
    As[acol + 3][arow] = av.w;
    *(float4*)&Bs[brow][bcol] = bv;
    __syncthreads();
#pragma unroll
    for (int kk = 0; kk < 16; ++kk) {
      float4 a = *(const float4*)&As[kk][ty * 4];
      float4 bq = *(const float4*)&Bs[kk][tx * 4];
      float am[4] = {a.x, a.y, a.z, a.w};
      float bn[4] = {bq.x, bq.y, bq.z, bq.w};
#pragma unroll
      for (int i = 0; i < 4; ++i)
#pragma unroll
        for (int j = 0; j < 4; ++j) acc[i][j] += am[i] * bn[j];
    }
  }
#pragma unroll
  for (int i = 0; i < 4; ++i) {
    int d = d0 + ty * 4 + i;
#pragma unroll
    for (int j = 0; j < 4; ++j)
      atomicAdd(&mu_raw[((long)b * D_ + d) * K_ + tx * 4 + j], acc[i][j]);
  }
}

// ---------------- BN stats ----------------
__global__ __launch_bounds__(256)
void bn_stats(const float* __restrict__ Y, const float* __restrict__ g,
              const float* __restrict__ be, float* __restrict__ scale,
              float* __restrict__ shift, int C) {
  int c = blockIdx.x;
  double s1 = 0.0, s2 = 0.0;
  for (int idx = threadIdx.x; idx < B_ * N_; idx += 256) {
    int b = idx >> 12, n = idx & (N_ - 1);
    float v = Y[((long)b * C + c) * N_ + n];
    s1 += v;
    s2 += (double)v * (double)v;
  }
  __shared__ double r1[256], r2[256];
  int tid = threadIdx.x;
  r1[tid] = s1; r2[tid] = s2;
  __syncthreads();
  for (int s = 128; s > 0; s >>= 1) {
    if (tid < s) { r1[tid] += r1[tid + s]; r2[tid] += r2[tid + s]; }
    __syncthreads();
  }
  if (tid == 0) {
    double m = r1[0] / (double)(B_ * N_);
    double var = r2[0] / (double)(B_ * N_) - m * m;
    float sc = (float)((double)g[c] / sqrt(var + 1e-5));
    scale[c] = sc;
    shift[c] = (float)((double)be[c] - m * (double)sc);
  }
}

// ---------------- BN+ReLU in place (layer 2) ----------------
__global__ __launch_bounds__(256)
void bn_relu(float* __restrict__ Y, const float* __restrict__ scale,
             const float* __restrict__ shift, int C) {
  long i4 = (long)blockIdx.x * 256 + threadIdx.x;
  long i = i4 * 4;
  int c = (int)((i >> 12) % C);
  float sc = scale[c], sh = shift[c];
  float4 v = *(float4*)(Y + i);
  v.x = fmaxf(v.x * sc + sh, 0.f);
  v.y = fmaxf(v.y * sc + sh, 0.f);
  v.z = fmaxf(v.z * sc + sh, 0.f);
  v.w = fmaxf(v.w * sc + sh, 0.f);
  *(float4*)(Y + i) = v;
}

// ---------------- BN+ReLU + transpose+split (layer 1) ----------------
__global__ __launch_bounds__(256)
void bn_relu_t(const float* __restrict__ Y, const float* __restrict__ scale,
               const float* __restrict__ shift, ushort* __restrict__ OhT,
               ushort* __restrict__ OlT) {
  __shared__ float tile[64][65];
  int b = blockIdx.z, h0 = blockIdx.y * 64, n0 = blockIdx.x * 64;
  const float* src = Y + ((long)b * H_ + h0) * N_ + n0;
  int t = threadIdx.x;
  int rr4 = t >> 4, c4 = (t & 15) * 4;
#pragma unroll
  for (int p = 0; p < 4; ++p) {
    int hl = p * 16 + rr4;
    float sc = scale[h0 + hl], sh = shift[h0 + hl];
    float4 v = *(const float4*)(src + (long)hl * N_ + c4);
    tile[hl][c4 + 0] = fmaxf(v.x * sc + sh, 0.f);
    tile[hl][c4 + 1] = fmaxf(v.y * sc + sh, 0.f);
    tile[hl][c4 + 2] = fmaxf(v.z * sc + sh, 0.f);
    tile[hl][c4 + 3] = fmaxf(v.w * sc + sh, 0.f);
  }
  __syncthreads();
  int nlb = t >> 3, hs = (t & 7) * 8;
#pragma unroll
  for (int p = 0; p < 2; ++p) {
    int nl = p * 32 + nlb;
    sx8 hv, lv;
#pragma unroll
    for (int j = 0; j < 8; ++j) {
      float f = tile[hs + j][nl];
      ushort h = f2bf(f);
      hv[j] = (short)h;
      lv[j] = (short)f2bf(f - bf2f(h));
    }
    long o = ((long)b * N_ + n0 + nl) * H_ + h0 + hs;
    *(sx8*)(OhT + o) = hv;
    *(sx8*)(OlT + o) = lv;
  }
}

// ---------------- softmax over K ----------------
__global__ __launch_bounds__(256)
void softmax_k(const float* __restrict__ ls, float* __restrict__ scoreT,
               float* __restrict__ logpKN, float* __restrict__ pi_raw) {
  __shared__ float ploc[64];
  int tid = threadIdx.x;
  if (tid < 64) ploc[tid] = 0.f;
  __syncthreads();
  long gid = (long)blockIdx.x * 256 + tid;
  int b = (int)(gid >> 12);
  int n = (int)(gid & (N_ - 1));
  const float* x = ls + ((long)b * K_) * N_ + n;
  float mx = -1e30f;
  for (int k = 0; k < 64; ++k) mx = fmaxf(mx, x[(long)k * N_]);
  float s = 0.f;
  for (int k = 0; k < 64; ++k) s += expf(x[(long)k * N_] - mx);
  float lg = logf(s);
  float inv = 1.f / s;
  float* st = scoreT + gid * 64;
  float* lp = logpKN + ((long)b * K_) * N_ + n;
  for (int k = 0; k < 64; ++k) {
    float xv = x[(long)k * N_] - mx;
    float e = expf(xv);
    float sc = e * inv;
    st[k] = sc;
    lp[(long)k * N_] = xv - lg;
    atomicAdd(&ploc[k], sc);
  }
  __syncthreads();
  if (tid < 64) atomicAdd(&pi_raw[b * 64 + tid], ploc[tid]);
}

__global__ void pi_fin(const float* __restrict__ pr, float* __restrict__ pi) {
  int i = blockIdx.x * 256 + threadIdx.x;
  if (i < B_ * K_) pi[i] = fmaxf(pr[i], 1e-4f);
}

// ---------------- mu_xyz ----------------
__global__ __launch_bounds__(64)
void mu_xyz_k(const float* __restrict__ scoreT, const float* __restrict__ xyz,
              const float* __restrict__ pi, float* __restrict__ mu, float* __restrict__ yn) {
  int k = blockIdx.x, b = blockIdx.y, t = threadIdx.x;
  const float* st = scoreT + ((long)b * N_) * K_ + k;
  const float* xp = xyz + (long)b * 3 * N_;
  float a0 = 0, a1 = 0, a2 = 0;
  for (int n = t; n < N_; n += 64) {
    float s = st[(long)n * K_];
    a0 += s * xp[n];
    a1 += s * xp[N_ + n];
    a2 += s * xp[2 * N_ + n];
  }
  for (int off = 32; off > 0; off >>= 1) {
    a0 += __shfl_down(a0, off);
    a1 += __shfl_down(a1, off);
    a2 += __shfl_down(a2, off);
  }
  if (t == 0) {
    float p = pi[b * K_ + k];
    float m0 = a0 / p, m1 = a1 / p, m2 = a2 / p;
    mu[((long)b * 3 + 0) * K_ + k] = m0;
    mu[((long)b * 3 + 1) * K_ + k] = m1;
    mu[((long)b * 3 + 2) * K_ + k] = m2;
    yn[b * K_ + k] = m0 * m0 + m1 * m1 + m2 * m2;
  }
}

// ---------------- regularizers ----------------
__global__ __launch_bounds__(256)
void reg_xyz_k(const float* __restrict__ mu, float* __restrict__ out) {
  __shared__ float red[256];
  int b = blockIdx.x, tid = threadIdx.x;
  float acc = 0.f;
  for (int e = tid; e < 4096; e += 256) {
    int m = e >> 6, n2 = e & 63;
    float g = 0.f;
    for (int d = 0; d < 3; ++d)
      g += mu[((long)b * 3 + d) * K_ + m] * mu[((long)b * 3 + d) * K_ + n2];
    acc += fabsf(g - (m == n2 ? 1.f : 0.f));
  }
  float tot = block_reduce_sum256(acc, red);
  if (tid == 0) atomicAdd(out, tot * (1e-7f / 32768.f));
}

// parallel reg_fea: grid (K_, B_), row m cached in LDS, 4 threads per column
__global__ __launch_bounds__(256)
void reg_fea_k(const float* __restrict__ nT, float* __restrict__ out) {
  __shared__ float pm[1024];
  __shared__ float red[256];
  int m = blockIdx.x, b = blockIdx.y, tid = threadIdx.x;
  const float* base = nT + (long)b * K_ * D_;
  *(float4*)&pm[tid * 4] = *(const float4*)(base + (long)m * D_ + tid * 4);
  __syncthreads();
  int n2 = tid >> 2, q = tid & 3;
  const float* pn = base + (long)n2 * D_ + q * 256;
  const float* pml = &pm[q * 256];
  float g = 0.f;
#pragma unroll 8
  for (int d = 0; d < 256; d += 4) {
    float4 v = *(const float4*)(pn + d);
    g += v.x * pml[d] + v.y * pml[d + 1] + v.z * pml[d + 2] + v.w * pml[d + 3];
  }
  g += __shfl_down(g, 2);
  g += __shfl_down(g, 1);
  float acc = (q == 0) ? fabsf(g - (m == n2 ? 1.f : 0.f)) : 0.f;
  float tot = block_reduce_sum256(acc, red);
  if (tid == 0) atomicAdd(out, tot * (1e-4f / 32768.f));
}

// ---------------- cost_xyz -> [b][K][N] ----------------
__global__ __launch_bounds__(256)
void cost_xyz_k(const float* __restrict__ xyz, const float* __restrict__ mu,
                const float* __restrict__ yn, float* __restrict__ cost) {
  __shared__ float m0s[64], m1s[64], m2s[64], yl[64];
  int b = blockIdx.y;
  int tid = threadIdx.x;
  if (tid < 64) {
    m0s[tid] = mu[((long)b * 3 + 0) * K_ + tid];
    m1s[tid] = mu[((long)b * 3 + 1) * K_ + tid];
    m2s[tid] = mu[((long)b * 3 + 2) * K_ + tid];
    yl[tid] = yn[b * K_ + tid];
  }
  __syncthreads();
  int n = blockIdx.x * 256 + tid;
  const float* xp = xyz + (long)b * 3 * N_;
  float x0 = xp[n], x1 = xp[N_ + n], x2 = xp[2 * N_ + n];
  float xn = x0 * x0 + x1 * x1 + x2 * x2;
  float* cb = cost + ((long)b * K_) * N_ + n;
  for (int m = 0; m < 64; ++m)
    cb[(long)m * N_] = xn + yl[m] - 2.f * (x0 * m0s[m] + x1 * m1s[m] + x2 * m2s[m]);
}

// ---------------- mu_fea finalize -> n_muT [b][K][D] ----------------
__global__ __launch_bounds__(256)
void mu_finalize(const float* __restrict__ mu_raw, const float* __restrict__ pi,
                 float* __restrict__ n_muT) {
  __shared__ float red[256];
  int k = blockIdx.x, b = blockIdx.y, tid = threadIdx.x;
  float p = pi[b * K_ + k];
  float ss = 0.f;
  for (int d = tid; d < D_; d += 256) {
    float v = mu_raw[((long)b * D_ + d) * K_ + k] / p;
    ss += v * v;
  }
  float tot = block_reduce_sum256(ss, red);
  float inv = 1.f / fmaxf(sqrtf(tot), 1e-12f);
  for (int d = tid; d < D_; d += 256) {
    float v = mu_raw[((long)b * D_ + d) * K_ + k] / p * inv;
    n_muT[((long)b * K_ + k) * D_ + d] = v;
  }
}

// ---------------- feature inverse norms ----------------
__global__ __launch_bounds__(256)
void inv_nrm_k(const float* __restrict__ F, float* __restrict__ invn) {
  int b = blockIdx.y;
  int n = blockIdx.x * 256 + threadIdx.x;
  const float* f = F + (long)b * D_ * N_ + n;
  float s0 = 0, s1 = 0, s2 = 0, s3 = 0;
  for (int d = 0; d < D_; d += 4) {
    float v0 = f[(long)d * N_], v1 = f[(long)(d + 1) * N_];
    float v2 = f[(long)(d + 2) * N_], v3 = f[(long)(d + 3) * N_];
    s0 += v0 * v0; s1 += v1 * v1; s2 += v2 * v2; s3 += v3 * v3;
  }
  float ss = (s0 + s1) + (s2 + s3);
  invn[b * N_ + n] = 1.f / fmaxf(sqrtf(ss), 1e-12f);
}

// ---------------- cost_fea: [K][N] = 2 - 2 * (n_muT @ F) * invn[n] ----------------
__global__ __launch_bounds__(256)
void cost_fea_kn(const float* __restrict__ nmuT, const float* __restrict__ F,
                 const float* __restrict__ invn, float* __restrict__ cost) {
  __shared__ float As[16][64];
  __shared__ float Bs[16][64];
  int b = blockIdx.z;
  int n0 = blockIdx.x * 64;
  const float* Ap = nmuT + (long)b * K_ * D_;
  const float* Bp = F + (long)b * D_ * N_;
  float* Cp = cost + (long)b * K_ * N_;
  int tid = threadIdx.x;
  int tx = tid & 15, ty = tid >> 4;
  int arow = tid >> 2, acol = (tid & 3) * 4;
  int brow = tid >> 4, bcol = (tid & 15) * 4;
  float acc[4][4];
#pragma unroll
  for (int i = 0; i < 4; ++i)
#pragma unroll
    for (int j = 0; j < 4; ++j) acc[i][j] = 0.f;

  for (int k0 = 0; k0 < D_; k0 += 16) {
    float4 av = *(const float4*)(Ap + (long)arow * D_ + k0 + acol);
    float4 bv = *(const float4*)(Bp + (long)(k0 + brow) * N_ + n0 + bcol);
    __syncthreads();
    As[acol + 0][arow] = av.x;
    As[acol + 1][arow] = av.y;
    As[acol + 2][arow] = av.z;
    As[acol + 3][arow] = av.w;
    *(float4*)&Bs[brow][bcol] = bv;
    __syncthreads();
#pragma unroll
    for (int kk = 0; kk < 16; ++kk) {
      float4 a = *(const float4*)&As[kk][ty * 4];
      float4 bq = *(const float4*)&Bs[kk][tx * 4];
      float am[4] = {a.x, a.y, a.z, a.w};
      float bn[4] = {bq.x, bq.y, bq.z, bq.w};
#pragma unroll
      for (int i = 0; i < 4; ++i)
#pragma unroll
        for (int j = 0; j < 4; ++j) acc[i][j] += am[i] * bn[j];
    }
  }
  float4 ivn = *(const float4*)(invn + (long)b * N_ + n0 + tx * 4);
#pragma unroll
  for (int i = 0; i < 4; ++i) {
    int m = ty * 4 + i;
    float4 o;
    o.x = 2.f - 2.f * acc[i][0] * ivn.x;
    o.y = 2.f - 2.f * acc[i][1] * ivn.y;
    o.z = 2.f - 2.f * acc[i][2] * ivn.z;
    o.w = 2.f - 2.f * acc[i][3] * ivn.w;
    *(float4*)(Cp + (long)m * N_ + n0 + tx * 4) = o;
  }
}

// ---------------- cooperative Sinkhorn ----------------
__global__ __launch_bounds__(256, 1)
void sinkhorn_coop(const float* __restrict__ costAll, const float* __restrict__ logpKN,
                   float* __restrict__ out, float* __restrict__ partM,
                   float* __restrict__ partS, unsigned int* __restrict__ cnt) {
  __shared__ float tile[4][64][33];
  __shared__ float vsh[64];
  __shared__ float wm[4][64];
  __shared__ float wsum[4][64];
  __shared__ float red[256];
  const int tid = threadIdx.x;
  const int g = blockIdx.x & 15;
  const int s = blockIdx.x >> 4;
  const int w = tid >> 6, lane = tid & 63;
  const int i = s * 256 + tid;
  const float* C = costAll + (long)g * K_ * N_;
  const float eps = 1e-3f, ti = 1000.0f;
  const float lgp = -8.317766166719343f;
  const float lgq = -4.1588830833596715f;

  float c[64];
#pragma unroll
  for (int j = 0; j < 64; ++j) c[j] = C[(long)j * N_ + i];

  float u = 0.f;
  if (tid < 64) vsh[tid] = 0.f;
  __syncthreads();

  for (int it = 0; it < 25; ++it) {
    float dm = -1e30f;
#pragma unroll
    for (int j = 0; j < 64; ++j) dm = fmaxf(dm, vsh[j] - c[j]);
    float ssum = 0.f;
#pragma unroll
    for (int j = 0; j < 64; ++j) ssum += __expf((vsh[j] - c[j] - dm) * ti);
    float lse = (u + dm) * ti + __logf(ssum);
    u = eps * (lgp - lse) + u;

#pragma unroll
    for (int h = 0; h < 2; ++h) {
#pragma unroll
      for (int j2 = 0; j2 < 32; ++j2) {
        int j = h * 32 + j2;
        tile[w][lane][j2] = (u + vsh[j] - c[j]) * ti;
      }
      __syncthreads();
      int col = lane & 31, rh = lane >> 5;
      float Mh = -1e30f, Sh = 0.f;
#pragma unroll
      for (int r = 0; r < 32; ++r) {
        float a = tile[w][rh * 32 + r][col];
        Mh = fmaxf(Mh, a);
        Sh += __expf(a - lgp);
      }
      float Mo = __shfl_xor(Mh, 32);
      float So = __shfl_xor(Sh, 32);
      Mh = fmaxf(Mh, Mo);
      Sh += So;
      if (rh == 0) { wm[w][h * 32 + col] = Mh; wsum[w][h * 32 + col] = Sh; }
      __syncthreads();
    }
    int buf = it & 1;
    if (tid < 64) {
      float Mb = fmaxf(fmaxf(wm[0][tid], wm[1][tid]), fmaxf(wm[2][tid], wm[3][tid]));
      float Sb = wsum[0][tid] + wsum[1][tid] + wsum[2][tid] + wsum[3][tid];
      long idx = (((long)buf * 16 + g) * 64 + tid) * 16 + s;
      __hip_atomic_store(&partM[idx], Mb, __ATOMIC_RELAXED, __HIP_MEMORY_SCOPE_AGENT);
      __hip_atomic_store(&partS[idx], Sb, __ATOMIC_RELAXED, __HIP_MEMORY_SCOPE_AGENT);
    }
    __syncthreads();
    if (tid == 0) {
      __hip_atomic_fetch_add(&cnt[g * 32], 1u, __ATOMIC_RELEASE, __HIP_MEMORY_SCOPE_AGENT);
      unsigned target = 16u * (unsigned)(it + 1);
      while (__hip_atomic_load(&cnt[g * 32], __ATOMIC_ACQUIRE, __HIP_MEMORY_SCOPE_AGENT) < target)
        __builtin_amdgcn_s_sleep(2);
    }
    __syncthreads();
    if (tid < 64) {
      long base = (((long)buf * 16 + g) * 64 + tid) * 16;
      float M = -1e30f, S = 0.f;
#pragma unroll
      for (int p = 0; p < 16; ++p) {
        M = fmaxf(M, __hip_atomic_load(&partM[base + p], __ATOMIC_RELAXED, __HIP_MEMORY_SCOPE_AGENT));
        S += __hip_atomic_load(&partS[base + p], __ATOMIC_RELAXED, __HIP_MEMORY_SCOPE_AGENT);
      }
      float lsec = fmaxf(M, lgp + __logf(S));
      vsh[tid] = eps * (lgq - lsec) + vsh[tid];
    }
    __syncthreads();
  }

  const float* lp = logpKN + ((long)(g & 7) * K_) * N_ + i;
  float part = 0.f;
#pragma unroll
  for (int j = 0; j < 64; ++j) {
    float gma = __expf((u + vsh[j] - c[j]) * ti);
    part += gma * lp[(long)j * N_];
  }
  red[tid] = part;
  __syncthreads();
  for (int st2 = 128; st2 > 0; st2 >>= 1) {
    if (tid < st2) red[tid] += red[tid + st2];
    __syncthreads();
  }
  if (tid == 0) atomicAdd(out, -red[0] / (float)B_);
}

// ---------------- launch ----------------
extern "C" void kernel_launch(void* const* d_in, const int* in_sizes, int n_in,
                              void* d_out, int out_size, void* d_ws, size_t ws_size,
                              hipStream_t stream) {
  const float* feature = (const float*)d_in[0];
  const float* xyz = (const float*)d_in[1];
  const float* w1 = (const float*)d_in[2];
  const float* b1 = (const float*)d_in[3];
  const float* g1 = (const float*)d_in[4];
  const float* be1 = (const float*)d_in[5];
  const float* w2 = (const float*)d_in[6];
  const float* b2 = (const float*)d_in[7];
  const float* g2 = (const float*)d_in[8];
  const float* be2 = (const float*)d_in[9];
  const float* w3 = (const float*)d_in[10];
  const float* b3 = (const float*)d_in[11];
  float* out = (float*)d_out;
  float* ws = (float*)d_ws;

  const long RSZ = 16777216L;
  float* regA = ws;
  float* regB1 = ws + RSZ;
  float* regB2 = ws + 2 * RSZ;
  float* sm = ws + 3 * RSZ;

  ushort* FhT = (ushort*)regB1;
  ushort* FlT = (ushort*)regB2;
  float* h1raw = regA;
  ushort* h1hT = (ushort*)regB1;
  ushort* h1lT = (ushort*)regB1 + RSZ;
  float* h2 = regB2;
  const long sz_sc = (long)B_ * N_ * K_;
  float* log_score = regA;
  float* scoreT = regA + sz_sc;
  float* logpKN = regA + 2 * sz_sc;
  float* cost_x = regA + 3 * sz_sc;
  float* cost_f = regA + 4 * sz_sc;

  ushort* Wh1 = (ushort*)sm; sm += 262144;
  ushort* Wl1 = (ushort*)sm; sm += 262144;
  ushort* Wh2 = (ushort*)sm; sm += 131072;
  ushort* Wl2 = (ushort*)sm; sm += 131072;
  float* mu_raw = sm; sm += (long)B_ * D_ * K_;
  float* n_muT = sm;  sm += (long)B_ * D_ * K_;
  float* partM = sm;  sm += 2 * 16 * 64 * 16;
  float* partS = sm;  sm += 2 * 16 * 64 * 16;
  unsigned int* cnt = (unsigned int*)sm; sm += 512;
  float* inv_nrm = sm; sm += (long)B_ * N_;
  float* mu_x = sm;   sm += 2048;
  float* yn = sm;     sm += 512;
  float* pi_raw = sm; sm += 512;
  float* pi = sm;     sm += 512;
  float* sc1 = sm; sm += 512;
  float* sh1 = sm; sm += 512;
  float* sc2 = sm; sm += 512;
  float* sh2 = sm; sm += 512;

  hipMemsetAsync(d_out, 0, sizeof(float) * out_size, stream);
  hipMemsetAsync(pi_raw, 0, 512 * sizeof(float), stream);
  hipMemsetAsync(cnt, 0, 512 * sizeof(unsigned int), stream);
  hipMemsetAsync(mu_raw, 0, (long)B_ * D_ * K_ * sizeof(float), stream);

  split_w<<<(H_ * D_) / 256, 256, 0, stream>>>(w1, Wh1, Wl1, H_ * D_);
  split_w<<<(H_ * H_) / 256, 256, 0, stream>>>(w2, Wh2, Wl2, H_ * H_);
  {
    dim3 g(N_ / 64, D_ / 64, B_);
    transpose_split<<<g, 256, 0, stream>>>(feature, FhT, FlT);
  }
  {
    dim3 g(N_ / 128, H_ / 128, B_);
    gemm_split_bf16<<<g, 256, 0, stream>>>(Wh1, Wl1, FhT, FlT, h1raw, b1,
                                           N_, D_, (long)N_ * D_, (long)H_ * N_);
  }
  bn_stats<<<H_, 256, 0, stream>>>(h1raw, g1, be1, sc1, sh1, H_);
  {
    dim3 g(N_ / 64, H_ / 64, B_);
    bn_relu_t<<<g, 256, 0, stream>>>(h1raw, sc1, sh1, h1hT, h1lT);
  }
  {
    dim3 g(N_ / 128, H_ / 128, B_);
    gemm_split_bf16<<<g, 256, 0, stream>>>(Wh2, Wl2, h1hT, h1lT, h2, b2,
                                           N_, H_, (long)N_ * H_, (long)H_ * N_);
  }
  bn_stats<<<H_, 256, 0, stream>>>(h2, g2, be2, sc2, sh2, H_);
  bn_relu<<<(int)((long)B_ * H_ * N_ / 4 / 256), 256, 0, stream>>>(h2, sc2, sh2, H_);
  {
    dim3 g(N_ / 64, K_ / 64, B_);
    sgemm64_nn<<<g, 256, 0, stream>>>(w3, h2, log_score, b3, K_, N_, H_, 0L,
                                      (long)H_ * N_, (long)K_ * N_);
  }
  softmax_k<<<B_ * N_ / 256, 256, 0, stream>>>(log_score, scoreT, logpKN, pi_raw);
  pi_fin<<<2, 256, 0, stream>>>(pi_raw, pi);
  {
    dim3 g(K_, B_);
    mu_xyz_k<<<g, 64, 0, stream>>>(scoreT, xyz, pi, mu_x, yn);
  }
  reg_xyz_k<<<B_, 256, 0, stream>>>(mu_x, out);
  {
    dim3 g(N_ / 256, B_);
    cost_xyz_k<<<g, 256, 0, stream>>>(xyz, mu_x, yn, cost_x);
  }
  {
    dim3 g(8, D_ / 64, B_);
    mu_fea_split<<<g, 256, 0, stream>>>(feature, scoreT, mu_raw);
  }
  {
    dim3 g(K_, B_);
    mu_finalize<<<g, 256, 0, stream>>>(mu_raw, pi, n_muT);
  }
  {
    dim3 g(K_, B_);
    reg_fea_k<<<g, 256, 0, stream>>>(n_muT, out);
  }
  {
    dim3 g(N_ / 256, B_);
    inv_nrm_k<<<g, 256, 0, stream>>>(feature, inv_nrm);
  }
  {
    dim3 g(N_ / 64, 1, B_);
    cost_fea_kn<<<g, 256, 0, stream>>>(n_muT, feature, inv_nrm, cost_f);
  }
  {
    void* kargs[] = {(void*)&cost_x, (void*)&logpKN, (void*)&out,
                     (void*)&partM, (void*)&partS, (void*)&cnt};
    hipLaunchCooperativeKernel((const void*)sinkhorn_coop, dim3(256), dim3(256),
                               kargs, 0, stream);
  }
}

// Round 5
// 1321.264 us; speedup vs baseline: 4.7133x; 1.0711x over previous
//
#include <hip/hip_runtime.h>
#include <math.h>

#define B_ 8
#define D_ 1024
#define N_ 4096
#define K_ 64
#define H_ 512

typedef short sx8 __attribute__((ext_vector_type(8)));
typedef float fx4 __attribute__((ext_vector_type(4)));

// ---------------- helpers ----------------
__device__ __forceinline__ float block_reduce_sum256(float v, float* sm) {
  int tid = threadIdx.x;
  sm[tid] = v;
  __syncthreads();
  for (int s = 128; s > 0; s >>= 1) {
    if (tid < s) sm[tid] += sm[tid + s];
    __syncthreads();
  }
  float r = sm[0];
  __syncthreads();
  return r;
}

__device__ __forceinline__ ushort f2bf(float f) {
  unsigned u = __float_as_uint(f);
  unsigned r = (u + 0x7fffu + ((u >> 16) & 1u)) >> 16;
  return (ushort)r;
}
__device__ __forceinline__ float bf2f(ushort h) {
  return __uint_as_float(((unsigned)h) << 16);
}

// ---------------- weight split: f32 -> bf16 hi/lo ----------------
__global__ __launch_bounds__(256)
void split_w(const float* __restrict__ W, ushort* __restrict__ Wh,
             ushort* __restrict__ Wl, int n) {
  int i = blockIdx.x * 256 + threadIdx.x;
  if (i < n) {
    float f = W[i];
    ushort h = f2bf(f);
    Wh[i] = h;
    Wl[i] = f2bf(f - bf2f(h));
  }
}

// ---------------- feature transpose+split: [B][D][N] f32 -> [B][N][D] bf16 hi/lo ----
__global__ __launch_bounds__(256)
void transpose_split(const float* __restrict__ F, ushort* __restrict__ FhT,
                     ushort* __restrict__ FlT) {
  __shared__ float tile[64][65];
  int b = blockIdx.z, d0 = blockIdx.y * 64, n0 = blockIdx.x * 64;
  const float* src = F + ((long)b * D_ + d0) * N_ + n0;
  int t = threadIdx.x;
  int rr4 = t >> 4, c4 = (t & 15) * 4;
#pragma unroll
  for (int p = 0; p < 4; ++p) {
    int dr = p * 16 + rr4;
    float4 v = *(const float4*)(src + (long)dr * N_ + c4);
    tile[dr][c4 + 0] = v.x;
    tile[dr][c4 + 1] = v.y;
    tile[dr][c4 + 2] = v.z;
    tile[dr][c4 + 3] = v.w;
  }
  __syncthreads();
  int nlb = t >> 3, ds = (t & 7) * 8;
#pragma unroll
  for (int p = 0; p < 2; ++p) {
    int nl = p * 32 + nlb;
    sx8 hv, lv;
#pragma unroll
    for (int j = 0; j < 8; ++j) {
      float f = tile[ds + j][nl];
      ushort h = f2bf(f);
      hv[j] = (short)h;
      lv[j] = (short)f2bf(f - bf2f(h));
    }
    long o = ((long)b * N_ + n0 + nl) * D_ + d0 + ds;
    *(sx8*)(FhT + o) = hv;
    *(sx8*)(FlT + o) = lv;
  }
}

// ---------------- 128x128 split-bf16 MFMA GEMM (conv1/conv2) ----------------
__global__ __launch_bounds__(256)
void gemm_split_bf16(const ushort* __restrict__ Ah, const ushort* __restrict__ Al,
                     const ushort* __restrict__ BhT, const ushort* __restrict__ BlT,
                     float* __restrict__ C, const float* __restrict__ bias,
                     int N, int Kd, long sBT, long sC) {
  __shared__ ushort As[2][128][40];
  __shared__ ushort Bs[2][128][40];
  const int t = threadIdx.x;
  const int m0 = blockIdx.y * 128, n0 = blockIdx.x * 128;
  const long bo = (long)blockIdx.z * sBT;
  float* Cp = C + (long)blockIdx.z * sC;
  const int half = t >> 7, r = t & 127;
  const ushort* Asrc = (half ? Al : Ah) + (long)(m0 + r) * Kd;
  const ushort* Bsrc = (half ? BlT : BhT) + bo + (long)(n0 + r) * Kd;
  ushort* AsD = &As[half][r][0];
  ushort* BsD = &Bs[half][r][0];
  const int w = t >> 6, ln = t & 15, qd = (t & 63) >> 4;
  const int wm = w >> 1, wn = w & 1;

  fx4 acc[4][4];
#pragma unroll
  for (int i = 0; i < 4; ++i)
#pragma unroll
    for (int j = 0; j < 4; ++j) acc[i][j] = (fx4)0.f;

  for (int k0 = 0; k0 < Kd; k0 += 32) {
    uint4 a0 = *(const uint4*)(Asrc + k0);
    uint4 a1 = *(const uint4*)(Asrc + k0 + 8);
    uint4 a2 = *(const uint4*)(Asrc + k0 + 16);
    uint4 a3 = *(const uint4*)(Asrc + k0 + 24);
    uint4 b0 = *(const uint4*)(Bsrc + k0);
    uint4 b1 = *(const uint4*)(Bsrc + k0 + 8);
    uint4 b2 = *(const uint4*)(Bsrc + k0 + 16);
    uint4 b3 = *(const uint4*)(Bsrc + k0 + 24);
    __syncthreads();
    *(uint4*)(AsD + 0) = a0;
    *(uint4*)(AsD + 8) = a1;
    *(uint4*)(AsD + 16) = a2;
    *(uint4*)(AsD + 24) = a3;
    *(uint4*)(BsD + 0) = b0;
    *(uint4*)(BsD + 8) = b1;
    *(uint4*)(BsD + 16) = b2;
    *(uint4*)(BsD + 24) = b3;
    __syncthreads();
    sx8 ahf[4], alf[4], bhf[4], blf[4];
#pragma unroll
    for (int mt = 0; mt < 4; ++mt) {
      ahf[mt] = *(const sx8*)&As[0][wm * 64 + mt * 16 + ln][qd * 8];
      alf[mt] = *(const sx8*)&As[1][wm * 64 + mt * 16 + ln][qd * 8];
    }
#pragma unroll
    for (int nt = 0; nt < 4; ++nt) {
      bhf[nt] = *(const sx8*)&Bs[0][wn * 64 + nt * 16 + ln][qd * 8];
      blf[nt] = *(const sx8*)&Bs[1][wn * 64 + nt * 16 + ln][qd * 8];
    }
#pragma unroll
    for (int mt = 0; mt < 4; ++mt)
#pragma unroll
      for (int nt = 0; nt < 4; ++nt) {
        acc[mt][nt] = __builtin_amdgcn_mfma_f32_16x16x32_bf16(ahf[mt], bhf[nt], acc[mt][nt], 0, 0, 0);
        acc[mt][nt] = __builtin_amdgcn_mfma_f32_16x16x32_bf16(alf[mt], bhf[nt], acc[mt][nt], 0, 0, 0);
        acc[mt][nt] = __builtin_amdgcn_mfma_f32_16x16x32_bf16(ahf[mt], blf[nt], acc[mt][nt], 0, 0, 0);
      }
  }
#pragma unroll
  for (int mt = 0; mt < 4; ++mt) {
#pragma unroll
    for (int rr = 0; rr < 4; ++rr) {
      int row = m0 + wm * 64 + mt * 16 + qd * 4 + rr;
      float bb = bias[row];
#pragma unroll
      for (int nt = 0; nt < 4; ++nt) {
        int col = n0 + wn * 64 + nt * 16 + ln;
        Cp[(long)row * N + col] = acc[mt][nt][rr] + bb;
      }
    }
  }
}

// ================= M64 split-bf16 MFMA family: 64x128 tile, 2x2 waves =================
// fragment mapping identical to gemm_split_bf16 (16x16x32 bf16).

// --- variant bb: A pre-split [64][Kd], B pre-split transposed [Nc][Kd] (conv3) ---
__global__ __launch_bounds__(256)
void gemm64_bb(const ushort* __restrict__ Ah, const ushort* __restrict__ Al,
               const ushort* __restrict__ BhT, const ushort* __restrict__ BlT,
               float* __restrict__ C, const float* __restrict__ bias,
               int N, int Kd, long sBT, long sC) {
  __shared__ ushort As[2][64][40];
  __shared__ ushort Bs[2][128][40];
  const int t = threadIdx.x;
  const int n0 = blockIdx.x * 128;
  float* Cp = C + (long)blockIdx.z * sC;
  const int hB = t >> 7, rB = t & 127;
  const ushort* Bsrc = (hB ? BlT : BhT) + (long)blockIdx.z * sBT + (long)(n0 + rB) * Kd;
  ushort* BsD = &Bs[hB][rB][0];
  const bool doA = t < 128;
  const int hA = (t >> 6) & 1, rA = t & 63;
  const ushort* Asrc = (hA ? Al : Ah) + (long)rA * Kd;
  ushort* AsD = &As[hA][rA][0];
  const int w = t >> 6, ln = t & 15, qd = (t & 63) >> 4;
  const int wm = w >> 1, wn = w & 1;

  fx4 acc[2][4];
#pragma unroll
  for (int i = 0; i < 2; ++i)
#pragma unroll
    for (int j = 0; j < 4; ++j) acc[i][j] = (fx4)0.f;

  for (int k0 = 0; k0 < Kd; k0 += 32) {
    uint4 b0 = *(const uint4*)(Bsrc + k0);
    uint4 b1 = *(const uint4*)(Bsrc + k0 + 8);
    uint4 b2 = *(const uint4*)(Bsrc + k0 + 16);
    uint4 b3 = *(const uint4*)(Bsrc + k0 + 24);
    uint4 a0, a1, a2, a3;
    if (doA) {
      a0 = *(const uint4*)(Asrc + k0);
      a1 = *(const uint4*)(Asrc + k0 + 8);
      a2 = *(const uint4*)(Asrc + k0 + 16);
      a3 = *(const uint4*)(Asrc + k0 + 24);
    }
    __syncthreads();
    *(uint4*)(BsD + 0) = b0;
    *(uint4*)(BsD + 8) = b1;
    *(uint4*)(BsD + 16) = b2;
    *(uint4*)(BsD + 24) = b3;
    if (doA) {
      *(uint4*)(AsD + 0) = a0;
      *(uint4*)(AsD + 8) = a1;
      *(uint4*)(AsD + 16) = a2;
      *(uint4*)(AsD + 24) = a3;
    }
    __syncthreads();
    sx8 ahf[2], alf[2], bhf[4], blf[4];
#pragma unroll
    for (int mt = 0; mt < 2; ++mt) {
      ahf[mt] = *(const sx8*)&As[0][wm * 32 + mt * 16 + ln][qd * 8];
      alf[mt] = *(const sx8*)&As[1][wm * 32 + mt * 16 + ln][qd * 8];
    }
#pragma unroll
    for (int nt = 0; nt < 4; ++nt) {
      bhf[nt] = *(const sx8*)&Bs[0][wn * 64 + nt * 16 + ln][qd * 8];
      blf[nt] = *(const sx8*)&Bs[1][wn * 64 + nt * 16 + ln][qd * 8];
    }
#pragma unroll
    for (int mt = 0; mt < 2; ++mt)
#pragma unroll
      for (int nt = 0; nt < 4; ++nt) {
        acc[mt][nt] = __builtin_amdgcn_mfma_f32_16x16x32_bf16(ahf[mt], bhf[nt], acc[mt][nt], 0, 0, 0);
        acc[mt][nt] = __builtin_amdgcn_mfma_f32_16x16x32_bf16(alf[mt], bhf[nt], acc[mt][nt], 0, 0, 0);
        acc[mt][nt] = __builtin_amdgcn_mfma_f32_16x16x32_bf16(ahf[mt], blf[nt], acc[mt][nt], 0, 0, 0);
      }
  }
#pragma unroll
  for (int mt = 0; mt < 2; ++mt)
#pragma unroll
    for (int rr = 0; rr < 4; ++rr) {
      int row = wm * 32 + mt * 16 + qd * 4 + rr;
      float bb = bias[row];
#pragma unroll
      for (int nt = 0; nt < 4; ++nt) {
        int col = n0 + wn * 64 + nt * 16 + ln;
        Cp[(long)row * N + col] = acc[mt][nt][rr] + bb;
      }
    }
}

// --- variant bf: A pre-split [b][64][N_], B = f32 rows natural along Kd (mu_fea) ---
// C^T form: muT[b][64 k][1024 d] += score[k][n] * F[d][n], Kd-range split by blockIdx.y
__global__ __launch_bounds__(256)
void gemm64_bf(const ushort* __restrict__ Ah, const ushort* __restrict__ Al,
               const float* __restrict__ Bf, float* __restrict__ Cacc) {
  __shared__ ushort As[2][64][40];
  __shared__ ushort Bs[2][128][40];
  const int t = threadIdx.x;
  const int nc0 = blockIdx.x * 128;          // d-range
  const int kBeg = blockIdx.y * 1024;        // n-range chunk
  const int b = blockIdx.z;
  const int pc = t >> 7, rB = t & 127;
  const float* Bsrc = Bf + (long)b * D_ * N_ + (long)(nc0 + rB) * N_ + kBeg + pc * 16;
  const bool doA = t < 128;
  const int hA = (t >> 6) & 1, rA = t & 63;
  const ushort* Asrc = (hA ? Al : Ah) + (long)b * K_ * N_ + (long)rA * N_ + kBeg;
  ushort* AsD = &As[hA][rA][0];
  const int w = t >> 6, ln = t & 15, qd = (t & 63) >> 4;
  const int wm = w >> 1, wn = w & 1;

  fx4 acc[2][4];
#pragma unroll
  for (int i = 0; i < 2; ++i)
#pragma unroll
    for (int j = 0; j < 4; ++j) acc[i][j] = (fx4)0.f;

  for (int k0 = 0; k0 < 1024; k0 += 32) {
    float4 f0 = *(const float4*)(Bsrc + k0);
    float4 f1 = *(const float4*)(Bsrc + k0 + 4);
    float4 f2 = *(const float4*)(Bsrc + k0 + 8);
    float4 f3 = *(const float4*)(Bsrc + k0 + 12);
    uint4 a0, a1, a2, a3;
    if (doA) {
      a0 = *(const uint4*)(Asrc + k0);
      a1 = *(const uint4*)(Asrc + k0 + 8);
      a2 = *(const uint4*)(Asrc + k0 + 16);
      a3 = *(const uint4*)(Asrc + k0 + 24);
    }
    float fv[16] = {f0.x, f0.y, f0.z, f0.w, f1.x, f1.y, f1.z, f1.w,
                    f2.x, f2.y, f2.z, f2.w, f3.x, f3.y, f3.z, f3.w};
    sx8 hv0, hv1, lv0, lv1;
#pragma unroll
    for (int j = 0; j < 8; ++j) {
      ushort h = f2bf(fv[j]);
      hv0[j] = (short)h;
      lv0[j] = (short)f2bf(fv[j] - bf2f(h));
    }
#pragma unroll
    for (int j = 0; j < 8; ++j) {
      ushort h = f2bf(fv[8 + j]);
      hv1[j] = (short)h;
      lv1[j] = (short)f2bf(fv[8 + j] - bf2f(h));
    }
    __syncthreads();
    *(sx8*)&Bs[0][rB][pc * 16] = hv0;
    *(sx8*)&Bs[0][rB][pc * 16 + 8] = hv1;
    *(sx8*)&Bs[1][rB][pc * 16] = lv0;
    *(sx8*)&Bs[1][rB][pc * 16 + 8] = lv1;
    if (doA) {
      *(uint4*)(AsD + 0) = a0;
      *(uint4*)(AsD + 8) = a1;
      *(uint4*)(AsD + 16) = a2;
      *(uint4*)(AsD + 24) = a3;
    }
    __syncthreads();
    sx8 ahf[2], alf[2], bhf[4], blf[4];
#pragma unroll
    for (int mt = 0; mt < 2; ++mt) {
      ahf[mt] = *(const sx8*)&As[0][wm * 32 + mt * 16 + ln][qd * 8];
      alf[mt] = *(const sx8*)&As[1][wm * 32 + mt * 16 + ln][qd * 8];
    }
#pragma unroll
    for (int nt = 0; nt < 4; ++nt) {
      bhf[nt] = *(const sx8*)&Bs[0][wn * 64 + nt * 16 + ln][qd * 8];
      blf[nt] = *(const sx8*)&Bs[1][wn * 64 + nt * 16 + ln][qd * 8];
    }
#pragma unroll
    for (int mt = 0; mt < 2; ++mt)
#pragma unroll
      for (int nt = 0; nt < 4; ++nt) {
        acc[mt][nt] = __builtin_amdgcn_mfma_f32_16x16x32_bf16(ahf[mt], bhf[nt], acc[mt][nt], 0, 0, 0);
        acc[mt][nt] = __builtin_amdgcn_mfma_f32_16x16x32_bf16(alf[mt], bhf[nt], acc[mt][nt], 0, 0, 0);
        acc[mt][nt] = __builtin_amdgcn_mfma_f32_16x16x32_bf16(ahf[mt], blf[nt], acc[mt][nt], 0, 0, 0);
      }
  }
#pragma unroll
  for (int mt = 0; mt < 2; ++mt)
#pragma unroll
    for (int rr = 0; rr < 4; ++rr) {
      int row = wm * 32 + mt * 16 + qd * 4 + rr;
#pragma unroll
      for (int nt = 0; nt < 4; ++nt) {
        int col = nc0 + wn * 64 + nt * 16 + ln;
        atomicAdd(&Cacc[((long)b * K_ + row) * D_ + col], acc[mt][nt][rr]);
      }
    }
}

// --- variant bt: A pre-split [b][64][D_], B = f32 [D][N] needing transpose (cost_fea) ---
__global__ __launch_bounds__(256)
void gemm64_bt(const ushort* __restrict__ Ah, const ushort* __restrict__ Al,
               const float* __restrict__ Bf, const float* __restrict__ invn,
               float* __restrict__ cost) {
  __shared__ ushort As[2][64][40];
  __shared__ ushort Bs[2][128][40];
  __shared__ float Ft[32][132];
  const int t = threadIdx.x;
  const int n0 = blockIdx.x * 128;
  const int b = blockIdx.z;
  const float* Fsrc = Bf + (long)b * D_ * N_;
  const bool doA = t < 128;
  const int hA = (t >> 6) & 1, rA = t & 63;
  const ushort* Asrc = (hA ? Al : Ah) + (long)b * K_ * D_ + (long)rA * D_;
  ushort* AsD = &As[hA][rA][0];
  const int dr = t >> 3, cc = (t & 7) * 16;
  const int nl = t & 127, dh = t >> 7;
  const int w = t >> 6, ln = t & 15, qd = (t & 63) >> 4;
  const int wm = w >> 1, wn = w & 1;

  fx4 acc[2][4];
#pragma unroll
  for (int i = 0; i < 2; ++i)
#pragma unroll
    for (int j = 0; j < 4; ++j) acc[i][j] = (fx4)0.f;

  for (int k0 = 0; k0 < D_; k0 += 32) {
    float4 f0 = *(const float4*)(Fsrc + (long)(k0 + dr) * N_ + n0 + cc);
    float4 f1 = *(const float4*)(Fsrc + (long)(k0 + dr) * N_ + n0 + cc + 4);
    float4 f2 = *(const float4*)(Fsrc + (long)(k0 + dr) * N_ + n0 + cc + 8);
    float4 f3 = *(const float4*)(Fsrc + (long)(k0 + dr) * N_ + n0 + cc + 12);
    uint4 a0, a1, a2, a3;
    if (doA) {
      a0 = *(const uint4*)(Asrc + k0);
      a1 = *(const uint4*)(Asrc + k0 + 8);
      a2 = *(const uint4*)(Asrc + k0 + 16);
      a3 = *(const uint4*)(Asrc + k0 + 24);
    }
    __syncthreads();  // prev iter frag reads done
    *(float4*)&Ft[dr][cc] = f0;
    *(float4*)&Ft[dr][cc + 4] = f1;
    *(float4*)&Ft[dr][cc + 8] = f2;
    *(float4*)&Ft[dr][cc + 12] = f3;
    if (doA) {
      *(uint4*)(AsD + 0) = a0;
      *(uint4*)(AsD + 8) = a1;
      *(uint4*)(AsD + 16) = a2;
      *(uint4*)(AsD + 24) = a3;
    }
    __syncthreads();
    // transpose-convert: thread owns column nl, d-range dh*16..+16
    float fv[16];
#pragma unroll
    for (int j = 0; j < 16; ++j) fv[j] = Ft[dh * 16 + j][nl];
    sx8 hv0, hv1, lv0, lv1;
#pragma unroll
    for (int j = 0; j < 8; ++j) {
      ushort h = f2bf(fv[j]);
      hv0[j] = (short)h;
      lv0[j] = (short)f2bf(fv[j] - bf2f(h));
    }
#pragma unroll
    for (int j = 0; j < 8; ++j) {
      ushort h = f2bf(fv[8 + j]);
      hv1[j] = (short)h;
      lv1[j] = (short)f2bf(fv[8 + j] - bf2f(h));
    }
    *(sx8*)&Bs[0][nl][dh * 16] = hv0;
    *(sx8*)&Bs[0][nl][dh * 16 + 8] = hv1;
    *(sx8*)&Bs[1][nl][dh * 16] = lv0;
    *(sx8*)&Bs[1][nl][dh * 16 + 8] = lv1;
    __syncthreads();
    sx8 ahf[2], alf[2], bhf[4], blf[4];
#pragma unroll
    for (int mt = 0; mt < 2; ++mt) {
      ahf[mt] = *(const sx8*)&As[0][wm * 32 + mt * 16 + ln][qd * 8];
      alf[mt] = *(const sx8*)&As[1][wm * 32 + mt * 16 + ln][qd * 8];
    }
#pragma unroll
    for (int nt = 0; nt < 4; ++nt) {
      bhf[nt] = *(const sx8*)&Bs[0][wn * 64 + nt * 16 + ln][qd * 8];
      blf[nt] = *(const sx8*)&Bs[1][wn * 64 + nt * 16 + ln][qd * 8];
    }
#pragma unroll
    for (int mt = 0; mt < 2; ++mt)
#pragma unroll
      for (int nt = 0; nt < 4; ++nt) {
        acc[mt][nt] = __builtin_amdgcn_mfma_f32_16x16x32_bf16(ahf[mt], bhf[nt], acc[mt][nt], 0, 0, 0);
        acc[mt][nt] = __builtin_amdgcn_mfma_f32_16x16x32_bf16(alf[mt], bhf[nt], acc[mt][nt], 0, 0, 0);
        acc[mt][nt] = __builtin_amdgcn_mfma_f32_16x16x32_bf16(ahf[mt], blf[nt], acc[mt][nt], 0, 0, 0);
      }
  }
#pragma unroll
  for (int nt = 0; nt < 4; ++nt) {
    int col = n0 + wn * 64 + nt * 16 + ln;
    float iv = invn[b * N_ + col];
#pragma unroll
    for (int mt = 0; mt < 2; ++mt)
#pragma unroll
      for (int rr = 0; rr < 4; ++rr) {
        int row = wm * 32 + mt * 16 + qd * 4 + rr;
        cost[((long)b * K_ + row) * N_ + col] = 2.f - 2.f * acc[mt][nt][rr] * iv;
      }
  }
}

// ---------------- BN stats ----------------
__global__ __launch_bounds__(256)
void bn_stats(const float* __restrict__ Y, const float* __restrict__ g,
              const float* __restrict__ be, float* __restrict__ scale,
              float* __restrict__ shift, int C) {
  int c = blockIdx.x;
  double s1 = 0.0, s2 = 0.0;
  for (int idx = threadIdx.x; idx < B_ * N_; idx += 256) {
    int b = idx >> 12, n = idx & (N_ - 1);
    float v = Y[((long)b * C + c) * N_ + n];
    s1 += v;
    s2 += (double)v * (double)v;
  }
  __shared__ double r1[256], r2[256];
  int tid = threadIdx.x;
  r1[tid] = s1; r2[tid] = s2;
  __syncthreads();
  for (int s = 128; s > 0; s >>= 1) {
    if (tid < s) { r1[tid] += r1[tid + s]; r2[tid] += r2[tid + s]; }
    __syncthreads();
  }
  if (tid == 0) {
    double m = r1[0] / (double)(B_ * N_);
    double var = r2[0] / (double)(B_ * N_) - m * m;
    float sc = (float)((double)g[c] / sqrt(var + 1e-5));
    scale[c] = sc;
    shift[c] = (float)((double)be[c] - m * (double)sc);
  }
}

// ---------------- BN+ReLU + transpose+split: [B][512][N] f32 -> [B][N][512] bf16 hi/lo
__global__ __launch_bounds__(256)
void bn_relu_t(const float* __restrict__ Y, const float* __restrict__ scale,
               const float* __restrict__ shift, ushort* __restrict__ OhT,
               ushort* __restrict__ OlT) {
  __shared__ float tile[64][65];
  int b = blockIdx.z, h0 = blockIdx.y * 64, n0 = blockIdx.x * 64;
  const float* src = Y + ((long)b * H_ + h0) * N_ + n0;
  int t = threadIdx.x;
  int rr4 = t >> 4, c4 = (t & 15) * 4;
#pragma unroll
  for (int p = 0; p < 4; ++p) {
    int hl = p * 16 + rr4;
    float sc = scale[h0 + hl], sh = shift[h0 + hl];
    float4 v = *(const float4*)(src + (long)hl * N_ + c4);
    tile[hl][c4 + 0] = fmaxf(v.x * sc + sh, 0.f);
    tile[hl][c4 + 1] = fmaxf(v.y * sc + sh, 0.f);
    tile[hl][c4 + 2] = fmaxf(v.z * sc + sh, 0.f);
    tile[hl][c4 + 3] = fmaxf(v.w * sc + sh, 0.f);
  }
  __syncthreads();
  int nlb = t >> 3, hs = (t & 7) * 8;
#pragma unroll
  for (int p = 0; p < 2; ++p) {
    int nl = p * 32 + nlb;
    sx8 hv, lv;
#pragma unroll
    for (int j = 0; j < 8; ++j) {
      float f = tile[hs + j][nl];
      ushort h = f2bf(f);
      hv[j] = (short)h;
      lv[j] = (short)f2bf(f - bf2f(h));
    }
    long o = ((long)b * N_ + n0 + nl) * H_ + h0 + hs;
    *(sx8*)(OhT + o) = hv;
    *(sx8*)(OlT + o) = lv;
  }
}

// ---------------- softmax: ls [b][K][N] -> score [b][K][N] f32 + bf16 hi/lo, logp [b][n][K]
__global__ __launch_bounds__(256)
void softmax_nk(const float* __restrict__ ls, float* __restrict__ scoreKN,
                ushort* __restrict__ sch, ushort* __restrict__ scl,
                float* __restrict__ logpNK, float* __restrict__ pi_raw) {
  __shared__ float L[64][65];
  __shared__ float ploc[64];
  int tid = threadIdx.x;
  if (tid < 64) ploc[tid] = 0.f;
  __syncthreads();
  int bi = blockIdx.x >> 4;           // 16 blocks per batch
  int nb = (blockIdx.x & 15) * 256;
  int n = nb + tid;
  const float* x = ls + ((long)bi * K_) * N_ + n;
  float xv[64];
#pragma unroll
  for (int k = 0; k < 64; ++k) xv[k] = x[(long)k * N_];
  float mx = -1e30f;
#pragma unroll
  for (int k = 0; k < 64; ++k) mx = fmaxf(mx, xv[k]);
  float s = 0.f;
#pragma unroll
  for (int k = 0; k < 64; ++k) s += __expf(xv[k] - mx);
  float lg = __logf(s);
  float inv = 1.f / s;
#pragma unroll
  for (int k = 0; k < 64; ++k) {
    float sc = __expf(xv[k] - mx) * inv;
    long o = ((long)bi * K_ + k) * N_ + n;
    scoreKN[o] = sc;
    ushort h = f2bf(sc);
    sch[o] = h;
    scl[o] = f2bf(sc - bf2f(h));
    atomicAdd(&ploc[k], sc);
  }
  __syncthreads();
  if (tid < 64) atomicAdd(&pi_raw[bi * 64 + tid], ploc[tid]);
  // logp -> [n][K] via LDS bounce, 4 sub-batches of 64 n
  int myw = tid >> 6, nl = tid & 63;
  int row = tid >> 2, ch = (tid & 3) * 16;
  for (int p = 0; p < 4; ++p) {
    __syncthreads();
    if (myw == p) {
#pragma unroll
      for (int k = 0; k < 64; ++k) L[nl][k] = xv[k] - mx - lg;
    }
    __syncthreads();
    float o0[16];
#pragma unroll
    for (int j = 0; j < 16; ++j) o0[j] = L[row][ch + j];
    float* dst = logpNK + ((long)bi * N_ + nb + p * 64 + row) * 64 + ch;
    *(float4*)(dst + 0) = make_float4(o0[0], o0[1], o0[2], o0[3]);
    *(float4*)(dst + 4) = make_float4(o0[4], o0[5], o0[6], o0[7]);
    *(float4*)(dst + 8) = make_float4(o0[8], o0[9], o0[10], o0[11]);
    *(float4*)(dst + 12) = make_float4(o0[12], o0[13], o0[14], o0[15]);
  }
}

// ---------------- mu_xyz (score [b][K][N] coalesced) ----------------
__global__ __launch_bounds__(64)
void mu_xyz_k(const float* __restrict__ scoreKN, const float* __restrict__ xyz,
              const float* __restrict__ pi_raw, float* __restrict__ mu,
              float* __restrict__ yn) {
  int k = blockIdx.x, b = blockIdx.y, t = threadIdx.x;
  const float* st = scoreKN + ((long)b * K_ + k) * N_;
  const float* xp = xyz + (long)b * 3 * N_;
  float a0 = 0, a1 = 0, a2 = 0;
  for (int n = t; n < N_; n += 64) {
    float s = st[n];
    a0 += s * xp[n];
    a1 += s * xp[N_ + n];
    a2 += s * xp[2 * N_ + n];
  }
  for (int off = 32; off > 0; off >>= 1) {
    a0 += __shfl_down(a0, off);
    a1 += __shfl_down(a1, off);
    a2 += __shfl_down(a2, off);
  }
  if (t == 0) {
    float p = fmaxf(pi_raw[b * K_ + k], 1e-4f);
    float m0 = a0 / p, m1 = a1 / p, m2 = a2 / p;
    mu[((long)b * 3 + 0) * K_ + k] = m0;
    mu[((long)b * 3 + 1) * K_ + k] = m1;
    mu[((long)b * 3 + 2) * K_ + k] = m2;
    yn[b * K_ + k] = m0 * m0 + m1 * m1 + m2 * m2;
  }
}

// ---------------- regularizers ----------------
__global__ __launch_bounds__(256)
void reg_xyz_k(const float* __restrict__ mu, float* __restrict__ out) {
  __shared__ float red[256];
  int b = blockIdx.x, tid = threadIdx.x;
  float acc = 0.f;
  for (int e = tid; e < 4096; e += 256) {
    int m = e >> 6, n2 = e & 63;
    float g = 0.f;
    for (int d = 0; d < 3; ++d)
      g += mu[((long)b * 3 + d) * K_ + m] * mu[((long)b * 3 + d) * K_ + n2];
    acc += fabsf(g - (m == n2 ? 1.f : 0.f));
  }
  float tot = block_reduce_sum256(acc, red);
  if (tid == 0) atomicAdd(out, tot * (1e-7f / 32768.f));
}

__global__ __launch_bounds__(256)
void reg_fea_k(const float* __restrict__ nT, float* __restrict__ out) {
  __shared__ float pm[1024];
  __shared__ float red[256];
  int m = blockIdx.x, b = blockIdx.y, tid = threadIdx.x;
  const float* base = nT + (long)b * K_ * D_;
  *(float4*)&pm[tid * 4] = *(const float4*)(base + (long)m * D_ + tid * 4);
  __syncthreads();
  int n2 = tid >> 2, q = tid & 3;
  const float* pn = base + (long)n2 * D_ + q * 256;
  const float* pml = &pm[q * 256];
  float g = 0.f;
#pragma unroll 8
  for (int d = 0; d < 256; d += 4) {
    float4 v = *(const float4*)(pn + d);
    g += v.x * pml[d] + v.y * pml[d + 1] + v.z * pml[d + 2] + v.w * pml[d + 3];
  }
  g += __shfl_down(g, 2);
  g += __shfl_down(g, 1);
  float acc = (q == 0) ? fabsf(g - (m == n2 ? 1.f : 0.f)) : 0.f;
  float tot = block_reduce_sum256(acc, red);
  if (tid == 0) atomicAdd(out, tot * (1e-4f / 32768.f));
}

// ---------------- cost_xyz -> [b][K][N] ----------------
__global__ __launch_bounds__(256)
void cost_xyz_k(const float* __restrict__ xyz, const float* __restrict__ mu,
                const float* __restrict__ yn, float* __restrict__ cost) {
  __shared__ float m0s[64], m1s[64], m2s[64], yl[64];
  int b = blockIdx.y;
  int tid = threadIdx.x;
  if (tid < 64) {
    m0s[tid] = mu[((long)b * 3 + 0) * K_ + tid];
    m1s[tid] = mu[((long)b * 3 + 1) * K_ + tid];
    m2s[tid] = mu[((long)b * 3 + 2) * K_ + tid];
    yl[tid] = yn[b * K_ + tid];
  }
  __syncthreads();
  int n = blockIdx.x * 256 + tid;
  const float* xp = xyz + (long)b * 3 * N_;
  float x0 = xp[n], x1 = xp[N_ + n], x2 = xp[2 * N_ + n];
  float xn = x0 * x0 + x1 * x1 + x2 * x2;
  float* cb = cost + ((long)b * K_) * N_ + n;
  for (int m = 0; m < 64; ++m)
    cb[(long)m * N_] = xn + yl[m] - 2.f * (x0 * m0s[m] + x1 * m1s[m] + x2 * m2s[m]);
}

// ---------------- mu_fea finalize: muT_raw [b][64][1024] -> n_muT f32 + bf16 hi/lo ----
__global__ __launch_bounds__(256)
void mu_finalize(const float* __restrict__ muT_raw, const float* __restrict__ pi_raw,
                 float* __restrict__ n_muT, ushort* __restrict__ nmu_h,
                 ushort* __restrict__ nmu_l) {
  __shared__ float red[256];
  int k = blockIdx.x, b = blockIdx.y, tid = threadIdx.x;
  float p = fmaxf(pi_raw[b * K_ + k], 1e-4f);
  const float* src = muT_raw + ((long)b * K_ + k) * D_;
  float ss = 0.f;
  for (int d = tid; d < D_; d += 256) {
    float v = src[d] / p;
    ss += v * v;
  }
  float tot = block_reduce_sum256(ss, red);
  float inv = 1.f / fmaxf(sqrtf(tot), 1e-12f);
  long o = ((long)b * K_ + k) * D_;
  for (int d = tid; d < D_; d += 256) {
    float v = src[d] / p * inv;
    n_muT[o + d] = v;
    ushort h = f2bf(v);
    nmu_h[o + d] = h;
    nmu_l[o + d] = f2bf(v - bf2f(h));
  }
}

// ---------------- feature inverse norms ----------------
__global__ __launch_bounds__(256)
void inv_nrm_k(const float* __restrict__ F, float* __restrict__ invn) {
  int b = blockIdx.y;
  int n = blockIdx.x * 256 + threadIdx.x;
  const float* f = F + (long)b * D_ * N_ + n;
  float s0 = 0, s1 = 0, s2 = 0, s3 = 0;
  for (int d = 0; d < D_; d += 4) {
    float v0 = f[(long)d * N_], v1 = f[(long)(d + 1) * N_];
    float v2 = f[(long)(d + 2) * N_], v3 = f[(long)(d + 3) * N_];
    s0 += v0 * v0; s1 += v1 * v1; s2 += v2 * v2; s3 += v3 * v3;
  }
  float ss = (s0 + s1) + (s2 + s3);
  invn[b * N_ + n] = 1.f / fmaxf(sqrtf(ss), 1e-12f);
}

// ---------------- cooperative Sinkhorn ----------------
__global__ __launch_bounds__(256, 1)
void sinkhorn_coop(const float* __restrict__ costAll, const float* __restrict__ logpNK,
                   float* __restrict__ out, float* __restrict__ partM,
                   float* __restrict__ partS, unsigned int* __restrict__ cnt) {
  __shared__ float tile[4][64][33];
  __shared__ float vsh[64];
  __shared__ float wm[4][64];
  __shared__ float wsum[4][64];
  __shared__ float red[256];
  const int tid = threadIdx.x;
  const int g = blockIdx.x & 15;
  const int s = blockIdx.x >> 4;
  const int w = tid >> 6, lane = tid & 63;
  const int i = s * 256 + tid;
  const float* C = costAll + (long)g * K_ * N_;
  const float eps = 1e-3f, ti = 1000.0f;
  const float lgp = -8.317766166719343f;
  const float lgq = -4.1588830833596715f;

  float c[64];
#pragma unroll
  for (int j = 0; j < 64; ++j) c[j] = C[(long)j * N_ + i];

  float u = 0.f;
  if (tid < 64) vsh[tid] = 0.f;
  __syncthreads();

  for (int it = 0; it < 25; ++it) {
    float tj[64];
#pragma unroll
    for (int j = 0; j < 64; ++j) tj[j] = vsh[j] - c[j];
    float dm = -1e30f;
#pragma unroll
    for (int j = 0; j < 64; ++j) dm = fmaxf(dm, tj[j]);
    float ssum = 0.f;
#pragma unroll
    for (int j = 0; j < 64; ++j) ssum += __expf((tj[j] - dm) * ti);
    float lse = (u + dm) * ti + __logf(ssum);
    u = eps * (lgp - lse) + u;

#pragma unroll
    for (int h = 0; h < 2; ++h) {
#pragma unroll
      for (int j2 = 0; j2 < 32; ++j2) {
        int j = h * 32 + j2;
        tile[w][lane][j2] = (u + tj[j]) * ti;
      }
      __syncthreads();
      int col = lane & 31, rh = lane >> 5;
      float Mh = -1e30f, Sh = 0.f;
#pragma unroll
      for (int r = 0; r < 32; ++r) {
        float a = tile[w][rh * 32 + r][col];
        Mh = fmaxf(Mh, a);
        Sh += __expf(a - lgp);
      }
      float Mo = __shfl_xor(Mh, 32);
      float So = __shfl_xor(Sh, 32);
      Mh = fmaxf(Mh, Mo);
      Sh += So;
      if (rh == 0) { wm[w][h * 32 + col] = Mh; wsum[w][h * 32 + col] = Sh; }
      __syncthreads();
    }
    int buf = it & 1;
    if (tid < 64) {
      float Mb = fmaxf(fmaxf(wm[0][tid], wm[1][tid]), fmaxf(wm[2][tid], wm[3][tid]));
      float Sb = wsum[0][tid] + wsum[1][tid] + wsum[2][tid] + wsum[3][tid];
      long idx = (((long)buf * 16 + g) * 64 + tid) * 16 + s;
      __hip_atomic_store(&partM[idx], Mb, __ATOMIC_RELAXED, __HIP_MEMORY_SCOPE_AGENT);
      __hip_atomic_store(&partS[idx], Sb, __ATOMIC_RELAXED, __HIP_MEMORY_SCOPE_AGENT);
    }
    __syncthreads();
    if (tid == 0) {
      __hip_atomic_fetch_add(&cnt[g * 32], 1u, __ATOMIC_RELEASE, __HIP_MEMORY_SCOPE_AGENT);
      unsigned target = 16u * (unsigned)(it + 1);
      while (__hip_atomic_load(&cnt[g * 32], __ATOMIC_ACQUIRE, __HIP_MEMORY_SCOPE_AGENT) < target)
        __builtin_amdgcn_s_sleep(2);
    }
    __syncthreads();
    if (tid < 64) {
      long base = (((long)buf * 16 + g) * 64 + tid) * 16;
      float M = -1e30f, S = 0.f;
#pragma unroll
      for (int p = 0; p < 16; ++p) {
        M = fmaxf(M, __hip_atomic_load(&partM[base + p], __ATOMIC_RELAXED, __HIP_MEMORY_SCOPE_AGENT));
        S += __hip_atomic_load(&partS[base + p], __ATOMIC_RELAXED, __HIP_MEMORY_SCOPE_AGENT);
      }
      float lsec = fmaxf(M, lgp + __logf(S));
      vsh[tid] = eps * (lgq - lsec) + vsh[tid];
    }
    __syncthreads();
  }

  // fused loss: logp now [n][K] contiguous
  const float* lp = logpNK + ((long)(g & 7) * N_ + i) * 64;
  float part = 0.f;
#pragma unroll
  for (int j = 0; j < 64; ++j) {
    float gma = __expf((u + vsh[j] - c[j]) * ti);
    part += gma * lp[j];
  }
  red[tid] = part;
  __syncthreads();
  for (int st2 = 128; st2 > 0; st2 >>= 1) {
    if (tid < st2) red[tid] += red[tid + st2];
    __syncthreads();
  }
  if (tid == 0) atomicAdd(out, -red[0] / (float)B_);
}

// ---------------- launch ----------------
extern "C" void kernel_launch(void* const* d_in, const int* in_sizes, int n_in,
                              void* d_out, int out_size, void* d_ws, size_t ws_size,
                              hipStream_t stream) {
  const float* feature = (const float*)d_in[0];
  const float* xyz = (const float*)d_in[1];
  const float* w1 = (const float*)d_in[2];
  const float* b1 = (const float*)d_in[3];
  const float* g1 = (const float*)d_in[4];
  const float* be1 = (const float*)d_in[5];
  const float* w2 = (const float*)d_in[6];
  const float* b2 = (const float*)d_in[7];
  const float* g2 = (const float*)d_in[8];
  const float* be2 = (const float*)d_in[9];
  const float* w3 = (const float*)d_in[10];
  const float* b3 = (const float*)d_in[11];
  float* out = (float*)d_out;
  float* ws = (float*)d_ws;

  const long RSZ = 16777216L;
  float* regA = ws;
  float* regB1 = ws + RSZ;
  float* regB2 = ws + 2 * RSZ;
  float* sm = ws + 3 * RSZ;

  // phase aliases
  ushort* FhT = (ushort*)regB1;
  ushort* FlT = (ushort*)regB2;
  float* h1raw = regA;
  ushort* h1hT = (ushort*)regB1;
  ushort* h1lT = (ushort*)regB1 + RSZ;
  float* h2 = regB2;
  ushort* h2hT = (ushort*)regB1;          // overwrites h1hT (dead after conv2)
  ushort* h2lT = (ushort*)regB1 + RSZ;
  const long sz = (long)B_ * N_ * K_;     // 2,097,152
  float* log_score = regA;                 // [b][K][N]
  float* score_KN = regA + sz;             // [b][K][N] f32
  float* logpNK = regA + 2 * sz;           // [b][n][K]
  float* cost_x = regA + 3 * sz;           // [b][K][N]
  float* cost_f = regA + 4 * sz;
  ushort* sc_h = (ushort*)(regA + 5 * sz); // [b][K][N] bf16 hi
  ushort* sc_l = (ushort*)(regA + 5 * sz) + sz;

  // smalls
  ushort* Wh1 = (ushort*)sm; sm += 262144;
  ushort* Wl1 = (ushort*)sm; sm += 262144;
  ushort* Wh2 = (ushort*)sm; sm += 131072;
  ushort* Wl2 = (ushort*)sm; sm += 131072;
  ushort* Wh3 = (ushort*)sm; sm += 16384;
  ushort* Wl3 = (ushort*)sm; sm += 16384;
  float* muT_raw = sm; sm += (long)B_ * K_ * D_;   // [b][64][1024]
  float* n_muT = sm;   sm += (long)B_ * K_ * D_;
  ushort* nmu_h = (ushort*)sm; sm += 262144;
  ushort* nmu_l = (ushort*)sm; sm += 262144;
  float* partM = sm;  sm += 2 * 16 * 64 * 16;
  float* partS = sm;  sm += 2 * 16 * 64 * 16;
  unsigned int* cnt = (unsigned int*)sm; sm += 512;
  float* inv_nrm = sm; sm += (long)B_ * N_;
  float* mu_x = sm;   sm += 2048;
  float* yn = sm;     sm += 512;
  float* pi_raw = sm; sm += 512;
  float* sc1 = sm; sm += 512;
  float* sh1 = sm; sm += 512;
  float* sc2 = sm; sm += 512;
  float* sh2 = sm; sm += 512;

  hipMemsetAsync(d_out, 0, sizeof(float) * out_size, stream);
  hipMemsetAsync(pi_raw, 0, 512 * sizeof(float), stream);
  hipMemsetAsync(cnt, 0, 512 * sizeof(unsigned int), stream);
  hipMemsetAsync(muT_raw, 0, (long)B_ * K_ * D_ * sizeof(float), stream);

  split_w<<<(H_ * D_) / 256, 256, 0, stream>>>(w1, Wh1, Wl1, H_ * D_);
  split_w<<<(H_ * H_) / 256, 256, 0, stream>>>(w2, Wh2, Wl2, H_ * H_);
  split_w<<<(K_ * H_) / 256, 256, 0, stream>>>(w3, Wh3, Wl3, K_ * H_);
  {
    dim3 g(N_ / 64, D_ / 64, B_);
    transpose_split<<<g, 256, 0, stream>>>(feature, FhT, FlT);
  }
  // conv1
  {
    dim3 g(N_ / 128, H_ / 128, B_);
    gemm_split_bf16<<<g, 256, 0, stream>>>(Wh1, Wl1, FhT, FlT, h1raw, b1,
                                           N_, D_, (long)N_ * D_, (long)H_ * N_);
  }
  bn_stats<<<H_, 256, 0, stream>>>(h1raw, g1, be1, sc1, sh1, H_);
  {
    dim3 g(N_ / 64, H_ / 64, B_);
    bn_relu_t<<<g, 256, 0, stream>>>(h1raw, sc1, sh1, h1hT, h1lT);
  }
  // conv2
  {
    dim3 g(N_ / 128, H_ / 128, B_);
    gemm_split_bf16<<<g, 256, 0, stream>>>(Wh2, Wl2, h1hT, h1lT, h2, b2,
                                           N_, H_, (long)N_ * H_, (long)H_ * N_);
  }
  bn_stats<<<H_, 256, 0, stream>>>(h2, g2, be2, sc2, sh2, H_);
  {
    dim3 g(N_ / 64, H_ / 64, B_);
    bn_relu_t<<<g, 256, 0, stream>>>(h2, sc2, sh2, h2hT, h2lT);
  }
  // conv3 (MFMA, M=64)
  {
    dim3 g(N_ / 128, 1, B_);
    gemm64_bb<<<g, 256, 0, stream>>>(Wh3, Wl3, h2hT, h2lT, log_score, b3,
                                     N_, H_, (long)N_ * H_, (long)K_ * N_);
  }
  softmax_nk<<<B_ * N_ / 256, 256, 0, stream>>>(log_score, score_KN, sc_h, sc_l,
                                                logpNK, pi_raw);
  {
    dim3 g(K_, B_);
    mu_xyz_k<<<g, 64, 0, stream>>>(score_KN, xyz, pi_raw, mu_x, yn);
  }
  reg_xyz_k<<<B_, 256, 0, stream>>>(mu_x, out);
  {
    dim3 g(N_ / 256, B_);
    cost_xyz_k<<<g, 256, 0, stream>>>(xyz, mu_x, yn, cost_x);
  }
  // mu_fea (MFMA, C^T form, 4-way K-split atomic)
  {
    dim3 g(D_ / 128, 4, B_);
    gemm64_bf<<<g, 256, 0, stream>>>(sc_h, sc_l, feature, muT_raw);
  }
  {
    dim3 g(K_, B_);
    mu_finalize<<<g, 256, 0, stream>>>(muT_raw, pi_raw, n_muT, nmu_h, nmu_l);
  }
  {
    dim3 g(K_, B_);
    reg_fea_k<<<g, 256, 0, stream>>>(n_muT, out);
  }
  {
    dim3 g(N_ / 256, B_);
    inv_nrm_k<<<g, 256, 0, stream>>>(feature, inv_nrm);
  }
  // cost_fea (MFMA, B transposed-converted in LDS)
  {
    dim3 g(N_ / 128, 1, B_);
    gemm64_bt<<<g, 256, 0, stream>>>(nmu_h, nmu_l, feature, inv_nrm, cost_f);
  }
  {
    void* kargs[] = {(void*)&cost_x, (void*)&logpNK, (void*)&out,
                     (void*)&partM, (void*)&partS, (void*)&cnt};
    hipLaunchCooperativeKernel((const void*)sinkhorn_coop, dim3(256), dim3(256),
                               kargs, 0, stream);
  }
}

// Round 6
// 1250.024 us; speedup vs baseline: 4.9820x; 1.0570x over previous
//
#include <hip/hip_runtime.h>
#include <math.h>

#define B_ 8
#define D_ 1024
#define N_ 4096
#define K_ 64
#define H_ 512

typedef short sx8 __attribute__((ext_vector_type(8)));
typedef float fx4 __attribute__((ext_vector_type(4)));

// ---------------- helpers ----------------
__device__ __forceinline__ float block_reduce_sum256(float v, float* sm) {
  int tid = threadIdx.x;
  sm[tid] = v;
  __syncthreads();
  for (int s = 128; s > 0; s >>= 1) {
    if (tid < s) sm[tid] += sm[tid + s];
    __syncthreads();
  }
  float r = sm[0];
  __syncthreads();
  return r;
}

__device__ __forceinline__ ushort f2bf(float f) {
  unsigned u = __float_as_uint(f);
  unsigned r = (u + 0x7fffu + ((u >> 16) & 1u)) >> 16;
  return (ushort)r;
}
__device__ __forceinline__ float bf2f(ushort h) {
  return __uint_as_float(((unsigned)h) << 16);
}

// ---------------- weight split: f32 -> bf16 hi/lo ----------------
__global__ __launch_bounds__(256)
void split_w(const float* __restrict__ W, ushort* __restrict__ Wh,
             ushort* __restrict__ Wl, int n) {
  int i = blockIdx.x * 256 + threadIdx.x;
  if (i < n) {
    float f = W[i];
    ushort h = f2bf(f);
    Wh[i] = h;
    Wl[i] = f2bf(f - bf2f(h));
  }
}

// ---------------- feature transpose+split + fused column sumsq ----------------
__global__ __launch_bounds__(256)
void transpose_split(const float* __restrict__ F, ushort* __restrict__ FhT,
                     ushort* __restrict__ FlT, float* __restrict__ nrmsq) {
  __shared__ float tile[64][65];
  __shared__ float nsq[64];
  int b = blockIdx.z, d0 = blockIdx.y * 64, n0 = blockIdx.x * 64;
  const float* src = F + ((long)b * D_ + d0) * N_ + n0;
  int t = threadIdx.x;
  if (t < 64) nsq[t] = 0.f;
  int rr4 = t >> 4, c4 = (t & 15) * 4;
#pragma unroll
  for (int p = 0; p < 4; ++p) {
    int dr = p * 16 + rr4;
    float4 v = *(const float4*)(src + (long)dr * N_ + c4);
    tile[dr][c4 + 0] = v.x;
    tile[dr][c4 + 1] = v.y;
    tile[dr][c4 + 2] = v.z;
    tile[dr][c4 + 3] = v.w;
  }
  __syncthreads();
  int nlb = t >> 3, ds = (t & 7) * 8;
#pragma unroll
  for (int p = 0; p < 2; ++p) {
    int nl = p * 32 + nlb;
    sx8 hv, lv;
    float sq = 0.f;
#pragma unroll
    for (int j = 0; j < 8; ++j) {
      float f = tile[ds + j][nl];
      sq += f * f;
      ushort h = f2bf(f);
      hv[j] = (short)h;
      lv[j] = (short)f2bf(f - bf2f(h));
    }
    atomicAdd(&nsq[nl], sq);
    long o = ((long)b * N_ + n0 + nl) * D_ + d0 + ds;
    *(sx8*)(FhT + o) = hv;
    *(sx8*)(FlT + o) = lv;
  }
  __syncthreads();
  if (t < 64) atomicAdd(&nrmsq[(long)b * N_ + n0 + t], nsq[t]);
}

// in-place: q = 1/max(sqrt(q),1e-12)
__global__ void inv_fin(float* __restrict__ q) {
  int i = blockIdx.x * 256 + threadIdx.x;
  float v = q[i];
  q[i] = 1.f / fmaxf(sqrtf(v), 1e-12f);
}

// ---------------- 128x128 split-bf16 MFMA GEMM (conv1/conv2) ----------------
__global__ __launch_bounds__(256)
void gemm_split_bf16(const ushort* __restrict__ Ah, const ushort* __restrict__ Al,
                     const ushort* __restrict__ BhT, const ushort* __restrict__ BlT,
                     float* __restrict__ C, const float* __restrict__ bias,
                     int N, int Kd, long sBT, long sC) {
  __shared__ ushort As[2][128][40];
  __shared__ ushort Bs[2][128][40];
  const int t = threadIdx.x;
  const int m0 = blockIdx.y * 128, n0 = blockIdx.x * 128;
  const long bo = (long)blockIdx.z * sBT;
  float* Cp = C + (long)blockIdx.z * sC;
  const int half = t >> 7, r = t & 127;
  const ushort* Asrc = (half ? Al : Ah) + (long)(m0 + r) * Kd;
  const ushort* Bsrc = (half ? BlT : BhT) + bo + (long)(n0 + r) * Kd;
  ushort* AsD = &As[half][r][0];
  ushort* BsD = &Bs[half][r][0];
  const int w = t >> 6, ln = t & 15, qd = (t & 63) >> 4;
  const int wm = w >> 1, wn = w & 1;

  fx4 acc[4][4];
#pragma unroll
  for (int i = 0; i < 4; ++i)
#pragma unroll
    for (int j = 0; j < 4; ++j) acc[i][j] = (fx4)0.f;

  for (int k0 = 0; k0 < Kd; k0 += 32) {
    uint4 a0 = *(const uint4*)(Asrc + k0);
    uint4 a1 = *(const uint4*)(Asrc + k0 + 8);
    uint4 a2 = *(const uint4*)(Asrc + k0 + 16);
    uint4 a3 = *(const uint4*)(Asrc + k0 + 24);
    uint4 b0 = *(const uint4*)(Bsrc + k0);
    uint4 b1 = *(const uint4*)(Bsrc + k0 + 8);
    uint4 b2 = *(const uint4*)(Bsrc + k0 + 16);
    uint4 b3 = *(const uint4*)(Bsrc + k0 + 24);
    __syncthreads();
    *(uint4*)(AsD + 0) = a0;
    *(uint4*)(AsD + 8) = a1;
    *(uint4*)(AsD + 16) = a2;
    *(uint4*)(AsD + 24) = a3;
    *(uint4*)(BsD + 0) = b0;
    *(uint4*)(BsD + 8) = b1;
    *(uint4*)(BsD + 16) = b2;
    *(uint4*)(BsD + 24) = b3;
    __syncthreads();
    sx8 ahf[4], alf[4], bhf[4], blf[4];
#pragma unroll
    for (int mt = 0; mt < 4; ++mt) {
      ahf[mt] = *(const sx8*)&As[0][wm * 64 + mt * 16 + ln][qd * 8];
      alf[mt] = *(const sx8*)&As[1][wm * 64 + mt * 16 + ln][qd * 8];
    }
#pragma unroll
    for (int nt = 0; nt < 4; ++nt) {
      bhf[nt] = *(const sx8*)&Bs[0][wn * 64 + nt * 16 + ln][qd * 8];
      blf[nt] = *(const sx8*)&Bs[1][wn * 64 + nt * 16 + ln][qd * 8];
    }
#pragma unroll
    for (int mt = 0; mt < 4; ++mt)
#pragma unroll
      for (int nt = 0; nt < 4; ++nt) {
        acc[mt][nt] = __builtin_amdgcn_mfma_f32_16x16x32_bf16(ahf[mt], bhf[nt], acc[mt][nt], 0, 0, 0);
        acc[mt][nt] = __builtin_amdgcn_mfma_f32_16x16x32_bf16(alf[mt], bhf[nt], acc[mt][nt], 0, 0, 0);
        acc[mt][nt] = __builtin_amdgcn_mfma_f32_16x16x32_bf16(ahf[mt], blf[nt], acc[mt][nt], 0, 0, 0);
      }
  }
#pragma unroll
  for (int mt = 0; mt < 4; ++mt) {
#pragma unroll
    for (int rr = 0; rr < 4; ++rr) {
      int row = m0 + wm * 64 + mt * 16 + qd * 4 + rr;
      float bb = bias[row];
#pragma unroll
      for (int nt = 0; nt < 4; ++nt) {
        int col = n0 + wn * 64 + nt * 16 + ln;
        Cp[(long)row * N + col] = acc[mt][nt][rr] + bb;
      }
    }
  }
}

// ================= M64 split-bf16 MFMA family =================

// --- variant bb: A pre-split [64][Kd], B pre-split transposed [Nc][Kd] (conv3) ---
__global__ __launch_bounds__(256)
void gemm64_bb(const ushort* __restrict__ Ah, const ushort* __restrict__ Al,
               const ushort* __restrict__ BhT, const ushort* __restrict__ BlT,
               float* __restrict__ C, const float* __restrict__ bias,
               int N, int Kd, long sBT, long sC) {
  __shared__ ushort As[2][64][40];
  __shared__ ushort Bs[2][128][40];
  const int t = threadIdx.x;
  const int n0 = blockIdx.x * 128;
  float* Cp = C + (long)blockIdx.z * sC;
  const int hB = t >> 7, rB = t & 127;
  const ushort* Bsrc = (hB ? BlT : BhT) + (long)blockIdx.z * sBT + (long)(n0 + rB) * Kd;
  ushort* BsD = &Bs[hB][rB][0];
  const bool doA = t < 128;
  const int hA = (t >> 6) & 1, rA = t & 63;
  const ushort* Asrc = (hA ? Al : Ah) + (long)rA * Kd;
  ushort* AsD = &As[hA][rA][0];
  const int w = t >> 6, ln = t & 15, qd = (t & 63) >> 4;
  const int wm = w >> 1, wn = w & 1;

  fx4 acc[2][4];
#pragma unroll
  for (int i = 0; i < 2; ++i)
#pragma unroll
    for (int j = 0; j < 4; ++j) acc[i][j] = (fx4)0.f;

  for (int k0 = 0; k0 < Kd; k0 += 32) {
    uint4 b0 = *(const uint4*)(Bsrc + k0);
    uint4 b1 = *(const uint4*)(Bsrc + k0 + 8);
    uint4 b2 = *(const uint4*)(Bsrc + k0 + 16);
    uint4 b3 = *(const uint4*)(Bsrc + k0 + 24);
    uint4 a0, a1, a2, a3;
    if (doA) {
      a0 = *(const uint4*)(Asrc + k0);
      a1 = *(const uint4*)(Asrc + k0 + 8);
      a2 = *(const uint4*)(Asrc + k0 + 16);
      a3 = *(const uint4*)(Asrc + k0 + 24);
    }
    __syncthreads();
    *(uint4*)(BsD + 0) = b0;
    *(uint4*)(BsD + 8) = b1;
    *(uint4*)(BsD + 16) = b2;
    *(uint4*)(BsD + 24) = b3;
    if (doA) {
      *(uint4*)(AsD + 0) = a0;
      *(uint4*)(AsD + 8) = a1;
      *(uint4*)(AsD + 16) = a2;
      *(uint4*)(AsD + 24) = a3;
    }
    __syncthreads();
    sx8 ahf[2], alf[2], bhf[4], blf[4];
#pragma unroll
    for (int mt = 0; mt < 2; ++mt) {
      ahf[mt] = *(const sx8*)&As[0][wm * 32 + mt * 16 + ln][qd * 8];
      alf[mt] = *(const sx8*)&As[1][wm * 32 + mt * 16 + ln][qd * 8];
    }
#pragma unroll
    for (int nt = 0; nt < 4; ++nt) {
      bhf[nt] = *(const sx8*)&Bs[0][wn * 64 + nt * 16 + ln][qd * 8];
      blf[nt] = *(const sx8*)&Bs[1][wn * 64 + nt * 16 + ln][qd * 8];
    }
#pragma unroll
    for (int mt = 0; mt < 2; ++mt)
#pragma unroll
      for (int nt = 0; nt < 4; ++nt) {
        acc[mt][nt] = __builtin_amdgcn_mfma_f32_16x16x32_bf16(ahf[mt], bhf[nt], acc[mt][nt], 0, 0, 0);
        acc[mt][nt] = __builtin_amdgcn_mfma_f32_16x16x32_bf16(alf[mt], bhf[nt], acc[mt][nt], 0, 0, 0);
        acc[mt][nt] = __builtin_amdgcn_mfma_f32_16x16x32_bf16(ahf[mt], blf[nt], acc[mt][nt], 0, 0, 0);
      }
  }
#pragma unroll
  for (int mt = 0; mt < 2; ++mt)
#pragma unroll
    for (int rr = 0; rr < 4; ++rr) {
      int row = wm * 32 + mt * 16 + qd * 4 + rr;
      float bb = bias[row];
#pragma unroll
      for (int nt = 0; nt < 4; ++nt) {
        int col = n0 + wn * 64 + nt * 16 + ln;
        Cp[(long)row * N + col] = acc[mt][nt][rr] + bb;
      }
    }
}

// --- variant bf: A pre-split [b][64][N_], B = f32 rows natural along Kd (mu_fea) ---
__global__ __launch_bounds__(256)
void gemm64_bf(const ushort* __restrict__ Ah, const ushort* __restrict__ Al,
               const float* __restrict__ Bf, float* __restrict__ Cacc) {
  __shared__ ushort As[2][64][40];
  __shared__ ushort Bs[2][128][40];
  const int t = threadIdx.x;
  const int nc0 = blockIdx.x * 128;
  const int kBeg = blockIdx.y * 1024;
  const int b = blockIdx.z;
  const int pc = t >> 7, rB = t & 127;
  const float* Bsrc = Bf + (long)b * D_ * N_ + (long)(nc0 + rB) * N_ + kBeg + pc * 16;
  const bool doA = t < 128;
  const int hA = (t >> 6) & 1, rA = t & 63;
  const ushort* Asrc = (hA ? Al : Ah) + (long)b * K_ * N_ + (long)rA * N_ + kBeg;
  ushort* AsD = &As[hA][rA][0];
  const int w = t >> 6, ln = t & 15, qd = (t & 63) >> 4;
  const int wm = w >> 1, wn = w & 1;

  fx4 acc[2][4];
#pragma unroll
  for (int i = 0; i < 2; ++i)
#pragma unroll
    for (int j = 0; j < 4; ++j) acc[i][j] = (fx4)0.f;

  for (int k0 = 0; k0 < 1024; k0 += 32) {
    float4 f0 = *(const float4*)(Bsrc + k0);
    float4 f1 = *(const float4*)(Bsrc + k0 + 4);
    float4 f2 = *(const float4*)(Bsrc + k0 + 8);
    float4 f3 = *(const float4*)(Bsrc + k0 + 12);
    uint4 a0, a1, a2, a3;
    if (doA) {
      a0 = *(const uint4*)(Asrc + k0);
      a1 = *(const uint4*)(Asrc + k0 + 8);
      a2 = *(const uint4*)(Asrc + k0 + 16);
      a3 = *(const uint4*)(Asrc + k0 + 24);
    }
    float fv[16] = {f0.x, f0.y, f0.z, f0.w, f1.x, f1.y, f1.z, f1.w,
                    f2.x, f2.y, f2.z, f2.w, f3.x, f3.y, f3.z, f3.w};
    sx8 hv0, hv1, lv0, lv1;
#pragma unroll
    for (int j = 0; j < 8; ++j) {
      ushort h = f2bf(fv[j]);
      hv0[j] = (short)h;
      lv0[j] = (short)f2bf(fv[j] - bf2f(h));
    }
#pragma unroll
    for (int j = 0; j < 8; ++j) {
      ushort h = f2bf(fv[8 + j]);
      hv1[j] = (short)h;
      lv1[j] = (short)f2bf(fv[8 + j] - bf2f(h));
    }
    __syncthreads();
    *(sx8*)&Bs[0][rB][pc * 16] = hv0;
    *(sx8*)&Bs[0][rB][pc * 16 + 8] = hv1;
    *(sx8*)&Bs[1][rB][pc * 16] = lv0;
    *(sx8*)&Bs[1][rB][pc * 16 + 8] = lv1;
    if (doA) {
      *(uint4*)(AsD + 0) = a0;
      *(uint4*)(AsD + 8) = a1;
      *(uint4*)(AsD + 16) = a2;
      *(uint4*)(AsD + 24) = a3;
    }
    __syncthreads();
    sx8 ahf[2], alf[2], bhf[4], blf[4];
#pragma unroll
    for (int mt = 0; mt < 2; ++mt) {
      ahf[mt] = *(const sx8*)&As[0][wm * 32 + mt * 16 + ln][qd * 8];
      alf[mt] = *(const sx8*)&As[1][wm * 32 + mt * 16 + ln][qd * 8];
    }
#pragma unroll
    for (int nt = 0; nt < 4; ++nt) {
      bhf[nt] = *(const sx8*)&Bs[0][wn * 64 + nt * 16 + ln][qd * 8];
      blf[nt] = *(const sx8*)&Bs[1][wn * 64 + nt * 16 + ln][qd * 8];
    }
#pragma unroll
    for (int mt = 0; mt < 2; ++mt)
#pragma unroll
      for (int nt = 0; nt < 4; ++nt) {
        acc[mt][nt] = __builtin_amdgcn_mfma_f32_16x16x32_bf16(ahf[mt], bhf[nt], acc[mt][nt], 0, 0, 0);
        acc[mt][nt] = __builtin_amdgcn_mfma_f32_16x16x32_bf16(alf[mt], bhf[nt], acc[mt][nt], 0, 0, 0);
        acc[mt][nt] = __builtin_amdgcn_mfma_f32_16x16x32_bf16(ahf[mt], blf[nt], acc[mt][nt], 0, 0, 0);
      }
  }
#pragma unroll
  for (int mt = 0; mt < 2; ++mt)
#pragma unroll
    for (int rr = 0; rr < 4; ++rr) {
      int row = wm * 32 + mt * 16 + qd * 4 + rr;
#pragma unroll
      for (int nt = 0; nt < 4; ++nt) {
        int col = nc0 + wn * 64 + nt * 16 + ln;
        atomicAdd(&Cacc[((long)b * K_ + row) * D_ + col], acc[mt][nt][rr]);
      }
    }
}

// --- variant bt: A pre-split [b][64][D_], B = f32 [D][N] transposed in LDS (cost_fea) ---
__global__ __launch_bounds__(256)
void gemm64_bt(const ushort* __restrict__ Ah, const ushort* __restrict__ Al,
               const float* __restrict__ Bf, const float* __restrict__ invn,
               float* __restrict__ cost) {
  __shared__ ushort As[2][64][40];
  __shared__ ushort Bs[2][128][40];
  __shared__ float Ft[32][132];
  const int t = threadIdx.x;
  const int n0 = blockIdx.x * 128;
  const int b = blockIdx.z;
  const float* Fsrc = Bf + (long)b * D_ * N_;
  const bool doA = t < 128;
  const int hA = (t >> 6) & 1, rA = t & 63;
  const ushort* Asrc = (hA ? Al : Ah) + (long)b * K_ * D_ + (long)rA * D_;
  ushort* AsD = &As[hA][rA][0];
  const int dr = t >> 3, cc = (t & 7) * 16;
  const int nl = t & 127, dh = t >> 7;
  const int w = t >> 6, ln = t & 15, qd = (t & 63) >> 4;
  const int wm = w >> 1, wn = w & 1;

  fx4 acc[2][4];
#pragma unroll
  for (int i = 0; i < 2; ++i)
#pragma unroll
    for (int j = 0; j < 4; ++j) acc[i][j] = (fx4)0.f;

  for (int k0 = 0; k0 < D_; k0 += 32) {
    float4 f0 = *(const float4*)(Fsrc + (long)(k0 + dr) * N_ + n0 + cc);
    float4 f1 = *(const float4*)(Fsrc + (long)(k0 + dr) * N_ + n0 + cc + 4);
    float4 f2 = *(const float4*)(Fsrc + (long)(k0 + dr) * N_ + n0 + cc + 8);
    float4 f3 = *(const float4*)(Fsrc + (long)(k0 + dr) * N_ + n0 + cc + 12);
    uint4 a0, a1, a2, a3;
    if (doA) {
      a0 = *(const uint4*)(Asrc + k0);
      a1 = *(const uint4*)(Asrc + k0 + 8);
      a2 = *(const uint4*)(Asrc + k0 + 16);
      a3 = *(const uint4*)(Asrc + k0 + 24);
    }
    __syncthreads();
    *(float4*)&Ft[dr][cc] = f0;
    *(float4*)&Ft[dr][cc + 4] = f1;
    *(float4*)&Ft[dr][cc + 8] = f2;
    *(float4*)&Ft[dr][cc + 12] = f3;
    if (doA) {
      *(uint4*)(AsD + 0) = a0;
      *(uint4*)(AsD + 8) = a1;
      *(uint4*)(AsD + 16) = a2;
      *(uint4*)(AsD + 24) = a3;
    }
    __syncthreads();
    float fv[16];
#pragma unroll
    for (int j = 0; j < 16; ++j) fv[j] = Ft[dh * 16 + j][nl];
    sx8 hv0, hv1, lv0, lv1;
#pragma unroll
    for (int j = 0; j < 8; ++j) {
      ushort h = f2bf(fv[j]);
      hv0[j] = (short)h;
      lv0[j] = (short)f2bf(fv[j] - bf2f(h));
    }
#pragma unroll
    for (int j = 0; j < 8; ++j) {
      ushort h = f2bf(fv[8 + j]);
      hv1[j] = (short)h;
      lv1[j] = (short)f2bf(fv[8 + j] - bf2f(h));
    }
    *(sx8*)&Bs[0][nl][dh * 16] = hv0;
    *(sx8*)&Bs[0][nl][dh * 16 + 8] = hv1;
    *(sx8*)&Bs[1][nl][dh * 16] = lv0;
    *(sx8*)&Bs[1][nl][dh * 16 + 8] = lv1;
    __syncthreads();
    sx8 ahf[2], alf[2], bhf[4], blf[4];
#pragma unroll
    for (int mt = 0; mt < 2; ++mt) {
      ahf[mt] = *(const sx8*)&As[0][wm * 32 + mt * 16 + ln][qd * 8];
      alf[mt] = *(const sx8*)&As[1][wm * 32 + mt * 16 + ln][qd * 8];
    }
#pragma unroll
    for (int nt = 0; nt < 4; ++nt) {
      bhf[nt] = *(const sx8*)&Bs[0][wn * 64 + nt * 16 + ln][qd * 8];
      blf[nt] = *(const sx8*)&Bs[1][wn * 64 + nt * 16 + ln][qd * 8];
    }
#pragma unroll
    for (int mt = 0; mt < 2; ++mt)
#pragma unroll
      for (int nt = 0; nt < 4; ++nt) {
        acc[mt][nt] = __builtin_amdgcn_mfma_f32_16x16x32_bf16(ahf[mt], bhf[nt], acc[mt][nt], 0, 0, 0);
        acc[mt][nt] = __builtin_amdgcn_mfma_f32_16x16x32_bf16(alf[mt], bhf[nt], acc[mt][nt], 0, 0, 0);
        acc[mt][nt] = __builtin_amdgcn_mfma_f32_16x16x32_bf16(ahf[mt], blf[nt], acc[mt][nt], 0, 0, 0);
      }
  }
#pragma unroll
  for (int nt = 0; nt < 4; ++nt) {
    int col = n0 + wn * 64 + nt * 16 + ln;
    float iv = invn[b * N_ + col];
#pragma unroll
    for (int mt = 0; mt < 2; ++mt)
#pragma unroll
      for (int rr = 0; rr < 4; ++rr) {
        int row = wm * 32 + mt * 16 + qd * 4 + rr;
        cost[((long)b * K_ + row) * N_ + col] = 2.f - 2.f * acc[mt][nt][rr] * iv;
      }
  }
}

// ---------------- BN stats ----------------
__global__ __launch_bounds__(256)
void bn_stats(const float* __restrict__ Y, const float* __restrict__ g,
              const float* __restrict__ be, float* __restrict__ scale,
              float* __restrict__ shift, int C) {
  int c = blockIdx.x;
  double s1 = 0.0, s2 = 0.0;
  for (int idx = threadIdx.x; idx < B_ * N_; idx += 256) {
    int b = idx >> 12, n = idx & (N_ - 1);
    float v = Y[((long)b * C + c) * N_ + n];
    s1 += v;
    s2 += (double)v * (double)v;
  }
  __shared__ double r1[256], r2[256];
  int tid = threadIdx.x;
  r1[tid] = s1; r2[tid] = s2;
  __syncthreads();
  for (int s = 128; s > 0; s >>= 1) {
    if (tid < s) { r1[tid] += r1[tid + s]; r2[tid] += r2[tid + s]; }
    __syncthreads();
  }
  if (tid == 0) {
    double m = r1[0] / (double)(B_ * N_);
    double var = r2[0] / (double)(B_ * N_) - m * m;
    float sc = (float)((double)g[c] / sqrt(var + 1e-5));
    scale[c] = sc;
    shift[c] = (float)((double)be[c] - m * (double)sc);
  }
}

// ---------------- BN+ReLU + transpose+split ----------------
__global__ __launch_bounds__(256)
void bn_relu_t(const float* __restrict__ Y, const float* __restrict__ scale,
               const float* __restrict__ shift, ushort* __restrict__ OhT,
               ushort* __restrict__ OlT) {
  __shared__ float tile[64][65];
  int b = blockIdx.z, h0 = blockIdx.y * 64, n0 = blockIdx.x * 64;
  const float* src = Y + ((long)b * H_ + h0) * N_ + n0;
  int t = threadIdx.x;
  int rr4 = t >> 4, c4 = (t & 15) * 4;
#pragma unroll
  for (int p = 0; p < 4; ++p) {
    int hl = p * 16 + rr4;
    float sc = scale[h0 + hl], sh = shift[h0 + hl];
    float4 v = *(const float4*)(src + (long)hl * N_ + c4);
    tile[hl][c4 + 0] = fmaxf(v.x * sc + sh, 0.f);
    tile[hl][c4 + 1] = fmaxf(v.y * sc + sh, 0.f);
    tile[hl][c4 + 2] = fmaxf(v.z * sc + sh, 0.f);
    tile[hl][c4 + 3] = fmaxf(v.w * sc + sh, 0.f);
  }
  __syncthreads();
  int nlb = t >> 3, hs = (t & 7) * 8;
#pragma unroll
  for (int p = 0; p < 2; ++p) {
    int nl = p * 32 + nlb;
    sx8 hv, lv;
#pragma unroll
    for (int j = 0; j < 8; ++j) {
      float f = tile[hs + j][nl];
      ushort h = f2bf(f);
      hv[j] = (short)h;
      lv[j] = (short)f2bf(f - bf2f(h));
    }
    long o = ((long)b * N_ + n0 + nl) * H_ + h0 + hs;
    *(sx8*)(OhT + o) = hv;
    *(sx8*)(OlT + o) = lv;
  }
}

// ---------------- softmax: score f32/bf16, logp [b][n][K] ----------------
__global__ __launch_bounds__(256)
void softmax_nk(const float* __restrict__ ls, float* __restrict__ scoreKN,
                ushort* __restrict__ sch, ushort* __restrict__ scl,
                float* __restrict__ logpNK, float* __restrict__ pi_raw) {
  __shared__ float L[64][65];
  __shared__ float ploc[64];
  int tid = threadIdx.x;
  if (tid < 64) ploc[tid] = 0.f;
  __syncthreads();
  int bi = blockIdx.x >> 4;
  int nb = (blockIdx.x & 15) * 256;
  int n = nb + tid;
  const float* x = ls + ((long)bi * K_) * N_ + n;
  float xv[64];
#pragma unroll
  for (int k = 0; k < 64; ++k) xv[k] = x[(long)k * N_];
  float mx = -1e30f;
#pragma unroll
  for (int k = 0; k < 64; ++k) mx = fmaxf(mx, xv[k]);
  float s = 0.f;
#pragma unroll
  for (int k = 0; k < 64; ++k) s += __expf(xv[k] - mx);
  float lg = __logf(s);
  float inv = 1.f / s;
#pragma unroll
  for (int k = 0; k < 64; ++k) {
    float sc = __expf(xv[k] - mx) * inv;
    long o = ((long)bi * K_ + k) * N_ + n;
    scoreKN[o] = sc;
    ushort h = f2bf(sc);
    sch[o] = h;
    scl[o] = f2bf(sc - bf2f(h));
    atomicAdd(&ploc[k], sc);
  }
  __syncthreads();
  if (tid < 64) atomicAdd(&pi_raw[bi * 64 + tid], ploc[tid]);
  int myw = tid >> 6, nl = tid & 63;
  int row = tid >> 2, ch = (tid & 3) * 16;
  for (int p = 0; p < 4; ++p) {
    __syncthreads();
    if (myw == p) {
#pragma unroll
      for (int k = 0; k < 64; ++k) L[nl][k] = xv[k] - mx - lg;
    }
    __syncthreads();
    float o0[16];
#pragma unroll
    for (int j = 0; j < 16; ++j) o0[j] = L[row][ch + j];
    float* dst = logpNK + ((long)bi * N_ + nb + p * 64 + row) * 64 + ch;
    *(float4*)(dst + 0) = make_float4(o0[0], o0[1], o0[2], o0[3]);
    *(float4*)(dst + 4) = make_float4(o0[4], o0[5], o0[6], o0[7]);
    *(float4*)(dst + 8) = make_float4(o0[8], o0[9], o0[10], o0[11]);
    *(float4*)(dst + 12) = make_float4(o0[12], o0[13], o0[14], o0[15]);
  }
}

// ---------------- mu_xyz ----------------
__global__ __launch_bounds__(64)
void mu_xyz_k(const float* __restrict__ scoreKN, const float* __restrict__ xyz,
              const float* __restrict__ pi_raw, float* __restrict__ mu,
              float* __restrict__ yn) {
  int k = blockIdx.x, b = blockIdx.y, t = threadIdx.x;
  const float* st = scoreKN + ((long)b * K_ + k) * N_;
  const float* xp = xyz + (long)b * 3 * N_;
  float a0 = 0, a1 = 0, a2 = 0;
  for (int n = t; n < N_; n += 64) {
    float s = st[n];
    a0 += s * xp[n];
    a1 += s * xp[N_ + n];
    a2 += s * xp[2 * N_ + n];
  }
  for (int off = 32; off > 0; off >>= 1) {
    a0 += __shfl_down(a0, off);
    a1 += __shfl_down(a1, off);
    a2 += __shfl_down(a2, off);
  }
  if (t == 0) {
    float p = fmaxf(pi_raw[b * K_ + k], 1e-4f);
    float m0 = a0 / p, m1 = a1 / p, m2 = a2 / p;
    mu[((long)b * 3 + 0) * K_ + k] = m0;
    mu[((long)b * 3 + 1) * K_ + k] = m1;
    mu[((long)b * 3 + 2) * K_ + k] = m2;
    yn[b * K_ + k] = m0 * m0 + m1 * m1 + m2 * m2;
  }
}

// ---------------- regularizers ----------------
__global__ __launch_bounds__(256)
void reg_xyz_k(const float* __restrict__ mu, float* __restrict__ out) {
  __shared__ float red[256];
  int b = blockIdx.x, tid = threadIdx.x;
  float acc = 0.f;
  for (int e = tid; e < 4096; e += 256) {
    int m = e >> 6, n2 = e & 63;
    float g = 0.f;
    for (int d = 0; d < 3; ++d)
      g += mu[((long)b * 3 + d) * K_ + m] * mu[((long)b * 3 + d) * K_ + n2];
    acc += fabsf(g - (m == n2 ? 1.f : 0.f));
  }
  float tot = block_reduce_sum256(acc, red);
  if (tid == 0) atomicAdd(out, tot * (1e-7f / 32768.f));
}

__global__ __launch_bounds__(256)
void reg_fea_k(const float* __restrict__ nT, float* __restrict__ out) {
  __shared__ float pm[1024];
  __shared__ float red[256];
  int m = blockIdx.x, b = blockIdx.y, tid = threadIdx.x;
  const float* base = nT + (long)b * K_ * D_;
  *(float4*)&pm[tid * 4] = *(const float4*)(base + (long)m * D_ + tid * 4);
  __syncthreads();
  int n2 = tid >> 2, q = tid & 3;
  const float* pn = base + (long)n2 * D_ + q * 256;
  const float* pml = &pm[q * 256];
  float g = 0.f;
#pragma unroll 8
  for (int d = 0; d < 256; d += 4) {
    float4 v = *(const float4*)(pn + d);
    g += v.x * pml[d] + v.y * pml[d + 1] + v.z * pml[d + 2] + v.w * pml[d + 3];
  }
  g += __shfl_down(g, 2);
  g += __shfl_down(g, 1);
  float acc = (q == 0) ? fabsf(g - (m == n2 ? 1.f : 0.f)) : 0.f;
  float tot = block_reduce_sum256(acc, red);
  if (tid == 0) atomicAdd(out, tot * (1e-4f / 32768.f));
}

// ---------------- mu_fea finalize ----------------
__global__ __launch_bounds__(256)
void mu_finalize(const float* __restrict__ muT_raw, const float* __restrict__ pi_raw,
                 float* __restrict__ n_muT, ushort* __restrict__ nmu_h,
                 ushort* __restrict__ nmu_l) {
  __shared__ float red[256];
  int k = blockIdx.x, b = blockIdx.y, tid = threadIdx.x;
  float p = fmaxf(pi_raw[b * K_ + k], 1e-4f);
  const float* src = muT_raw + ((long)b * K_ + k) * D_;
  float ss = 0.f;
  for (int d = tid; d < D_; d += 256) {
    float v = src[d] / p;
    ss += v * v;
  }
  float tot = block_reduce_sum256(ss, red);
  float inv = 1.f / fmaxf(sqrtf(tot), 1e-12f);
  long o = ((long)b * K_ + k) * D_;
  for (int d = tid; d < D_; d += 256) {
    float v = src[d] / p * inv;
    n_muT[o + d] = v;
    ushort h = f2bf(v);
    nmu_h[o + d] = h;
    nmu_l[o + d] = f2bf(v - bf2f(h));
  }
}

// ---------------- cooperative Sinkhorn v2 ----------------
// branch-x cost computed on the fly; full-width single transpose; XCD-local groups
__global__ __launch_bounds__(256, 1)
void sinkhorn_coop(const float* __restrict__ cost_f, const float* __restrict__ xyz,
                   const float* __restrict__ mu, const float* __restrict__ yn,
                   const float* __restrict__ logpNK, float* __restrict__ out,
                   float* __restrict__ partM, float* __restrict__ partS,
                   unsigned int* __restrict__ cnt) {
  __shared__ float tile[4][64][68];   // stride 68: 16B-aligned rows, conflict-free
  __shared__ float vsh[64];
  __shared__ float wm[4][64];
  __shared__ float wsum[4][64];
  __shared__ float red[256];
  __shared__ float mub[4][64];
  const int tid = threadIdx.x;
  const int id = blockIdx.x;
  // co-locate a group's 16 slices on one XCD residue (id % 8 == g % 8)
  const int g = (id & 7) | (((id >> 3) & 1) << 3);
  const int s = id >> 4;
  const int w = tid >> 6, lane = tid & 63;
  const int i = s * 256 + tid;
  const int b = g & 7;
  const float eps = 1e-3f, ti = 1000.0f;
  const float lgp = -8.317766166719343f;   // -log(4096)
  const float lgq = -4.1588830833596715f;  // -log(64)

  float c[64];
  if (g < 8) {
    if (tid < 64) {
      mub[0][tid] = mu[(b * 3 + 0) * K_ + tid];
      mub[1][tid] = mu[(b * 3 + 1) * K_ + tid];
      mub[2][tid] = mu[(b * 3 + 2) * K_ + tid];
      mub[3][tid] = yn[b * K_ + tid];
      vsh[tid] = 0.f;
    }
    __syncthreads();
    float x0 = xyz[((long)b * 3 + 0) * N_ + i];
    float x1 = xyz[((long)b * 3 + 1) * N_ + i];
    float x2 = xyz[((long)b * 3 + 2) * N_ + i];
    float xn = x0 * x0 + x1 * x1 + x2 * x2;
#pragma unroll
    for (int j = 0; j < 64; ++j)
      c[j] = xn + mub[3][j] - 2.f * (x0 * mub[0][j] + x1 * mub[1][j] + x2 * mub[2][j]);
  } else {
    const float* C = cost_f + (long)b * K_ * N_;
#pragma unroll
    for (int j = 0; j < 64; ++j) c[j] = C[(long)j * N_ + i];
    if (tid < 64) vsh[tid] = 0.f;
    __syncthreads();
  }
  float u = 0.f;

  for (int it = 0; it < 25; ++it) {
    float tj[64];
#pragma unroll
    for (int j = 0; j < 64; ++j) tj[j] = vsh[j] - c[j];
    float dm = -1e30f;
#pragma unroll
    for (int j = 0; j < 64; ++j) dm = fmaxf(dm, tj[j]);
    float ssum = 0.f;
#pragma unroll
    for (int j = 0; j < 64; ++j) ssum += __expf((tj[j] - dm) * ti);
    u = eps * (lgp - ((u + dm) * ti + __logf(ssum))) + u;
    // single full-width row write (b128, conflict-free)
#pragma unroll
    for (int j4 = 0; j4 < 16; ++j4) {
      float4 v4;
      v4.x = (u + tj[j4 * 4 + 0]) * ti;
      v4.y = (u + tj[j4 * 4 + 1]) * ti;
      v4.z = (u + tj[j4 * 4 + 2]) * ti;
      v4.w = (u + tj[j4 * 4 + 3]) * ti;
      *(float4*)&tile[w][lane][j4 * 4] = v4;
    }
    __syncthreads();
    // per-lane column ownership: lane reduces column `lane` over its wave's 64 rows
    float M = -1e30f, S = 0.f;
#pragma unroll
    for (int r = 0; r < 64; ++r) {
      float a = tile[w][r][lane];
      M = fmaxf(M, a);
      S += __expf(a - lgp);
    }
    wm[w][lane] = M;
    wsum[w][lane] = S;
    __syncthreads();
    int buf = it & 1;
    if (tid < 64) {
      float Mb = fmaxf(fmaxf(wm[0][tid], wm[1][tid]), fmaxf(wm[2][tid], wm[3][tid]));
      float Sb = wsum[0][tid] + wsum[1][tid] + wsum[2][tid] + wsum[3][tid];
      long idx = (((long)buf * 16 + g) * 64 + tid) * 16 + s;
      __hip_atomic_store(&partM[idx], Mb, __ATOMIC_RELAXED, __HIP_MEMORY_SCOPE_AGENT);
      __hip_atomic_store(&partS[idx], Sb, __ATOMIC_RELAXED, __HIP_MEMORY_SCOPE_AGENT);
    }
    // release-add drains wave 0's stores via wave-level vmcnt(0); no extra barrier
    if (tid == 0) {
      __hip_atomic_fetch_add(&cnt[g * 32], 1u, __ATOMIC_ACQ_REL, __HIP_MEMORY_SCOPE_AGENT);
      unsigned target = 16u * (unsigned)(it + 1);
      while (__hip_atomic_load(&cnt[g * 32], __ATOMIC_ACQUIRE, __HIP_MEMORY_SCOPE_AGENT) < target)
        __builtin_amdgcn_s_sleep(1);
    }
    __syncthreads();
    if (tid < 64) {
      long base = (((long)buf * 16 + g) * 64 + tid) * 16;
      float M2 = -1e30f, S2 = 0.f;
#pragma unroll
      for (int p = 0; p < 16; ++p) {
        M2 = fmaxf(M2, __hip_atomic_load(&partM[base + p], __ATOMIC_RELAXED, __HIP_MEMORY_SCOPE_AGENT));
        S2 += __hip_atomic_load(&partS[base + p], __ATOMIC_RELAXED, __HIP_MEMORY_SCOPE_AGENT);
      }
      float lsec = fmaxf(M2, lgp + __logf(S2));
      vsh[tid] = eps * (lgq - lsec) + vsh[tid];
    }
    __syncthreads();
  }

  // fused loss
  const float* lp = logpNK + ((long)b * N_ + i) * 64;
  float part = 0.f;
#pragma unroll
  for (int j = 0; j < 64; ++j)
    part += __expf((u + vsh[j] - c[j]) * ti) * lp[j];
  red[tid] = part;
  __syncthreads();
  for (int st2 = 128; st2 > 0; st2 >>= 1) {
    if (tid < st2) red[tid] += red[tid + st2];
    __syncthreads();
  }
  if (tid == 0) atomicAdd(out, -red[0] / (float)B_);
}

// ---------------- launch ----------------
extern "C" void kernel_launch(void* const* d_in, const int* in_sizes, int n_in,
                              void* d_out, int out_size, void* d_ws, size_t ws_size,
                              hipStream_t stream) {
  const float* feature = (const float*)d_in[0];
  const float* xyz = (const float*)d_in[1];
  const float* w1 = (const float*)d_in[2];
  const float* b1 = (const float*)d_in[3];
  const float* g1 = (const float*)d_in[4];
  const float* be1 = (const float*)d_in[5];
  const float* w2 = (const float*)d_in[6];
  const float* b2 = (const float*)d_in[7];
  const float* g2 = (const float*)d_in[8];
  const float* be2 = (const float*)d_in[9];
  const float* w3 = (const float*)d_in[10];
  const float* b3 = (const float*)d_in[11];
  float* out = (float*)d_out;
  float* ws = (float*)d_ws;

  const long RSZ = 16777216L;
  float* regA = ws;
  float* regB1 = ws + RSZ;
  float* regB2 = ws + 2 * RSZ;
  float* sm = ws + 3 * RSZ;

  ushort* FhT = (ushort*)regB1;
  ushort* FlT = (ushort*)regB2;
  float* h1raw = regA;
  ushort* h1hT = (ushort*)regB1;
  ushort* h1lT = (ushort*)regB1 + RSZ;
  float* h2 = regB2;
  ushort* h2hT = (ushort*)regB1;
  ushort* h2lT = (ushort*)regB1 + RSZ;
  const long sz = (long)B_ * N_ * K_;
  float* log_score = regA;
  float* score_KN = regA + sz;
  float* logpNK = regA + 2 * sz;
  float* cost_f = regA + 3 * sz;
  ushort* sc_h = (ushort*)(regA + 4 * sz);
  ushort* sc_l = (ushort*)(regA + 4 * sz) + sz;

  ushort* Wh1 = (ushort*)sm; sm += 262144;
  ushort* Wl1 = (ushort*)sm; sm += 262144;
  ushort* Wh2 = (ushort*)sm; sm += 131072;
  ushort* Wl2 = (ushort*)sm; sm += 131072;
  ushort* Wh3 = (ushort*)sm; sm += 16384;
  ushort* Wl3 = (ushort*)sm; sm += 16384;
  float* muT_raw = sm; sm += (long)B_ * K_ * D_;
  float* n_muT = sm;   sm += (long)B_ * K_ * D_;
  ushort* nmu_h = (ushort*)sm; sm += 262144;
  ushort* nmu_l = (ushort*)sm; sm += 262144;
  float* partM = sm;  sm += 2 * 16 * 64 * 16;
  float* partS = sm;  sm += 2 * 16 * 64 * 16;
  unsigned int* cnt = (unsigned int*)sm; sm += 512;
  float* invn = sm; sm += (long)B_ * N_;   // accumulates sumsq, then 1/norm in place
  float* mu_x = sm;   sm += 2048;
  float* yn = sm;     sm += 512;
  float* pi_raw = sm; sm += 512;
  float* sc1 = sm; sm += 512;
  float* sh1 = sm; sm += 512;
  float* sc2 = sm; sm += 512;
  float* sh2 = sm; sm += 512;

  hipMemsetAsync(d_out, 0, sizeof(float) * out_size, stream);
  hipMemsetAsync(pi_raw, 0, 512 * sizeof(float), stream);
  hipMemsetAsync(cnt, 0, 512 * sizeof(unsigned int), stream);
  hipMemsetAsync(muT_raw, 0, (long)B_ * K_ * D_ * sizeof(float), stream);
  hipMemsetAsync(invn, 0, (long)B_ * N_ * sizeof(float), stream);

  split_w<<<(H_ * D_) / 256, 256, 0, stream>>>(w1, Wh1, Wl1, H_ * D_);
  split_w<<<(H_ * H_) / 256, 256, 0, stream>>>(w2, Wh2, Wl2, H_ * H_);
  split_w<<<(K_ * H_) / 256, 256, 0, stream>>>(w3, Wh3, Wl3, K_ * H_);
  {
    dim3 g(N_ / 64, D_ / 64, B_);
    transpose_split<<<g, 256, 0, stream>>>(feature, FhT, FlT, invn);
  }
  inv_fin<<<(B_ * N_) / 256, 256, 0, stream>>>(invn);
  // conv1
  {
    dim3 g(N_ / 128, H_ / 128, B_);
    gemm_split_bf16<<<g, 256, 0, stream>>>(Wh1, Wl1, FhT, FlT, h1raw, b1,
                                           N_, D_, (long)N_ * D_, (long)H_ * N_);
  }
  bn_stats<<<H_, 256, 0, stream>>>(h1raw, g1, be1, sc1, sh1, H_);
  {
    dim3 g(N_ / 64, H_ / 64, B_);
    bn_relu_t<<<g, 256, 0, stream>>>(h1raw, sc1, sh1, h1hT, h1lT);
  }
  // conv2
  {
    dim3 g(N_ / 128, H_ / 128, B_);
    gemm_split_bf16<<<g, 256, 0, stream>>>(Wh2, Wl2, h1hT, h1lT, h2, b2,
                                           N_, H_, (long)N_ * H_, (long)H_ * N_);
  }
  bn_stats<<<H_, 256, 0, stream>>>(h2, g2, be2, sc2, sh2, H_);
  {
    dim3 g(N_ / 64, H_ / 64, B_);
    bn_relu_t<<<g, 256, 0, stream>>>(h2, sc2, sh2, h2hT, h2lT);
  }
  // conv3
  {
    dim3 g(N_ / 128, 1, B_);
    gemm64_bb<<<g, 256, 0, stream>>>(Wh3, Wl3, h2hT, h2lT, log_score, b3,
                                     N_, H_, (long)N_ * H_, (long)K_ * N_);
  }
  softmax_nk<<<B_ * N_ / 256, 256, 0, stream>>>(log_score, score_KN, sc_h, sc_l,
                                                logpNK, pi_raw);
  {
    dim3 g(K_, B_);
    mu_xyz_k<<<g, 64, 0, stream>>>(score_KN, xyz, pi_raw, mu_x, yn);
  }
  reg_xyz_k<<<B_, 256, 0, stream>>>(mu_x, out);
  // mu_fea
  {
    dim3 g(D_ / 128, 4, B_);
    gemm64_bf<<<g, 256, 0, stream>>>(sc_h, sc_l, feature, muT_raw);
  }
  {
    dim3 g(K_, B_);
    mu_finalize<<<g, 256, 0, stream>>>(muT_raw, pi_raw, n_muT, nmu_h, nmu_l);
  }
  {
    dim3 g(K_, B_);
    reg_fea_k<<<g, 256, 0, stream>>>(n_muT, out);
  }
  // cost_fea
  {
    dim3 g(N_ / 128, 1, B_);
    gemm64_bt<<<g, 256, 0, stream>>>(nmu_h, nmu_l, feature, invn, cost_f);
  }
  // cooperative Sinkhorn + fused loss
  {
    void* kargs[] = {(void*)&cost_f, (void*)&xyz, (void*)&mu_x, (void*)&yn,
                     (void*)&logpNK, (void*)&out, (void*)&partM, (void*)&partS,
                     (void*)&cnt};
    hipLaunchCooperativeKernel((const void*)sinkhorn_coop, dim3(256), dim3(256),
                               kargs, 0, stream);
  }
}

// Round 7
// 1185.908 us; speedup vs baseline: 5.2513x; 1.0541x over previous
//
#include <hip/hip_runtime.h>
#include <math.h>

#define B_ 8
#define D_ 1024
#define N_ 4096
#define K_ 64
#define H_ 512

typedef short sx8 __attribute__((ext_vector_type(8)));
typedef float fx4 __attribute__((ext_vector_type(4)));

// ---------------- helpers ----------------
__device__ __forceinline__ float block_reduce_sum256(float v, float* sm) {
  int tid = threadIdx.x;
  sm[tid] = v;
  __syncthreads();
  for (int s = 128; s > 0; s >>= 1) {
    if (tid < s) sm[tid] += sm[tid + s];
    __syncthreads();
  }
  float r = sm[0];
  __syncthreads();
  return r;
}

__device__ __forceinline__ ushort f2bf(float f) {
  unsigned u = __float_as_uint(f);
  unsigned r = (u + 0x7fffu + ((u >> 16) & 1u)) >> 16;
  return (ushort)r;
}
__device__ __forceinline__ float bf2f(ushort h) {
  return __uint_as_float(((unsigned)h) << 16);
}

// ---------------- fused weight split (w1,w2,w3 in one launch) ----------------
__global__ __launch_bounds__(256)
void split_w3(const float* __restrict__ W1, const float* __restrict__ W2,
              const float* __restrict__ W3, ushort* __restrict__ Wh1,
              ushort* __restrict__ Wl1, ushort* __restrict__ Wh2,
              ushort* __restrict__ Wl2, ushort* __restrict__ Wh3,
              ushort* __restrict__ Wl3) {
  int i = blockIdx.x * 256 + threadIdx.x;
  const float* W;
  ushort *Wh, *Wl;
  int o;
  if (i < 524288) { W = W1; Wh = Wh1; Wl = Wl1; o = i; }
  else if (i < 786432) { W = W2; Wh = Wh2; Wl = Wl2; o = i - 524288; }
  else { W = W3; Wh = Wh3; Wl = Wl3; o = i - 786432; }
  float f = W[o];
  ushort h = f2bf(f);
  Wh[o] = h;
  Wl[o] = f2bf(f - bf2f(h));
}

// ---------------- feature transpose+split + fused column sumsq ----------------
__global__ __launch_bounds__(256)
void transpose_split(const float* __restrict__ F, ushort* __restrict__ FhT,
                     ushort* __restrict__ FlT, float* __restrict__ nrmsq) {
  __shared__ float tile[64][65];
  __shared__ float nsq[64];
  int b = blockIdx.z, d0 = blockIdx.y * 64, n0 = blockIdx.x * 64;
  const float* src = F + ((long)b * D_ + d0) * N_ + n0;
  int t = threadIdx.x;
  if (t < 64) nsq[t] = 0.f;
  int rr4 = t >> 4, c4 = (t & 15) * 4;
#pragma unroll
  for (int p = 0; p < 4; ++p) {
    int dr = p * 16 + rr4;
    float4 v = *(const float4*)(src + (long)dr * N_ + c4);
    tile[dr][c4 + 0] = v.x;
    tile[dr][c4 + 1] = v.y;
    tile[dr][c4 + 2] = v.z;
    tile[dr][c4 + 3] = v.w;
  }
  __syncthreads();
  int nlb = t >> 3, ds = (t & 7) * 8;
#pragma unroll
  for (int p = 0; p < 2; ++p) {
    int nl = p * 32 + nlb;
    sx8 hv, lv;
    float sq = 0.f;
#pragma unroll
    for (int j = 0; j < 8; ++j) {
      float f = tile[ds + j][nl];
      sq += f * f;
      ushort h = f2bf(f);
      hv[j] = (short)h;
      lv[j] = (short)f2bf(f - bf2f(h));
    }
    atomicAdd(&nsq[nl], sq);
    long o = ((long)b * N_ + n0 + nl) * D_ + d0 + ds;
    *(sx8*)(FhT + o) = hv;
    *(sx8*)(FlT + o) = lv;
  }
  __syncthreads();
  if (t < 64) atomicAdd(&nrmsq[(long)b * N_ + n0 + t], nsq[t]);
}

// in-place: q = 1/max(sqrt(q),1e-12)
__global__ void inv_fin(float* __restrict__ q) {
  int i = blockIdx.x * 256 + threadIdx.x;
  float v = q[i];
  q[i] = 1.f / fmaxf(sqrtf(v), 1e-12f);
}

// ---------------- 128x128 split-bf16 MFMA GEMM (conv1/conv2) ----------------
__global__ __launch_bounds__(256)
void gemm_split_bf16(const ushort* __restrict__ Ah, const ushort* __restrict__ Al,
                     const ushort* __restrict__ BhT, const ushort* __restrict__ BlT,
                     float* __restrict__ C, const float* __restrict__ bias,
                     int N, int Kd, long sBT, long sC) {
  __shared__ ushort As[2][128][40];
  __shared__ ushort Bs[2][128][40];
  const int t = threadIdx.x;
  const int m0 = blockIdx.y * 128, n0 = blockIdx.x * 128;
  const long bo = (long)blockIdx.z * sBT;
  float* Cp = C + (long)blockIdx.z * sC;
  const int half = t >> 7, r = t & 127;
  const ushort* Asrc = (half ? Al : Ah) + (long)(m0 + r) * Kd;
  const ushort* Bsrc = (half ? BlT : BhT) + bo + (long)(n0 + r) * Kd;
  ushort* AsD = &As[half][r][0];
  ushort* BsD = &Bs[half][r][0];
  const int w = t >> 6, ln = t & 15, qd = (t & 63) >> 4;
  const int wm = w >> 1, wn = w & 1;

  fx4 acc[4][4];
#pragma unroll
  for (int i = 0; i < 4; ++i)
#pragma unroll
    for (int j = 0; j < 4; ++j) acc[i][j] = (fx4)0.f;

  for (int k0 = 0; k0 < Kd; k0 += 32) {
    uint4 a0 = *(const uint4*)(Asrc + k0);
    uint4 a1 = *(const uint4*)(Asrc + k0 + 8);
    uint4 a2 = *(const uint4*)(Asrc + k0 + 16);
    uint4 a3 = *(const uint4*)(Asrc + k0 + 24);
    uint4 b0 = *(const uint4*)(Bsrc + k0);
    uint4 b1 = *(const uint4*)(Bsrc + k0 + 8);
    uint4 b2 = *(const uint4*)(Bsrc + k0 + 16);
    uint4 b3 = *(const uint4*)(Bsrc + k0 + 24);
    __syncthreads();
    *(uint4*)(AsD + 0) = a0;
    *(uint4*)(AsD + 8) = a1;
    *(uint4*)(AsD + 16) = a2;
    *(uint4*)(AsD + 24) = a3;
    *(uint4*)(BsD + 0) = b0;
    *(uint4*)(BsD + 8) = b1;
    *(uint4*)(BsD + 16) = b2;
    *(uint4*)(BsD + 24) = b3;
    __syncthreads();
    sx8 ahf[4], alf[4], bhf[4], blf[4];
#pragma unroll
    for (int mt = 0; mt < 4; ++mt) {
      ahf[mt] = *(const sx8*)&As[0][wm * 64 + mt * 16 + ln][qd * 8];
      alf[mt] = *(const sx8*)&As[1][wm * 64 + mt * 16 + ln][qd * 8];
    }
#pragma unroll
    for (int nt = 0; nt < 4; ++nt) {
      bhf[nt] = *(const sx8*)&Bs[0][wn * 64 + nt * 16 + ln][qd * 8];
      blf[nt] = *(const sx8*)&Bs[1][wn * 64 + nt * 16 + ln][qd * 8];
    }
#pragma unroll
    for (int mt = 0; mt < 4; ++mt)
#pragma unroll
      for (int nt = 0; nt < 4; ++nt) {
        acc[mt][nt] = __builtin_amdgcn_mfma_f32_16x16x32_bf16(ahf[mt], bhf[nt], acc[mt][nt], 0, 0, 0);
        acc[mt][nt] = __builtin_amdgcn_mfma_f32_16x16x32_bf16(alf[mt], bhf[nt], acc[mt][nt], 0, 0, 0);
        acc[mt][nt] = __builtin_amdgcn_mfma_f32_16x16x32_bf16(ahf[mt], blf[nt], acc[mt][nt], 0, 0, 0);
      }
  }
#pragma unroll
  for (int mt = 0; mt < 4; ++mt) {
#pragma unroll
    for (int rr = 0; rr < 4; ++rr) {
      int row = m0 + wm * 64 + mt * 16 + qd * 4 + rr;
      float bb = bias[row];
#pragma unroll
      for (int nt = 0; nt < 4; ++nt) {
        int col = n0 + wn * 64 + nt * 16 + ln;
        Cp[(long)row * N + col] = acc[mt][nt][rr] + bb;
      }
    }
  }
}

// ================= M64 split-bf16 MFMA family =================

// --- variant bb: A pre-split [64][Kd], B pre-split transposed [Nc][Kd] (conv3) ---
__global__ __launch_bounds__(256)
void gemm64_bb(const ushort* __restrict__ Ah, const ushort* __restrict__ Al,
               const ushort* __restrict__ BhT, const ushort* __restrict__ BlT,
               float* __restrict__ C, const float* __restrict__ bias,
               int N, int Kd, long sBT, long sC) {
  __shared__ ushort As[2][64][40];
  __shared__ ushort Bs[2][128][40];
  const int t = threadIdx.x;
  const int n0 = blockIdx.x * 128;
  float* Cp = C + (long)blockIdx.z * sC;
  const int hB = t >> 7, rB = t & 127;
  const ushort* Bsrc = (hB ? BlT : BhT) + (long)blockIdx.z * sBT + (long)(n0 + rB) * Kd;
  ushort* BsD = &Bs[hB][rB][0];
  const bool doA = t < 128;
  const int hA = (t >> 6) & 1, rA = t & 63;
  const ushort* Asrc = (hA ? Al : Ah) + (long)rA * Kd;
  ushort* AsD = &As[hA][rA][0];
  const int w = t >> 6, ln = t & 15, qd = (t & 63) >> 4;
  const int wm = w >> 1, wn = w & 1;

  fx4 acc[2][4];
#pragma unroll
  for (int i = 0; i < 2; ++i)
#pragma unroll
    for (int j = 0; j < 4; ++j) acc[i][j] = (fx4)0.f;

  for (int k0 = 0; k0 < Kd; k0 += 32) {
    uint4 b0 = *(const uint4*)(Bsrc + k0);
    uint4 b1 = *(const uint4*)(Bsrc + k0 + 8);
    uint4 b2 = *(const uint4*)(Bsrc + k0 + 16);
    uint4 b3 = *(const uint4*)(Bsrc + k0 + 24);
    uint4 a0, a1, a2, a3;
    if (doA) {
      a0 = *(const uint4*)(Asrc + k0);
      a1 = *(const uint4*)(Asrc + k0 + 8);
      a2 = *(const uint4*)(Asrc + k0 + 16);
      a3 = *(const uint4*)(Asrc + k0 + 24);
    }
    __syncthreads();
    *(uint4*)(BsD + 0) = b0;
    *(uint4*)(BsD + 8) = b1;
    *(uint4*)(BsD + 16) = b2;
    *(uint4*)(BsD + 24) = b3;
    if (doA) {
      *(uint4*)(AsD + 0) = a0;
      *(uint4*)(AsD + 8) = a1;
      *(uint4*)(AsD + 16) = a2;
      *(uint4*)(AsD + 24) = a3;
    }
    __syncthreads();
    sx8 ahf[2], alf[2], bhf[4], blf[4];
#pragma unroll
    for (int mt = 0; mt < 2; ++mt) {
      ahf[mt] = *(const sx8*)&As[0][wm * 32 + mt * 16 + ln][qd * 8];
      alf[mt] = *(const sx8*)&As[1][wm * 32 + mt * 16 + ln][qd * 8];
    }
#pragma unroll
    for (int nt = 0; nt < 4; ++nt) {
      bhf[nt] = *(const sx8*)&Bs[0][wn * 64 + nt * 16 + ln][qd * 8];
      blf[nt] = *(const sx8*)&Bs[1][wn * 64 + nt * 16 + ln][qd * 8];
    }
#pragma unroll
    for (int mt = 0; mt < 2; ++mt)
#pragma unroll
      for (int nt = 0; nt < 4; ++nt) {
        acc[mt][nt] = __builtin_amdgcn_mfma_f32_16x16x32_bf16(ahf[mt], bhf[nt], acc[mt][nt], 0, 0, 0);
        acc[mt][nt] = __builtin_amdgcn_mfma_f32_16x16x32_bf16(alf[mt], bhf[nt], acc[mt][nt], 0, 0, 0);
        acc[mt][nt] = __builtin_amdgcn_mfma_f32_16x16x32_bf16(ahf[mt], blf[nt], acc[mt][nt], 0, 0, 0);
      }
  }
#pragma unroll
  for (int mt = 0; mt < 2; ++mt)
#pragma unroll
    for (int rr = 0; rr < 4; ++rr) {
      int row = wm * 32 + mt * 16 + qd * 4 + rr;
      float bb = bias[row];
#pragma unroll
      for (int nt = 0; nt < 4; ++nt) {
        int col = n0 + wn * 64 + nt * 16 + ln;
        Cp[(long)row * N + col] = acc[mt][nt][rr] + bb;
      }
    }
}

// --- variant bf: A pre-split [b][64][N_], B = f32 rows natural along Kd (mu_fea) ---
__global__ __launch_bounds__(256)
void gemm64_bf(const ushort* __restrict__ Ah, const ushort* __restrict__ Al,
               const float* __restrict__ Bf, float* __restrict__ Cacc) {
  __shared__ ushort As[2][64][40];
  __shared__ ushort Bs[2][128][40];
  const int t = threadIdx.x;
  const int nc0 = blockIdx.x * 128;
  const int kBeg = blockIdx.y * 1024;
  const int b = blockIdx.z;
  const int pc = t >> 7, rB = t & 127;
  const float* Bsrc = Bf + (long)b * D_ * N_ + (long)(nc0 + rB) * N_ + kBeg + pc * 16;
  const bool doA = t < 128;
  const int hA = (t >> 6) & 1, rA = t & 63;
  const ushort* Asrc = (hA ? Al : Ah) + (long)b * K_ * N_ + (long)rA * N_ + kBeg;
  ushort* AsD = &As[hA][rA][0];
  const int w = t >> 6, ln = t & 15, qd = (t & 63) >> 4;
  const int wm = w >> 1, wn = w & 1;

  fx4 acc[2][4];
#pragma unroll
  for (int i = 0; i < 2; ++i)
#pragma unroll
    for (int j = 0; j < 4; ++j) acc[i][j] = (fx4)0.f;

  for (int k0 = 0; k0 < 1024; k0 += 32) {
    float4 f0 = *(const float4*)(Bsrc + k0);
    float4 f1 = *(const float4*)(Bsrc + k0 + 4);
    float4 f2 = *(const float4*)(Bsrc + k0 + 8);
    float4 f3 = *(const float4*)(Bsrc + k0 + 12);
    uint4 a0, a1, a2, a3;
    if (doA) {
      a0 = *(const uint4*)(Asrc + k0);
      a1 = *(const uint4*)(Asrc + k0 + 8);
      a2 = *(const uint4*)(Asrc + k0 + 16);
      a3 = *(const uint4*)(Asrc + k0 + 24);
    }
    float fv[16] = {f0.x, f0.y, f0.z, f0.w, f1.x, f1.y, f1.z, f1.w,
                    f2.x, f2.y, f2.z, f2.w, f3.x, f3.y, f3.z, f3.w};
    sx8 hv0, hv1, lv0, lv1;
#pragma unroll
    for (int j = 0; j < 8; ++j) {
      ushort h = f2bf(fv[j]);
      hv0[j] = (short)h;
      lv0[j] = (short)f2bf(fv[j] - bf2f(h));
    }
#pragma unroll
    for (int j = 0; j < 8; ++j) {
      ushort h = f2bf(fv[8 + j]);
      hv1[j] = (short)h;
      lv1[j] = (short)f2bf(fv[8 + j] - bf2f(h));
    }
    __syncthreads();
    *(sx8*)&Bs[0][rB][pc * 16] = hv0;
    *(sx8*)&Bs[0][rB][pc * 16 + 8] = hv1;
    *(sx8*)&Bs[1][rB][pc * 16] = lv0;
    *(sx8*)&Bs[1][rB][pc * 16 + 8] = lv1;
    if (doA) {
      *(uint4*)(AsD + 0) = a0;
      *(uint4*)(AsD + 8) = a1;
      *(uint4*)(AsD + 16) = a2;
      *(uint4*)(AsD + 24) = a3;
    }
    __syncthreads();
    sx8 ahf[2], alf[2], bhf[4], blf[4];
#pragma unroll
    for (int mt = 0; mt < 2; ++mt) {
      ahf[mt] = *(const sx8*)&As[0][wm * 32 + mt * 16 + ln][qd * 8];
      alf[mt] = *(const sx8*)&As[1][wm * 32 + mt * 16 + ln][qd * 8];
    }
#pragma unroll
    for (int nt = 0; nt < 4; ++nt) {
      bhf[nt] = *(const sx8*)&Bs[0][wn * 64 + nt * 16 + ln][qd * 8];
      blf[nt] = *(const sx8*)&Bs[1][wn * 64 + nt * 16 + ln][qd * 8];
    }
#pragma unroll
    for (int mt = 0; mt < 2; ++mt)
#pragma unroll
      for (int nt = 0; nt < 4; ++nt) {
        acc[mt][nt] = __builtin_amdgcn_mfma_f32_16x16x32_bf16(ahf[mt], bhf[nt], acc[mt][nt], 0, 0, 0);
        acc[mt][nt] = __builtin_amdgcn_mfma_f32_16x16x32_bf16(alf[mt], bhf[nt], acc[mt][nt], 0, 0, 0);
        acc[mt][nt] = __builtin_amdgcn_mfma_f32_16x16x32_bf16(ahf[mt], blf[nt], acc[mt][nt], 0, 0, 0);
      }
  }
#pragma unroll
  for (int mt = 0; mt < 2; ++mt)
#pragma unroll
    for (int rr = 0; rr < 4; ++rr) {
      int row = wm * 32 + mt * 16 + qd * 4 + rr;
#pragma unroll
      for (int nt = 0; nt < 4; ++nt) {
        int col = nc0 + wn * 64 + nt * 16 + ln;
        atomicAdd(&Cacc[((long)b * K_ + row) * D_ + col], acc[mt][nt][rr]);
      }
    }
}

// --- variant bt: A pre-split [b][64][D_], B = f32 [D][N] transposed in LDS (cost_fea) ---
__global__ __launch_bounds__(256)
void gemm64_bt(const ushort* __restrict__ Ah, const ushort* __restrict__ Al,
               const float* __restrict__ Bf, const float* __restrict__ invn,
               float* __restrict__ cost) {
  __shared__ ushort As[2][64][40];
  __shared__ ushort Bs[2][128][40];
  __shared__ float Ft[32][132];
  const int t = threadIdx.x;
  const int n0 = blockIdx.x * 128;
  const int b = blockIdx.z;
  const float* Fsrc = Bf + (long)b * D_ * N_;
  const bool doA = t < 128;
  const int hA = (t >> 6) & 1, rA = t & 63;
  const ushort* Asrc = (hA ? Al : Ah) + (long)b * K_ * D_ + (long)rA * D_;
  ushort* AsD = &As[hA][rA][0];
  const int dr = t >> 3, cc = (t & 7) * 16;
  const int nl = t & 127, dh = t >> 7;
  const int w = t >> 6, ln = t & 15, qd = (t & 63) >> 4;
  const int wm = w >> 1, wn = w & 1;

  fx4 acc[2][4];
#pragma unroll
  for (int i = 0; i < 2; ++i)
#pragma unroll
    for (int j = 0; j < 4; ++j) acc[i][j] = (fx4)0.f;

  for (int k0 = 0; k0 < D_; k0 += 32) {
    float4 f0 = *(const float4*)(Fsrc + (long)(k0 + dr) * N_ + n0 + cc);
    float4 f1 = *(const float4*)(Fsrc + (long)(k0 + dr) * N_ + n0 + cc + 4);
    float4 f2 = *(const float4*)(Fsrc + (long)(k0 + dr) * N_ + n0 + cc + 8);
    float4 f3 = *(const float4*)(Fsrc + (long)(k0 + dr) * N_ + n0 + cc + 12);
    uint4 a0, a1, a2, a3;
    if (doA) {
      a0 = *(const uint4*)(Asrc + k0);
      a1 = *(const uint4*)(Asrc + k0 + 8);
      a2 = *(const uint4*)(Asrc + k0 + 16);
      a3 = *(const uint4*)(Asrc + k0 + 24);
    }
    __syncthreads();
    *(float4*)&Ft[dr][cc] = f0;
    *(float4*)&Ft[dr][cc + 4] = f1;
    *(float4*)&Ft[dr][cc + 8] = f2;
    *(float4*)&Ft[dr][cc + 12] = f3;
    if (doA) {
      *(uint4*)(AsD + 0) = a0;
      *(uint4*)(AsD + 8) = a1;
      *(uint4*)(AsD + 16) = a2;
      *(uint4*)(AsD + 24) = a3;
    }
    __syncthreads();
    float fv[16];
#pragma unroll
    for (int j = 0; j < 16; ++j) fv[j] = Ft[dh * 16 + j][nl];
    sx8 hv0, hv1, lv0, lv1;
#pragma unroll
    for (int j = 0; j < 8; ++j) {
      ushort h = f2bf(fv[j]);
      hv0[j] = (short)h;
      lv0[j] = (short)f2bf(fv[j] - bf2f(h));
    }
#pragma unroll
    for (int j = 0; j < 8; ++j) {
      ushort h = f2bf(fv[8 + j]);
      hv1[j] = (short)h;
      lv1[j] = (short)f2bf(fv[8 + j] - bf2f(h));
    }
    *(sx8*)&Bs[0][nl][dh * 16] = hv0;
    *(sx8*)&Bs[0][nl][dh * 16 + 8] = hv1;
    *(sx8*)&Bs[1][nl][dh * 16] = lv0;
    *(sx8*)&Bs[1][nl][dh * 16 + 8] = lv1;
    __syncthreads();
    sx8 ahf[2], alf[2], bhf[4], blf[4];
#pragma unroll
    for (int mt = 0; mt < 2; ++mt) {
      ahf[mt] = *(const sx8*)&As[0][wm * 32 + mt * 16 + ln][qd * 8];
      alf[mt] = *(const sx8*)&As[1][wm * 32 + mt * 16 + ln][qd * 8];
    }
#pragma unroll
    for (int nt = 0; nt < 4; ++nt) {
      bhf[nt] = *(const sx8*)&Bs[0][wn * 64 + nt * 16 + ln][qd * 8];
      blf[nt] = *(const sx8*)&Bs[1][wn * 64 + nt * 16 + ln][qd * 8];
    }
#pragma unroll
    for (int mt = 0; mt < 2; ++mt)
#pragma unroll
      for (int nt = 0; nt < 4; ++nt) {
        acc[mt][nt] = __builtin_amdgcn_mfma_f32_16x16x32_bf16(ahf[mt], bhf[nt], acc[mt][nt], 0, 0, 0);
        acc[mt][nt] = __builtin_amdgcn_mfma_f32_16x16x32_bf16(alf[mt], bhf[nt], acc[mt][nt], 0, 0, 0);
        acc[mt][nt] = __builtin_amdgcn_mfma_f32_16x16x32_bf16(ahf[mt], blf[nt], acc[mt][nt], 0, 0, 0);
      }
  }
#pragma unroll
  for (int nt = 0; nt < 4; ++nt) {
    int col = n0 + wn * 64 + nt * 16 + ln;
    float iv = invn[b * N_ + col];
#pragma unroll
    for (int mt = 0; mt < 2; ++mt)
#pragma unroll
      for (int rr = 0; rr < 4; ++rr) {
        int row = wm * 32 + mt * 16 + qd * 4 + rr;
        cost[((long)b * K_ + row) * N_ + col] = 2.f - 2.f * acc[mt][nt][rr] * iv;
      }
  }
}

// ---------------- BN stats ----------------
__global__ __launch_bounds__(256)
void bn_stats(const float* __restrict__ Y, const float* __restrict__ g,
              const float* __restrict__ be, float* __restrict__ scale,
              float* __restrict__ shift, int C) {
  int c = blockIdx.x;
  double s1 = 0.0, s2 = 0.0;
  for (int idx = threadIdx.x; idx < B_ * N_; idx += 256) {
    int b = idx >> 12, n = idx & (N_ - 1);
    float v = Y[((long)b * C + c) * N_ + n];
    s1 += v;
    s2 += (double)v * (double)v;
  }
  __shared__ double r1[256], r2[256];
  int tid = threadIdx.x;
  r1[tid] = s1; r2[tid] = s2;
  __syncthreads();
  for (int s = 128; s > 0; s >>= 1) {
    if (tid < s) { r1[tid] += r1[tid + s]; r2[tid] += r2[tid + s]; }
    __syncthreads();
  }
  if (tid == 0) {
    double m = r1[0] / (double)(B_ * N_);
    double var = r2[0] / (double)(B_ * N_) - m * m;
    float sc = (float)((double)g[c] / sqrt(var + 1e-5));
    scale[c] = sc;
    shift[c] = (float)((double)be[c] - m * (double)sc);
  }
}

// ---------------- BN+ReLU + transpose+split ----------------
__global__ __launch_bounds__(256)
void bn_relu_t(const float* __restrict__ Y, const float* __restrict__ scale,
               const float* __restrict__ shift, ushort* __restrict__ OhT,
               ushort* __restrict__ OlT) {
  __shared__ float tile[64][65];
  int b = blockIdx.z, h0 = blockIdx.y * 64, n0 = blockIdx.x * 64;
  const float* src = Y + ((long)b * H_ + h0) * N_ + n0;
  int t = threadIdx.x;
  int rr4 = t >> 4, c4 = (t & 15) * 4;
#pragma unroll
  for (int p = 0; p < 4; ++p) {
    int hl = p * 16 + rr4;
    float sc = scale[h0 + hl], sh = shift[h0 + hl];
    float4 v = *(const float4*)(src + (long)hl * N_ + c4);
    tile[hl][c4 + 0] = fmaxf(v.x * sc + sh, 0.f);
    tile[hl][c4 + 1] = fmaxf(v.y * sc + sh, 0.f);
    tile[hl][c4 + 2] = fmaxf(v.z * sc + sh, 0.f);
    tile[hl][c4 + 3] = fmaxf(v.w * sc + sh, 0.f);
  }
  __syncthreads();
  int nlb = t >> 3, hs = (t & 7) * 8;
#pragma unroll
  for (int p = 0; p < 2; ++p) {
    int nl = p * 32 + nlb;
    sx8 hv, lv;
#pragma unroll
    for (int j = 0; j < 8; ++j) {
      float f = tile[hs + j][nl];
      ushort h = f2bf(f);
      hv[j] = (short)h;
      lv[j] = (short)f2bf(f - bf2f(h));
    }
    long o = ((long)b * N_ + n0 + nl) * H_ + h0 + hs;
    *(sx8*)(OhT + o) = hv;
    *(sx8*)(OlT + o) = lv;
  }
}

// ---------------- softmax: score f32/bf16, logp [b][n][K] ----------------
__global__ __launch_bounds__(256)
void softmax_nk(const float* __restrict__ ls, float* __restrict__ scoreKN,
                ushort* __restrict__ sch, ushort* __restrict__ scl,
                float* __restrict__ logpNK, float* __restrict__ pi_raw) {
  __shared__ float L[64][65];
  __shared__ float ploc[64];
  int tid = threadIdx.x;
  if (tid < 64) ploc[tid] = 0.f;
  __syncthreads();
  int bi = blockIdx.x >> 4;
  int nb = (blockIdx.x & 15) * 256;
  int n = nb + tid;
  const float* x = ls + ((long)bi * K_) * N_ + n;
  float xv[64];
#pragma unroll
  for (int k = 0; k < 64; ++k) xv[k] = x[(long)k * N_];
  float mx = -1e30f;
#pragma unroll
  for (int k = 0; k < 64; ++k) mx = fmaxf(mx, xv[k]);
  float s = 0.f;
#pragma unroll
  for (int k = 0; k < 64; ++k) s += __expf(xv[k] - mx);
  float lg = __logf(s);
  float inv = 1.f / s;
#pragma unroll
  for (int k = 0; k < 64; ++k) {
    float sc = __expf(xv[k] - mx) * inv;
    long o = ((long)bi * K_ + k) * N_ + n;
    scoreKN[o] = sc;
    ushort h = f2bf(sc);
    sch[o] = h;
    scl[o] = f2bf(sc - bf2f(h));
    atomicAdd(&ploc[k], sc);
  }
  __syncthreads();
  if (tid < 64) atomicAdd(&pi_raw[bi * 64 + tid], ploc[tid]);
  int myw = tid >> 6, nl = tid & 63;
  int row = tid >> 2, ch = (tid & 3) * 16;
  for (int p = 0; p < 4; ++p) {
    __syncthreads();
    if (myw == p) {
#pragma unroll
      for (int k = 0; k < 64; ++k) L[nl][k] = xv[k] - mx - lg;
    }
    __syncthreads();
    float o0[16];
#pragma unroll
    for (int j = 0; j < 16; ++j) o0[j] = L[row][ch + j];
    float* dst = logpNK + ((long)bi * N_ + nb + p * 64 + row) * 64 + ch;
    *(float4*)(dst + 0) = make_float4(o0[0], o0[1], o0[2], o0[3]);
    *(float4*)(dst + 4) = make_float4(o0[4], o0[5], o0[6], o0[7]);
    *(float4*)(dst + 8) = make_float4(o0[8], o0[9], o0[10], o0[11]);
    *(float4*)(dst + 12) = make_float4(o0[12], o0[13], o0[14], o0[15]);
  }
}

// ---------------- mu_xyz ----------------
__global__ __launch_bounds__(64)
void mu_xyz_k(const float* __restrict__ scoreKN, const float* __restrict__ xyz,
              const float* __restrict__ pi_raw, float* __restrict__ mu,
              float* __restrict__ yn) {
  int k = blockIdx.x, b = blockIdx.y, t = threadIdx.x;
  const float* st = scoreKN + ((long)b * K_ + k) * N_;
  const float* xp = xyz + (long)b * 3 * N_;
  float a0 = 0, a1 = 0, a2 = 0;
  for (int n = t; n < N_; n += 64) {
    float s = st[n];
    a0 += s * xp[n];
    a1 += s * xp[N_ + n];
    a2 += s * xp[2 * N_ + n];
  }
  for (int off = 32; off > 0; off >>= 1) {
    a0 += __shfl_down(a0, off);
    a1 += __shfl_down(a1, off);
    a2 += __shfl_down(a2, off);
  }
  if (t == 0) {
    float p = fmaxf(pi_raw[b * K_ + k], 1e-4f);
    float m0 = a0 / p, m1 = a1 / p, m2 = a2 / p;
    mu[((long)b * 3 + 0) * K_ + k] = m0;
    mu[((long)b * 3 + 1) * K_ + k] = m1;
    mu[((long)b * 3 + 2) * K_ + k] = m2;
    yn[b * K_ + k] = m0 * m0 + m1 * m1 + m2 * m2;
  }
}

// ---------------- regularizers ----------------
__global__ __launch_bounds__(256)
void reg_xyz_k(const float* __restrict__ mu, float* __restrict__ out) {
  __shared__ float red[256];
  int b = blockIdx.x, tid = threadIdx.x;
  float acc = 0.f;
  for (int e = tid; e < 4096; e += 256) {
    int m = e >> 6, n2 = e & 63;
    float g = 0.f;
    for (int d = 0; d < 3; ++d)
      g += mu[((long)b * 3 + d) * K_ + m] * mu[((long)b * 3 + d) * K_ + n2];
    acc += fabsf(g - (m == n2 ? 1.f : 0.f));
  }
  float tot = block_reduce_sum256(acc, red);
  if (tid == 0) atomicAdd(out, tot * (1e-7f / 32768.f));
}

__global__ __launch_bounds__(256)
void reg_fea_k(const float* __restrict__ nT, float* __restrict__ out) {
  __shared__ float pm[1024];
  __shared__ float red[256];
  int m = blockIdx.x, b = blockIdx.y, tid = threadIdx.x;
  const float* base = nT + (long)b * K_ * D_;
  *(float4*)&pm[tid * 4] = *(const float4*)(base + (long)m * D_ + tid * 4);
  __syncthreads();
  int n2 = tid >> 2, q = tid & 3;
  const float* pn = base + (long)n2 * D_ + q * 256;
  const float* pml = &pm[q * 256];
  float g = 0.f;
#pragma unroll 8
  for (int d = 0; d < 256; d += 4) {
    float4 v = *(const float4*)(pn + d);
    g += v.x * pml[d] + v.y * pml[d + 1] + v.z * pml[d + 2] + v.w * pml[d + 3];
  }
  g += __shfl_down(g, 2);
  g += __shfl_down(g, 1);
  float acc = (q == 0) ? fabsf(g - (m == n2 ? 1.f : 0.f)) : 0.f;
  float tot = block_reduce_sum256(acc, red);
  if (tid == 0) atomicAdd(out, tot * (1e-4f / 32768.f));
}

// ---------------- mu_fea finalize ----------------
__global__ __launch_bounds__(256)
void mu_finalize(const float* __restrict__ muT_raw, const float* __restrict__ pi_raw,
                 float* __restrict__ n_muT, ushort* __restrict__ nmu_h,
                 ushort* __restrict__ nmu_l) {
  __shared__ float red[256];
  int k = blockIdx.x, b = blockIdx.y, tid = threadIdx.x;
  float p = fmaxf(pi_raw[b * K_ + k], 1e-4f);
  const float* src = muT_raw + ((long)b * K_ + k) * D_;
  float ss = 0.f;
  for (int d = tid; d < D_; d += 256) {
    float v = src[d] / p;
    ss += v * v;
  }
  float tot = block_reduce_sum256(ss, red);
  float inv = 1.f / fmaxf(sqrtf(tot), 1e-12f);
  long o = ((long)b * K_ + k) * D_;
  for (int d = tid; d < D_; d += 256) {
    float v = src[d] / p * inv;
    n_muT[o + d] = v;
    ushort h = f2bf(v);
    nmu_h[o + d] = h;
    nmu_l[o + d] = f2bf(v - bf2f(h));
  }
}

// ---------------- cooperative Sinkhorn v3: coalesced packed partials ----------------
__global__ __launch_bounds__(256, 1)
void sinkhorn_coop(const float* __restrict__ cost_f, const float* __restrict__ xyz,
                   const float* __restrict__ mu, const float* __restrict__ yn,
                   const float* __restrict__ logpNK, float* __restrict__ out,
                   unsigned long long* __restrict__ partMS,
                   unsigned int* __restrict__ cnt) {
  __shared__ float tile[4][64][68];
  __shared__ float vsh[64];
  __shared__ float wm[4][64];
  __shared__ float wsum[4][64];
  __shared__ float red[256];
  __shared__ float mub[4][64];
  const int tid = threadIdx.x;
  const int g = blockIdx.x & 15;
  const int s = blockIdx.x >> 4;
  const int w = tid >> 6, lane = tid & 63;
  const int i = s * 256 + tid;
  const int b = g & 7;
  const float eps = 1e-3f, ti = 1000.0f;
  const float lgp = -8.317766166719343f;   // -log(4096)
  const float lgq = -4.1588830833596715f;  // -log(64)

  float c[64];
  if (g < 8) {
    if (tid < 64) {
      mub[0][tid] = mu[(b * 3 + 0) * K_ + tid];
      mub[1][tid] = mu[(b * 3 + 1) * K_ + tid];
      mub[2][tid] = mu[(b * 3 + 2) * K_ + tid];
      mub[3][tid] = yn[b * K_ + tid];
      vsh[tid] = 0.f;
    }
    __syncthreads();
    float x0 = xyz[((long)b * 3 + 0) * N_ + i];
    float x1 = xyz[((long)b * 3 + 1) * N_ + i];
    float x2 = xyz[((long)b * 3 + 2) * N_ + i];
    float xn = x0 * x0 + x1 * x1 + x2 * x2;
#pragma unroll
    for (int j = 0; j < 64; ++j)
      c[j] = xn + mub[3][j] - 2.f * (x0 * mub[0][j] + x1 * mub[1][j] + x2 * mub[2][j]);
  } else {
    const float* C = cost_f + (long)b * K_ * N_;
#pragma unroll
    for (int j = 0; j < 64; ++j) c[j] = C[(long)j * N_ + i];
    if (tid < 64) vsh[tid] = 0.f;
    __syncthreads();
  }
  float u = 0.f;

  for (int it = 0; it < 25; ++it) {
    float tj[64];
#pragma unroll
    for (int j = 0; j < 64; ++j) tj[j] = vsh[j] - c[j];
    float dm = -1e30f;
#pragma unroll
    for (int j = 0; j < 64; ++j) dm = fmaxf(dm, tj[j]);
    float ssum = 0.f;
#pragma unroll
    for (int j = 0; j < 64; ++j) ssum += __expf((tj[j] - dm) * ti);
    u = eps * (lgp - ((u + dm) * ti + __logf(ssum))) + u;
#pragma unroll
    for (int j4 = 0; j4 < 16; ++j4) {
      float4 v4;
      v4.x = (u + tj[j4 * 4 + 0]) * ti;
      v4.y = (u + tj[j4 * 4 + 1]) * ti;
      v4.z = (u + tj[j4 * 4 + 2]) * ti;
      v4.w = (u + tj[j4 * 4 + 3]) * ti;
      *(float4*)&tile[w][lane][j4 * 4] = v4;
    }
    __syncthreads();
    float M = -1e30f, S = 0.f;
#pragma unroll
    for (int r = 0; r < 64; ++r) {
      float a = tile[w][r][lane];
      M = fmaxf(M, a);
      S += __expf(a - lgp);
    }
    wm[w][lane] = M;
    wsum[w][lane] = S;
    __syncthreads();
    int buf = it & 1;
    if (tid < 64) {
      float Mb = fmaxf(fmaxf(wm[0][tid], wm[1][tid]), fmaxf(wm[2][tid], wm[3][tid]));
      float Sb = wsum[0][tid] + wsum[1][tid] + wsum[2][tid] + wsum[3][tid];
      // coalesced packed write: [buf][g][s][tid]
      unsigned long long pk =
          ((unsigned long long)__float_as_uint(Sb) << 32) | (unsigned long long)__float_as_uint(Mb);
      long idx = (((long)buf * 16 + g) * 16 + s) * 64 + tid;
      __hip_atomic_store(&partMS[idx], pk, __ATOMIC_RELAXED, __HIP_MEMORY_SCOPE_AGENT);
    }
    if (tid == 0) {
      __hip_atomic_fetch_add(&cnt[g * 32], 1u, __ATOMIC_ACQ_REL, __HIP_MEMORY_SCOPE_AGENT);
      unsigned target = 16u * (unsigned)(it + 1);
      while (__hip_atomic_load(&cnt[g * 32], __ATOMIC_ACQUIRE, __HIP_MEMORY_SCOPE_AGENT) < target)
        __builtin_amdgcn_s_sleep(1);
    }
    __syncthreads();
    if (tid < 64) {
      long base = (((long)buf * 16 + g) * 16) * 64 + tid;
      float M2 = -1e30f, S2 = 0.f;
#pragma unroll
      for (int p = 0; p < 16; ++p) {
        unsigned long long v =
            __hip_atomic_load(&partMS[base + (long)p * 64], __ATOMIC_RELAXED, __HIP_MEMORY_SCOPE_AGENT);
        M2 = fmaxf(M2, __uint_as_float((unsigned)v));
        S2 += __uint_as_float((unsigned)(v >> 32));
      }
      float lsec = fmaxf(M2, lgp + __logf(S2));
      vsh[tid] = eps * (lgq - lsec) + vsh[tid];
    }
    __syncthreads();
  }

  // fused loss
  const float* lp = logpNK + ((long)b * N_ + i) * 64;
  float part = 0.f;
#pragma unroll
  for (int j = 0; j < 64; ++j)
    part += __expf((u + vsh[j] - c[j]) * ti) * lp[j];
  red[tid] = part;
  __syncthreads();
  for (int st2 = 128; st2 > 0; st2 >>= 1) {
    if (tid < st2) red[tid] += red[tid + st2];
    __syncthreads();
  }
  if (tid == 0) atomicAdd(out, -red[0] / (float)B_);
}

// ---------------- launch ----------------
extern "C" void kernel_launch(void* const* d_in, const int* in_sizes, int n_in,
                              void* d_out, int out_size, void* d_ws, size_t ws_size,
                              hipStream_t stream) {
  const float* feature = (const float*)d_in[0];
  const float* xyz = (const float*)d_in[1];
  const float* w1 = (const float*)d_in[2];
  const float* b1 = (const float*)d_in[3];
  const float* g1 = (const float*)d_in[4];
  const float* be1 = (const float*)d_in[5];
  const float* w2 = (const float*)d_in[6];
  const float* b2 = (const float*)d_in[7];
  const float* g2 = (const float*)d_in[8];
  const float* be2 = (const float*)d_in[9];
  const float* w3 = (const float*)d_in[10];
  const float* b3 = (const float*)d_in[11];
  float* out = (float*)d_out;
  float* ws = (float*)d_ws;

  const long RSZ = 16777216L;
  float* regA = ws;
  float* regB1 = ws + RSZ;
  float* regB2 = ws + 2 * RSZ;
  float* sm = ws + 3 * RSZ;

  ushort* FhT = (ushort*)regB1;
  ushort* FlT = (ushort*)regB2;
  float* h1raw = regA;
  ushort* h1hT = (ushort*)regB1;
  ushort* h1lT = (ushort*)regB1 + RSZ;
  float* h2 = regB2;
  ushort* h2hT = (ushort*)regB1;
  ushort* h2lT = (ushort*)regB1 + RSZ;
  const long sz = (long)B_ * N_ * K_;
  float* log_score = regA;
  float* score_KN = regA + sz;
  float* logpNK = regA + 2 * sz;
  float* cost_f = regA + 3 * sz;
  ushort* sc_h = (ushort*)(regA + 4 * sz);
  ushort* sc_l = (ushort*)(regA + 4 * sz) + sz;

  ushort* Wh1 = (ushort*)sm; sm += 262144;
  ushort* Wl1 = (ushort*)sm; sm += 262144;
  ushort* Wh2 = (ushort*)sm; sm += 131072;
  ushort* Wl2 = (ushort*)sm; sm += 131072;
  ushort* Wh3 = (ushort*)sm; sm += 16384;
  ushort* Wl3 = (ushort*)sm; sm += 16384;
  float* muT_raw = sm; sm += (long)B_ * K_ * D_;
  float* n_muT = sm;   sm += (long)B_ * K_ * D_;
  ushort* nmu_h = (ushort*)sm; sm += 262144;
  ushort* nmu_l = (ushort*)sm; sm += 262144;
  unsigned long long* partMS = (unsigned long long*)sm; sm += 2 * 16 * 16 * 64 * 2;
  unsigned int* cnt = (unsigned int*)sm; sm += 512;
  float* invn = sm; sm += (long)B_ * N_;
  float* mu_x = sm;   sm += 2048;
  float* yn = sm;     sm += 512;
  float* pi_raw = sm; sm += 512;
  float* sc1 = sm; sm += 512;
  float* sh1 = sm; sm += 512;
  float* sc2 = sm; sm += 512;
  float* sh2 = sm; sm += 512;

  hipMemsetAsync(d_out, 0, sizeof(float) * out_size, stream);
  hipMemsetAsync(pi_raw, 0, 512 * sizeof(float), stream);
  hipMemsetAsync(cnt, 0, 512 * sizeof(unsigned int), stream);
  hipMemsetAsync(muT_raw, 0, (long)B_ * K_ * D_ * sizeof(float), stream);
  hipMemsetAsync(invn, 0, (long)B_ * N_ * sizeof(float), stream);

  split_w3<<<3200, 256, 0, stream>>>(w1, w2, w3, Wh1, Wl1, Wh2, Wl2, Wh3, Wl3);
  {
    dim3 g(N_ / 64, D_ / 64, B_);
    transpose_split<<<g, 256, 0, stream>>>(feature, FhT, FlT, invn);
  }
  inv_fin<<<(B_ * N_) / 256, 256, 0, stream>>>(invn);
  // conv1
  {
    dim3 g(N_ / 128, H_ / 128, B_);
    gemm_split_bf16<<<g, 256, 0, stream>>>(Wh1, Wl1, FhT, FlT, h1raw, b1,
                                           N_, D_, (long)N_ * D_, (long)H_ * N_);
  }
  bn_stats<<<H_, 256, 0, stream>>>(h1raw, g1, be1, sc1, sh1, H_);
  {
    dim3 g(N_ / 64, H_ / 64, B_);
    bn_relu_t<<<g, 256, 0, stream>>>(h1raw, sc1, sh1, h1hT, h1lT);
  }
  // conv2
  {
    dim3 g(N_ / 128, H_ / 128, B_);
    gemm_split_bf16<<<g, 256, 0, stream>>>(Wh2, Wl2, h1hT, h1lT, h2, b2,
                                           N_, H_, (long)N_ * H_, (long)H_ * N_);
  }
  bn_stats<<<H_, 256, 0, stream>>>(h2, g2, be2, sc2, sh2, H_);
  {
    dim3 g(N_ / 64, H_ / 64, B_);
    bn_relu_t<<<g, 256, 0, stream>>>(h2, sc2, sh2, h2hT, h2lT);
  }
  // conv3
  {
    dim3 g(N_ / 128, 1, B_);
    gemm64_bb<<<g, 256, 0, stream>>>(Wh3, Wl3, h2hT, h2lT, log_score, b3,
                                     N_, H_, (long)N_ * H_, (long)K_ * N_);
  }
  softmax_nk<<<B_ * N_ / 256, 256, 0, stream>>>(log_score, score_KN, sc_h, sc_l,
                                                logpNK, pi_raw);
  {
    dim3 g(K_, B_);
    mu_xyz_k<<<g, 64, 0, stream>>>(score_KN, xyz, pi_raw, mu_x, yn);
  }
  reg_xyz_k<<<B_, 256, 0, stream>>>(mu_x, out);
  // mu_fea
  {
    dim3 g(D_ / 128, 4, B_);
    gemm64_bf<<<g, 256, 0, stream>>>(sc_h, sc_l, feature, muT_raw);
  }
  {
    dim3 g(K_, B_);
    mu_finalize<<<g, 256, 0, stream>>>(muT_raw, pi_raw, n_muT, nmu_h, nmu_l);
  }
  {
    dim3 g(K_, B_);
    reg_fea_k<<<g, 256, 0, stream>>>(n_muT, out);
  }
  // cost_fea
  {
    dim3 g(N_ / 128, 1, B_);
    gemm64_bt<<<g, 256, 0, stream>>>(nmu_h, nmu_l, feature, invn, cost_f);
  }
  // cooperative Sinkhorn + fused loss
  {
    void* kargs[] = {(void*)&cost_f, (void*)&xyz, (void*)&mu_x, (void*)&yn,
                     (void*)&logpNK, (void*)&out, (void*)&partMS, (void*)&cnt};
    hipLaunchCooperativeKernel((const void*)sinkhorn_coop, dim3(256), dim3(256),
                               kargs, 0, stream);
  }
}